// Round 5
// baseline (586.401 us; speedup 1.0000x reference)
//
#include <hip/hip_runtime.h>

#define N_NODES 100000
#define E_EDGES 1600000
#define D 128
#define SHIFT 7
#define BNODES 128
#define NB ((N_NODES + BNODES - 1) / BNODES)     // 782 bins

#define CNT_CHUNK 2048
#define CNT_NBLK ((E_EDGES + CNT_CHUNK - 1) / CNT_CHUNK)    // 782
#define PREP_NBLK (N_NODES * 32 / 256)                      // 12500
#define SCAT_CHUNK 8192
#define SCAT_PASS 2                                         // 8192 / (1024*4)
#define SCAT_NBLK ((E_EDGES + SCAT_CHUNK - 1) / SCAT_CHUNK) // 196
#define GATH32_NBLK (N_NODES / 8)                           // 12500 (mid tier)

// fused gather+gemm tiling
#define FBLK 64
#define FGRID ((N_NODES + FBLK - 1) / FBLK)                 // 1563

// single-block node scan
#define SCAN_CHUNK 98                                       // 1024*98 = 100352 >= N

// fp32-GEMM tiling (tier-0 fallback only)
#define GROWS 64
#define KCH 32

typedef _Float16       f16x8  __attribute__((ext_vector_type(8)));
typedef float          f32x4  __attribute__((ext_vector_type(4)));
typedef unsigned short u16x8  __attribute__((ext_vector_type(8)));

// ---- workspace layout (int units) ----
#define WS_CNT   0
#define WS_BOFF  784
#define WS_POS   1568
#define WS_NOFF  2352                      // N+1 (mid tier)
#define WS_EBUF  102400                    // E (mid tier); full tier reuses as ncnt/pos/noff
#define WS_ESRC  (102400 + E_EDGES)        // E
#define WS_HS    (102400 + 2 * E_EDGES)    // N*D/2 ints (bf16 h*norm)
#define WS_FULL_INTS ((size_t)WS_HS + (size_t)N_NODES * D / 2)
#define WS_MID_INTS  ((size_t)WS_HS)

// full-tier direct-CSR layout (inside dead ebuf region, 1.6M ints available)
#define WF_NCNT  WS_EBUF                   // 100000
#define WF_POS   (WS_EBUF + 100352)        // 100000
#define WF_NOFF  (WS_EBUF + 200704)        // 100001 (ends 300705 << 1.6M)

// ======================= full tier: prep + per-node count =======================
// blocks < prep_blocks: hs = bf16(h * norm_src); rest: global atomic per-node count.
__global__ __launch_bounds__(256) void prep_ncount(const float* __restrict__ h,
                                                   const float* __restrict__ norm,
                                                   unsigned short* __restrict__ hs,
                                                   const int* __restrict__ dst,
                                                   int* __restrict__ ncnt,
                                                   int prep_blocks) {
    const int t = threadIdx.x;
    if ((int)blockIdx.x < prep_blocks) {
        const int idx = blockIdx.x * 256 + t;
        const int node = idx >> 5;
        const int c = (idx & 31) << 2;
        const float nv = norm[node];
        const float4 v = *reinterpret_cast<const float4*>(h + node * D + c);
        float a[4] = {v.x * nv, v.y * nv, v.z * nv, v.w * nv};
        ushort4 o;
        unsigned short* op = reinterpret_cast<unsigned short*>(&o);
        #pragma unroll
        for (int i = 0; i < 4; ++i) {
            unsigned int u = __float_as_uint(a[i]);
            u += 0x7FFFu + ((u >> 16) & 1u);            // round-to-nearest-even
            op[i] = (unsigned short)(u >> 16);
        }
        *reinterpret_cast<ushort4*>(hs + node * D + c) = o;
        return;
    }
    const int cb = blockIdx.x - prep_blocks;
    const int e0 = cb * CNT_CHUNK;
    const int rem = (E_EDGES - e0 < CNT_CHUNK) ? (E_EDGES - e0) : CNT_CHUNK;
    if (rem == CNT_CHUNK) {
        const int4* d4 = reinterpret_cast<const int4*>(dst + e0);
        #pragma unroll
        for (int p = 0; p < 2; ++p) {
            const int4 v = d4[p * 256 + t];
            atomicAdd(&ncnt[v.x], 1);
            atomicAdd(&ncnt[v.y], 1);
            atomicAdd(&ncnt[v.z], 1);
            atomicAdd(&ncnt[v.w], 1);
        }
    } else {
        for (int i = t; i < rem; i += 256)
            atomicAdd(&ncnt[dst[e0 + i]], 1);
    }
}

// ======================= full tier: single-block scan of 100k node counts ====
__global__ __launch_bounds__(1024) void node_scan(const int* __restrict__ ncnt,
                                                  int* __restrict__ noff,
                                                  int* __restrict__ pos) {
    __shared__ int buf[2][1024];
    const int t = threadIdx.x;
    const int base = t * SCAN_CHUNK;
    int s = 0;
    for (int i = 0; i < SCAN_CHUNK; ++i) {
        const int idx = base + i;
        if (idx < N_NODES) s += ncnt[idx];
    }
    int pi = 0;
    buf[0][t] = s;
    __syncthreads();
    #pragma unroll
    for (int o = 1; o < 1024; o <<= 1) {
        const int nv = buf[pi][t] + (t >= o ? buf[pi][t - o] : 0);
        buf[1 - pi][t] = nv;
        pi = 1 - pi;
        __syncthreads();
    }
    int run = buf[pi][t] - s;                       // exclusive prefix of this chunk
    for (int i = 0; i < SCAN_CHUNK; ++i) {
        const int idx = base + i;
        if (idx < N_NODES) {
            noff[idx] = run;
            pos[idx] = run;
            run += ncnt[idx];
        }
    }
    if (t == 0) noff[N_NODES] = E_EDGES;
}

// ======================= full tier: direct scatter into node CSR =============
__global__ __launch_bounds__(1024) void scatter_direct(const int* __restrict__ src,
                                                       const int* __restrict__ dst,
                                                       int* __restrict__ pos,
                                                       int* __restrict__ esrc) {
    const int t = threadIdx.x;
    const int e0 = blockIdx.x * SCAT_CHUNK;
    const int rem = (E_EDGES - e0 < SCAT_CHUNK) ? (E_EDGES - e0) : SCAT_CHUNK;
    if (rem == SCAT_CHUNK) {
        const int4* d4 = reinterpret_cast<const int4*>(dst + e0);
        const int4* s4 = reinterpret_cast<const int4*>(src + e0);
        #pragma unroll
        for (int p = 0; p < SCAT_PASS; ++p) {
            const int4 dv = d4[p * 1024 + t];
            const int4 sv = s4[p * 1024 + t];
            int pz;
            pz = atomicAdd(&pos[dv.x], 1); esrc[pz] = sv.x;
            pz = atomicAdd(&pos[dv.y], 1); esrc[pz] = sv.y;
            pz = atomicAdd(&pos[dv.z], 1); esrc[pz] = sv.z;
            pz = atomicAdd(&pos[dv.w], 1); esrc[pz] = sv.w;
        }
    } else {
        for (int i = t; i < rem; i += 1024) {
            const int d = dst[e0 + i];
            const int p = atomicAdd(&pos[d], 1);
            esrc[p] = src[e0 + i];
        }
    }
}

// ======================= FUSED gather (bf16) + MFMA GEMM + epilogue ==========
// (round-3 correctness-proven version). Phase A: 16 lanes/node, 8 edge-rows in
// flight, fp32 accum, f16 into LDS gs[64][136]. Phase B: W staged in TWO
// K-halves (Wlds 16KB) -> total LDS ~34KB -> 4 blocks/CU = 16 waves/CU, equal
// to the standalone gather's measured effective occupancy.
__global__ __launch_bounds__(256) void fused_gather_gemm(
    const unsigned short* __restrict__ hs, const int* __restrict__ noff,
    const int* __restrict__ esrc, const float* __restrict__ Wm,
    const float* __restrict__ bias, const float* __restrict__ norm,
    float* __restrict__ out)
{
    __shared__ _Float16 gs[FBLK][136];
    __shared__ f16x8 Wlds[1024];           // 16 KB, half of W fragments
    const int t = threadIdx.x;
    const int row0 = blockIdx.x * FBLK;
    const int c = (t & 15) << 3;                    // 8 cols per lane

    // ---------------- phase A: gather 64 node-rows ----------------
    #pragma unroll 1
    for (int r = 0; r < 4; ++r) {
        const int nl = r * 16 + (t >> 4);
        const int node = row0 + nl;
        float a[8];
        #pragma unroll
        for (int j = 0; j < 8; ++j) a[j] = 0.f;
        if (node < N_NODES) {
            int i = noff[node];
            const int end = noff[node + 1];
            for (; i + 7 < end; i += 8) {
                const int s0 = esrc[i];     const int s1 = esrc[i + 1];
                const int s2 = esrc[i + 2]; const int s3 = esrc[i + 3];
                const int s4 = esrc[i + 4]; const int s5 = esrc[i + 5];
                const int s6 = esrc[i + 6]; const int s7 = esrc[i + 7];
                const u16x8 u0 = *reinterpret_cast<const u16x8*>(hs + s0 * D + c);
                const u16x8 u1 = *reinterpret_cast<const u16x8*>(hs + s1 * D + c);
                const u16x8 u2 = *reinterpret_cast<const u16x8*>(hs + s2 * D + c);
                const u16x8 u3 = *reinterpret_cast<const u16x8*>(hs + s3 * D + c);
                const u16x8 u4 = *reinterpret_cast<const u16x8*>(hs + s4 * D + c);
                const u16x8 u5 = *reinterpret_cast<const u16x8*>(hs + s5 * D + c);
                const u16x8 u6 = *reinterpret_cast<const u16x8*>(hs + s6 * D + c);
                const u16x8 u7 = *reinterpret_cast<const u16x8*>(hs + s7 * D + c);
                #pragma unroll
                for (int j = 0; j < 8; ++j) {
                    a[j] += __uint_as_float((unsigned int)u0[j] << 16);
                    a[j] += __uint_as_float((unsigned int)u1[j] << 16);
                    a[j] += __uint_as_float((unsigned int)u2[j] << 16);
                    a[j] += __uint_as_float((unsigned int)u3[j] << 16);
                    a[j] += __uint_as_float((unsigned int)u4[j] << 16);
                    a[j] += __uint_as_float((unsigned int)u5[j] << 16);
                    a[j] += __uint_as_float((unsigned int)u6[j] << 16);
                    a[j] += __uint_as_float((unsigned int)u7[j] << 16);
                }
            }
            if (i + 3 < end) {
                const int s0 = esrc[i];     const int s1 = esrc[i + 1];
                const int s2 = esrc[i + 2]; const int s3 = esrc[i + 3];
                const u16x8 u0 = *reinterpret_cast<const u16x8*>(hs + s0 * D + c);
                const u16x8 u1 = *reinterpret_cast<const u16x8*>(hs + s1 * D + c);
                const u16x8 u2 = *reinterpret_cast<const u16x8*>(hs + s2 * D + c);
                const u16x8 u3 = *reinterpret_cast<const u16x8*>(hs + s3 * D + c);
                #pragma unroll
                for (int j = 0; j < 8; ++j) {
                    a[j] += __uint_as_float((unsigned int)u0[j] << 16);
                    a[j] += __uint_as_float((unsigned int)u1[j] << 16);
                    a[j] += __uint_as_float((unsigned int)u2[j] << 16);
                    a[j] += __uint_as_float((unsigned int)u3[j] << 16);
                }
                i += 4;
            }
            for (; i < end; ++i) {
                const int s = esrc[i];
                const u16x8 u = *reinterpret_cast<const u16x8*>(hs + s * D + c);
                #pragma unroll
                for (int j = 0; j < 8; ++j)
                    a[j] += __uint_as_float((unsigned int)u[j] << 16);
            }
        }
        f16x8 o;
        #pragma unroll
        for (int j = 0; j < 8; ++j) o[j] = (_Float16)a[j];
        *reinterpret_cast<f16x8*>(&gs[nl][c]) = o;
    }

    // ---------------- phase B: MFMA over two W half-tiles ----------------
    const int lane = t & 63;
    const int strip = t >> 6;
    const int q = lane >> 4;
    const int l15 = lane & 15;

    f32x4 acc[8];
    #pragma unroll
    for (int i = 0; i < 8; ++i) acc[i] = (f32x4){0.f, 0.f, 0.f, 0.f};

    #pragma unroll 1
    for (int half = 0; half < 2; ++half) {
        __syncthreads();                   // half 0: gs ready; half 1: Wlds drained
        for (int e = t; e < 1024; e += 256) {
            const int ge = (half << 10) + e;
            const int kiter = ge >> 9;
            const int nt = (ge >> 6) & 7;
            const int lane2 = ge & 63;
            const int q2 = lane2 >> 4;
            const int col = nt * 16 + (lane2 & 15);
            f16x8 v;
            #pragma unroll
            for (int j = 0; j < 8; ++j)
                v[j] = (_Float16)Wm[(kiter * 32 + q2 * 8 + j) * D + col];
            Wlds[e] = v;
        }
        __syncthreads();
        #pragma unroll
        for (int kk = 0; kk < 2; ++kk) {
            const int kiter = half * 2 + kk;
            const f16x8 a =
                *reinterpret_cast<const f16x8*>(&gs[strip * 16 + l15][kiter * 32 + q * 8]);
            #pragma unroll
            for (int nt = 0; nt < 8; ++nt) {
                const f16x8 b = Wlds[(kk * 8 + nt) * 64 + lane];
                acc[nt] = __builtin_amdgcn_mfma_f32_16x16x32_f16(a, b, acc[nt], 0, 0, 0);
            }
        }
    }

    float nrm[4];
    int mr[4];
    #pragma unroll
    for (int rgi = 0; rgi < 4; ++rgi) {
        mr[rgi] = row0 + strip * 16 + q * 4 + rgi;
        nrm[rgi] = (mr[rgi] < N_NODES) ? norm[mr[rgi]] : 0.f;
    }
    #pragma unroll
    for (int nt = 0; nt < 8; ++nt) {
        const int col = nt * 16 + l15;
        const float bc = bias[col];
        #pragma unroll
        for (int rgi = 0; rgi < 4; ++rgi) {
            if (mr[rgi] < N_NODES) {
                float v = acc[nt][rgi] * nrm[rgi] + bc;
                v = v > 0.f ? v : 0.2f * v;
                out[mr[rgi] * D + col] = v;
            }
        }
    }
}

// ======================= mid-tier legacy chain (unchanged, proven) ===========
__global__ __launch_bounds__(256) void prep_count(const float* __restrict__ h,
                                                  const float* __restrict__ norm,
                                                  unsigned short* __restrict__ hs,
                                                  const int* __restrict__ dst,
                                                  int* __restrict__ cnt,
                                                  int prep_blocks) {
    __shared__ int hist[NB];
    const int t = threadIdx.x;
    if ((int)blockIdx.x < prep_blocks) {
        const int idx = blockIdx.x * 256 + t;
        const int node = idx >> 5;
        const int c = (idx & 31) << 2;
        const float nv = norm[node];
        const float4 v = *reinterpret_cast<const float4*>(h + node * D + c);
        float a[4] = {v.x * nv, v.y * nv, v.z * nv, v.w * nv};
        ushort4 o;
        unsigned short* op = reinterpret_cast<unsigned short*>(&o);
        #pragma unroll
        for (int i = 0; i < 4; ++i) {
            unsigned int u = __float_as_uint(a[i]);
            u += 0x7FFFu + ((u >> 16) & 1u);
            op[i] = (unsigned short)(u >> 16);
        }
        *reinterpret_cast<ushort4*>(hs + node * D + c) = o;
        return;
    }
    const int cb = blockIdx.x - prep_blocks;
    const int e0 = cb * CNT_CHUNK;
    const int rem = (E_EDGES - e0 < CNT_CHUNK) ? (E_EDGES - e0) : CNT_CHUNK;
    for (int i = t; i < NB; i += 256) hist[i] = 0;
    __syncthreads();
    if (rem == CNT_CHUNK) {
        const int4* d4 = reinterpret_cast<const int4*>(dst + e0);
        #pragma unroll
        for (int p = 0; p < 2; ++p) {
            const int4 v = d4[p * 256 + t];
            atomicAdd(&hist[v.x >> SHIFT], 1);
            atomicAdd(&hist[v.y >> SHIFT], 1);
            atomicAdd(&hist[v.z >> SHIFT], 1);
            atomicAdd(&hist[v.w >> SHIFT], 1);
        }
    } else {
        for (int i = t; i < rem; i += 256)
            atomicAdd(&hist[dst[e0 + i] >> SHIFT], 1);
    }
    __syncthreads();
    for (int b = t; b < NB; b += 256) {
        const int c = hist[b];
        if (c) atomicAdd(&cnt[b], c);
    }
}

__global__ __launch_bounds__(1024) void coarse_scan(const int* __restrict__ cnt,
                                                    int* __restrict__ boff,
                                                    int* __restrict__ pos) {
    __shared__ int buf[2][1024];
    const int t = threadIdx.x;
    const int v = (t < NB) ? cnt[t] : 0;
    int pi = 0;
    buf[0][t] = v;
    __syncthreads();
    #pragma unroll
    for (int o = 1; o < 1024; o <<= 1) {
        const int nv = buf[pi][t] + (t >= o ? buf[pi][t - o] : 0);
        buf[1 - pi][t] = nv;
        pi = 1 - pi;
        __syncthreads();
    }
    if (t < NB) {
        const int excl = buf[pi][t] - v;
        boff[t] = excl;
        pos[t] = excl;
    }
    if (t == 0) boff[NB] = E_EDGES;
}

__global__ __launch_bounds__(1024) void coarse_scatter(const int* __restrict__ src,
                                                       const int* __restrict__ dst,
                                                       int* __restrict__ pos,
                                                       int* __restrict__ ebuf) {
    __shared__ int hist[NB];
    const int t = threadIdx.x;
    const int e0 = blockIdx.x * SCAT_CHUNK;
    const int rem = (E_EDGES - e0 < SCAT_CHUNK) ? (E_EDGES - e0) : SCAT_CHUNK;
    for (int i = t; i < NB; i += 1024) hist[i] = 0;
    __syncthreads();
    if (rem == SCAT_CHUNK) {
        const int4* d4 = reinterpret_cast<const int4*>(dst + e0);
        #pragma unroll
        for (int p = 0; p < SCAT_PASS; ++p) {
            const int4 v = d4[p * 1024 + t];
            atomicAdd(&hist[v.x >> SHIFT], 1);
            atomicAdd(&hist[v.y >> SHIFT], 1);
            atomicAdd(&hist[v.z >> SHIFT], 1);
            atomicAdd(&hist[v.w >> SHIFT], 1);
        }
    } else {
        for (int i = t; i < rem; i += 1024)
            atomicAdd(&hist[dst[e0 + i] >> SHIFT], 1);
    }
    __syncthreads();
    for (int b = t; b < NB; b += 1024) {
        const int c = hist[b];
        if (c) hist[b] = atomicAdd(&pos[b], c);
    }
    __syncthreads();
    if (rem == SCAT_CHUNK) {
        const int4* d4 = reinterpret_cast<const int4*>(dst + e0);
        const int4* s4 = reinterpret_cast<const int4*>(src + e0);
        #pragma unroll
        for (int p = 0; p < SCAT_PASS; ++p) {
            const int4 dv = d4[p * 1024 + t];
            const int4 sv = s4[p * 1024 + t];
            int pz;
            pz = atomicAdd(&hist[dv.x >> SHIFT], 1);
            ebuf[pz] = (sv.x << SHIFT) | (dv.x & (BNODES - 1));
            pz = atomicAdd(&hist[dv.y >> SHIFT], 1);
            ebuf[pz] = (sv.y << SHIFT) | (dv.y & (BNODES - 1));
            pz = atomicAdd(&hist[dv.z >> SHIFT], 1);
            ebuf[pz] = (sv.z << SHIFT) | (dv.z & (BNODES - 1));
            pz = atomicAdd(&hist[dv.w >> SHIFT], 1);
            ebuf[pz] = (sv.w << SHIFT) | (dv.w & (BNODES - 1));
        }
    } else {
        for (int i = t; i < rem; i += 1024) {
            const int d = dst[e0 + i];
            const int b = d >> SHIFT;
            const int p = atomicAdd(&hist[b], 1);
            ebuf[p] = (src[e0 + i] << SHIFT) | (d & (BNODES - 1));
        }
    }
}

__global__ __launch_bounds__(256) void bin_sort(const int* __restrict__ boff,
                                                const int* __restrict__ ebuf,
                                                int* __restrict__ esrc,
                                                int* __restrict__ noff) {
    __shared__ int hist[BNODES];
    __shared__ int curs[BNODES];
    __shared__ int sbuf[2][BNODES];
    const int t = threadIdx.x;
    const int bin = blockIdx.x;
    if (t < BNODES) hist[t] = 0;
    __syncthreads();
    const int b0 = boff[bin];
    const int b1 = boff[bin + 1];
    for (int i = b0 + t; i < b1; i += 256)
        atomicAdd(&hist[ebuf[i] & (BNODES - 1)], 1);
    __syncthreads();
    if (t < BNODES) sbuf[0][t] = hist[t];
    __syncthreads();
    int pi = 0;
    #pragma unroll
    for (int o = 1; o < BNODES; o <<= 1) {
        if (t < BNODES)
            sbuf[1 - pi][t] = sbuf[pi][t] + (t >= o ? sbuf[pi][t - o] : 0);
        pi = 1 - pi;
        __syncthreads();
    }
    if (t < BNODES) {
        const int base = b0 + sbuf[pi][t] - hist[t];
        curs[t] = base;
        const int node = (bin << SHIFT) + t;
        if (node < N_NODES) noff[node] = base;
    }
    if (bin == 0 && t == 0) noff[N_NODES] = E_EDGES;
    __syncthreads();
    for (int i = b0 + t; i < b1; i += 256) {
        const int w = ebuf[i];
        const int p = atomicAdd(&curs[w & (BNODES - 1)], 1);
        esrc[p] = w >> SHIFT;
    }
}

__device__ __forceinline__ void wprep_body(int tid, const float* __restrict__ Wm,
                                           f16x8* __restrict__ Whs) {
    const int kiter = tid >> 9;
    const int nt = (tid >> 6) & 7;
    const int lane = tid & 63;
    const int q = lane >> 4;
    const int col = nt * 16 + (lane & 15);
    f16x8 v;
    #pragma unroll
    for (int j = 0; j < 8; ++j)
        v[j] = (_Float16)Wm[(kiter * 32 + q * 8 + j) * D + col];
    Whs[tid] = v;
}

__global__ __launch_bounds__(256) void gather_fp32(const float* __restrict__ h,
                                                   const float* __restrict__ norm,
                                                   const int* __restrict__ noff,
                                                   const int* __restrict__ esrc,
                                                   float* __restrict__ g,
                                                   const float* __restrict__ Wm,
                                                   f16x8* __restrict__ Whs) {
    if ((int)blockIdx.x >= GATH32_NBLK) {
        wprep_body((blockIdx.x - GATH32_NBLK) * 256 + threadIdx.x, Wm, Whs);
        return;
    }
    const int t = threadIdx.x;
    const int node = blockIdx.x * 8 + (t >> 5);
    const int c = (t & 31) << 2;
    const int beg = noff[node];
    const int end = noff[node + 1];
    float4 acc = make_float4(0.f, 0.f, 0.f, 0.f);
    for (int i = beg; i < end; ++i) {
        const int s = esrc[i];
        const float nv = norm[s];
        const float4 hv = *reinterpret_cast<const float4*>(h + s * D + c);
        acc.x += hv.x * nv;
        acc.y += hv.y * nv;
        acc.z += hv.z * nv;
        acc.w += hv.w * nv;
    }
    *reinterpret_cast<float4*>(g + node * D + c) = acc;
}

__global__ __launch_bounds__(256) void scatter_kernel(
    const float* __restrict__ h, const float* __restrict__ norm,
    const int* __restrict__ src, const int* __restrict__ dst,
    float* __restrict__ g)
{
    const int idx = blockIdx.x * 256 + threadIdx.x;
    const int e = idx >> 5;
    const int c = (idx & 31) << 2;
    const int s = src[e];
    const int d = dst[e];
    const float nv = norm[s];
    const float4 hv = *reinterpret_cast<const float4*>(h + s * D + c);
    float* gp = g + d * D + c;
    atomicAdd(gp + 0, hv.x * nv);
    atomicAdd(gp + 1, hv.y * nv);
    atomicAdd(gp + 2, hv.z * nv);
    atomicAdd(gp + 3, hv.w * nv);
}

__global__ __launch_bounds__(256) void gemm_mfma(
    float* __restrict__ out, const f16x8* __restrict__ Whs,
    const float* __restrict__ bias, const float* __restrict__ norm)
{
    __shared__ f16x8 Wlds[2048];           // 32 KB
    const int t = threadIdx.x;
    const int row0 = blockIdx.x * 64;

    #pragma unroll
    for (int p = 0; p < 8; ++p)
        reinterpret_cast<float4*>(Wlds)[p * 256 + t] =
            reinterpret_cast<const float4*>(Whs)[p * 256 + t];
    __syncthreads();

    const int lane = t & 63;
    const int strip = t >> 6;
    const int q = lane >> 4;
    const int l15 = lane & 15;

    int mrow = row0 + strip * 16 + l15;
    if (mrow >= N_NODES) mrow = N_NODES - 1;

    f32x4 acc[8];
    #pragma unroll
    for (int i = 0; i < 8; ++i) acc[i] = (f32x4){0.f, 0.f, 0.f, 0.f};

    #pragma unroll
    for (int kiter = 0; kiter < 4; ++kiter) {
        const float* gp = out + mrow * D + kiter * 32 + q * 8;
        const float4 ga = *reinterpret_cast<const float4*>(gp);
        const float4 gb = *reinterpret_cast<const float4*>(gp + 4);
        f16x8 a;
        a[0] = (_Float16)ga.x; a[1] = (_Float16)ga.y;
        a[2] = (_Float16)ga.z; a[3] = (_Float16)ga.w;
        a[4] = (_Float16)gb.x; a[5] = (_Float16)gb.y;
        a[6] = (_Float16)gb.z; a[7] = (_Float16)gb.w;
        #pragma unroll
        for (int nt = 0; nt < 8; ++nt) {
            const f16x8 b = Wlds[(kiter * 8 + nt) * 64 + lane];
            acc[nt] = __builtin_amdgcn_mfma_f32_16x16x32_f16(a, b, acc[nt], 0, 0, 0);
        }
    }

    float nrm[4];
    int mr[4];
    #pragma unroll
    for (int rgi = 0; rgi < 4; ++rgi) {
        mr[rgi] = row0 + strip * 16 + q * 4 + rgi;
        nrm[rgi] = (mr[rgi] < N_NODES) ? norm[mr[rgi]] : 0.f;
    }
    #pragma unroll
    for (int nt = 0; nt < 8; ++nt) {
        const int col = nt * 16 + l15;
        const float bc = bias[col];
        #pragma unroll
        for (int rgi = 0; rgi < 4; ++rgi) {
            if (mr[rgi] < N_NODES) {
                float v = acc[nt][rgi] * nrm[rgi] + bc;
                v = v > 0.f ? v : 0.2f * v;
                out[mr[rgi] * D + col] = v;
            }
        }
    }
}

__global__ __launch_bounds__(256) void gemm_epilogue(
    float* __restrict__ out, const float* __restrict__ Wm,
    const float* __restrict__ bias, const float* __restrict__ norm)
{
    __shared__ float gs[GROWS][D + 4];
    __shared__ float Wlds[KCH][D];
    const int t = threadIdx.x;
    const int row0 = blockIdx.x * GROWS;

    #pragma unroll
    for (int p = 0; p < 8; ++p) {
        const int i = p * 256 + t;
        const int r = i >> 5;
        const int c = (i & 31) << 2;
        int gr = row0 + r;
        if (gr >= N_NODES) gr = N_NODES - 1;
        const float4 v = *reinterpret_cast<const float4*>(out + gr * D + c);
        *reinterpret_cast<float4*>(&gs[r][c]) = v;
    }

    const int rg = (t >> 5) * 8;
    const int cb = (t & 31) << 2;

    float4 acc[8];
    #pragma unroll
    for (int i = 0; i < 8; ++i) acc[i] = make_float4(0.f, 0.f, 0.f, 0.f);

    for (int kc = 0; kc < D; kc += KCH) {
        __syncthreads();
        #pragma unroll
        for (int p = 0; p < 4; ++p) {
            const int i = p * 256 + t;
            const int kk = i >> 5;
            const int c = (i & 31) << 2;
            *reinterpret_cast<float4*>(&Wlds[kk][c]) =
                *reinterpret_cast<const float4*>(Wm + (kc + kk) * D + c);
        }
        __syncthreads();

        #pragma unroll
        for (int k4 = 0; k4 < KCH; k4 += 4) {
            float4 wv[4];
            #pragma unroll
            for (int kk = 0; kk < 4; ++kk)
                wv[kk] = *reinterpret_cast<const float4*>(&Wlds[k4 + kk][cb]);
            #pragma unroll
            for (int i = 0; i < 8; ++i) {
                const float4 gv = *reinterpret_cast<const float4*>(&gs[rg + i][kc + k4]);
                acc[i].x += gv.x * wv[0].x; acc[i].y += gv.x * wv[0].y;
                acc[i].z += gv.x * wv[0].z; acc[i].w += gv.x * wv[0].w;
                acc[i].x += gv.y * wv[1].x; acc[i].y += gv.y * wv[1].y;
                acc[i].z += gv.y * wv[1].z; acc[i].w += gv.y * wv[1].w;
                acc[i].x += gv.z * wv[2].x; acc[i].y += gv.z * wv[2].y;
                acc[i].z += gv.z * wv[2].z; acc[i].w += gv.z * wv[2].w;
                acc[i].x += gv.w * wv[3].x; acc[i].y += gv.w * wv[3].y;
                acc[i].z += gv.w * wv[3].z; acc[i].w += gv.w * wv[3].w;
            }
        }
    }

    const float4 b = *reinterpret_cast<const float4*>(bias + cb);
    #pragma unroll
    for (int i = 0; i < 8; ++i) {
        const int gr = row0 + rg + i;
        if (gr < N_NODES) {
            const float nv = norm[gr];
            float4 v;
            v.x = acc[i].x * nv + b.x;
            v.y = acc[i].y * nv + b.y;
            v.z = acc[i].z * nv + b.z;
            v.w = acc[i].w * nv + b.w;
            v.x = v.x > 0.f ? v.x : 0.2f * v.x;
            v.y = v.y > 0.f ? v.y : 0.2f * v.y;
            v.z = v.z > 0.f ? v.z : 0.2f * v.z;
            v.w = v.w > 0.f ? v.w : 0.2f * v.w;
            *reinterpret_cast<float4*>(out + gr * D + cb) = v;
        }
    }
}

extern "C" void kernel_launch(void* const* d_in, const int* in_sizes, int n_in,
                              void* d_out, int out_size, void* d_ws, size_t ws_size,
                              hipStream_t stream) {
    const float* h    = (const float*)d_in[0];
    const float* norm = (const float*)d_in[1];
    const float* Wm   = (const float*)d_in[2];
    const float* bias = (const float*)d_in[3];
    const int*   src  = (const int*)d_in[4];
    const int*   dst  = (const int*)d_in[5];
    float* out = (float*)d_out;
    int* ws = (int*)d_ws;

    if (ws_size >= WS_FULL_INTS * 4) {
        // ---- full tier: 5-dispatch direct-CSR pipeline ----
        int* ncnt = ws + WF_NCNT;
        int* pos  = ws + WF_POS;
        int* noff = ws + WF_NOFF;
        int* esrc = ws + WS_ESRC;
        unsigned short* hs = (unsigned short*)(ws + WS_HS);

        hipMemsetAsync(ncnt, 0, N_NODES * sizeof(int), stream);
        prep_ncount<<<PREP_NBLK + CNT_NBLK, 256, 0, stream>>>(h, norm, hs, dst, ncnt, PREP_NBLK);
        node_scan<<<1, 1024, 0, stream>>>(ncnt, noff, pos);
        scatter_direct<<<SCAT_NBLK, 1024, 0, stream>>>(src, dst, pos, esrc);
        fused_gather_gemm<<<FGRID, 256, 0, stream>>>(hs, noff, esrc, Wm, bias, norm, out);
    } else if (ws_size >= WS_MID_INTS * 4) {
        // ---- mid tier: legacy proven chain ----
        int* cnt  = ws + WS_CNT;
        int* boff = ws + WS_BOFF;
        int* pos  = ws + WS_POS;
        int* noff = ws + WS_NOFF;
        int* ebuf = ws + WS_EBUF;
        int* esrc = ws + WS_ESRC;
        f16x8* Whs = (f16x8*)ebuf;         // ebuf dead after bin_sort

        hipMemsetAsync(cnt, 0, NB * sizeof(int), stream);
        prep_count<<<CNT_NBLK, 256, 0, stream>>>(h, norm, (unsigned short*)ws, dst, cnt, 0);
        coarse_scan   <<<1, 1024, 0, stream>>>(cnt, boff, pos);
        coarse_scatter<<<SCAT_NBLK / 2 + 1, 1024, 0, stream>>>(src, dst, pos, ebuf);
        bin_sort      <<<NB, 256, 0, stream>>>(boff, ebuf, esrc, noff);
        gather_fp32<<<GATH32_NBLK + 8, 256, 0, stream>>>(h, norm, noff, esrc, out, Wm, Whs);
        gemm_mfma<<<(N_NODES + 63) / 64, 256, 0, stream>>>(out, Whs, bias, norm);
    } else {
        hipMemsetAsync(out, 0, (size_t)N_NODES * D * sizeof(float), stream);
        scatter_kernel<<<(E_EDGES * 32) / 256, 256, 0, stream>>>(h, norm, src, dst, out);
        gemm_epilogue<<<(N_NODES + GROWS - 1) / GROWS, 256, 0, stream>>>(out, Wm, bias, norm);
    }
}

// Round 6
// 236.563 us; speedup vs baseline: 2.4788x; 2.4788x over previous
//
#include <hip/hip_runtime.h>

#define N_NODES 100000
#define E_EDGES 1600000
#define D 128
#define SHIFT 7
#define BNODES 128
#define NB ((N_NODES + BNODES - 1) / BNODES)     // 782 bins

#define CNT_CHUNK 2048
#define CNT_NBLK ((E_EDGES + CNT_CHUNK - 1) / CNT_CHUNK)    // 782
#define PREP_NBLK (N_NODES * 32 / 256)                      // 12500
#define SCAT_CHUNK 8192
#define SCAT_PASS 2                                         // 8192 / (1024*4)
#define SCAT_NBLK ((E_EDGES + SCAT_CHUNK - 1) / SCAT_CHUNK) // 196
#define GATH_NBLK (N_NODES / 16)                            // 6250
#define GATH32_NBLK (N_NODES / 8)                           // 12500 (mid tier)

// fp32-GEMM tiling (tier-0 fallback only)
#define GROWS 64
#define KCH 32

typedef _Float16       f16x8  __attribute__((ext_vector_type(8)));
typedef float          f32x4  __attribute__((ext_vector_type(4)));
typedef unsigned short u16x8  __attribute__((ext_vector_type(8)));

// ---- workspace layout (int units) ----
// cnt and pos are contiguous so one memset zeroes both (full tier).
#define WS_CNT   0                         // 784 slots
#define WS_POS   784                       // 784 slots
#define WS_BOFF  1568                      // 785 slots
#define WS_NOFF  2356                      // N+1
#define WS_EBUF  102400                    // E   (reused as Whs after bin_sort)
#define WS_ESRC  (102400 + E_EDGES)        // E
#define WS_HS    (102400 + 2 * E_EDGES)    // N*D/2 ints (bf16 h*norm)
#define WS_FULL_INTS ((size_t)WS_HS + (size_t)N_NODES * D / 2)
#define WS_MID_INTS  ((size_t)WS_HS)

// f16 g staging inside `out`: row r occupies the FIRST 256 B of row r's fp32
// slot. gemm blocks read only their own 64-row slab's f16 before overwriting
// that slab with fp32 (in-block __syncthreads between A-reads and stores).
#define GROW16 256                          // _Float16 elements per row slot

// ======================= fused prep + coarse count =======================
__global__ __launch_bounds__(256) void prep_count(const float* __restrict__ h,
                                                  const float* __restrict__ norm,
                                                  unsigned short* __restrict__ hs,
                                                  const int* __restrict__ dst,
                                                  int* __restrict__ cnt,
                                                  int prep_blocks) {
    __shared__ int hist[NB];
    const int t = threadIdx.x;
    if ((int)blockIdx.x < prep_blocks) {
        const int idx = blockIdx.x * 256 + t;
        const int node = idx >> 5;
        const int c = (idx & 31) << 2;
        const float nv = norm[node];
        const float4 v = *reinterpret_cast<const float4*>(h + node * D + c);
        float a[4] = {v.x * nv, v.y * nv, v.z * nv, v.w * nv};
        ushort4 o;
        unsigned short* op = reinterpret_cast<unsigned short*>(&o);
        #pragma unroll
        for (int i = 0; i < 4; ++i) {
            unsigned int u = __float_as_uint(a[i]);
            u += 0x7FFFu + ((u >> 16) & 1u);            // round-to-nearest-even
            op[i] = (unsigned short)(u >> 16);
        }
        *reinterpret_cast<ushort4*>(hs + node * D + c) = o;
        return;
    }
    const int cb = blockIdx.x - prep_blocks;
    const int e0 = cb * CNT_CHUNK;
    const int rem = (E_EDGES - e0 < CNT_CHUNK) ? (E_EDGES - e0) : CNT_CHUNK;
    for (int i = t; i < NB; i += 256) hist[i] = 0;
    __syncthreads();
    if (rem == CNT_CHUNK) {
        const int4* d4 = reinterpret_cast<const int4*>(dst + e0);
        #pragma unroll
        for (int p = 0; p < 2; ++p) {
            const int4 v = d4[p * 256 + t];
            atomicAdd(&hist[v.x >> SHIFT], 1);
            atomicAdd(&hist[v.y >> SHIFT], 1);
            atomicAdd(&hist[v.z >> SHIFT], 1);
            atomicAdd(&hist[v.w >> SHIFT], 1);
        }
    } else {
        for (int i = t; i < rem; i += 256)
            atomicAdd(&hist[dst[e0 + i] >> SHIFT], 1);
    }
    __syncthreads();
    for (int b = t; b < NB; b += 256) {
        const int c = hist[b];
        if (c) atomicAdd(&cnt[b], c);
    }
}

// ======================= scatter + inline scan (full tier) =======================
// Replaces coarse_scan + coarse_scatter. Each block redundantly scans cnt[782]
// in LDS (proven ping-pong scan, ~1us, blocks run 1/CU in parallel), keeps its
// exclusive prefix in a register, claims slots via atomicAdd on zero-init pos:
// final = excl + claim  ==  old (pos pre-init to excl) semantics. Block 0
// writes boff for the later bin_sort dispatch.
__global__ __launch_bounds__(1024) void scatter_scan(const int* __restrict__ src,
                                                     const int* __restrict__ dst,
                                                     const int* __restrict__ cnt,
                                                     int* __restrict__ pos,
                                                     int* __restrict__ boff,
                                                     int* __restrict__ ebuf) {
    __shared__ int buf[2][1024];
    __shared__ int hist[NB];
    const int t = threadIdx.x;

    // ---- inline exclusive scan of cnt[0..NB) ----
    const int v = (t < NB) ? cnt[t] : 0;
    int pi = 0;
    buf[0][t] = v;
    __syncthreads();
    #pragma unroll
    for (int o = 1; o < 1024; o <<= 1) {
        const int nv = buf[pi][t] + (t >= o ? buf[pi][t - o] : 0);
        buf[1 - pi][t] = nv;
        pi = 1 - pi;
        __syncthreads();
    }
    const int excl = buf[pi][t] - v;                 // exclusive prefix (t < NB valid)
    if (blockIdx.x == 0) {
        if (t < NB) boff[t] = excl;
        if (t == 0) boff[NB] = E_EDGES;
    }
    if (t < NB) hist[t] = 0;
    __syncthreads();

    // ---- count this chunk ----
    const int e0 = blockIdx.x * SCAT_CHUNK;
    const int rem = (E_EDGES - e0 < SCAT_CHUNK) ? (E_EDGES - e0) : SCAT_CHUNK;
    if (rem == SCAT_CHUNK) {
        const int4* d4 = reinterpret_cast<const int4*>(dst + e0);
        #pragma unroll
        for (int p = 0; p < SCAT_PASS; ++p) {
            const int4 vv = d4[p * 1024 + t];
            atomicAdd(&hist[vv.x >> SHIFT], 1);
            atomicAdd(&hist[vv.y >> SHIFT], 1);
            atomicAdd(&hist[vv.z >> SHIFT], 1);
            atomicAdd(&hist[vv.w >> SHIFT], 1);
        }
    } else {
        for (int i = t; i < rem; i += 1024)
            atomicAdd(&hist[dst[e0 + i] >> SHIFT], 1);
    }
    __syncthreads();

    // ---- claim global slots ----
    if (t < NB) {
        const int c = hist[t];
        if (c) hist[t] = excl + atomicAdd(&pos[t], c);
    }
    __syncthreads();

    // ---- scatter packed words ----
    if (rem == SCAT_CHUNK) {
        const int4* d4 = reinterpret_cast<const int4*>(dst + e0);
        const int4* s4 = reinterpret_cast<const int4*>(src + e0);
        #pragma unroll
        for (int p = 0; p < SCAT_PASS; ++p) {
            const int4 dv = d4[p * 1024 + t];
            const int4 sv = s4[p * 1024 + t];
            int pz;
            pz = atomicAdd(&hist[dv.x >> SHIFT], 1);
            ebuf[pz] = (sv.x << SHIFT) | (dv.x & (BNODES - 1));
            pz = atomicAdd(&hist[dv.y >> SHIFT], 1);
            ebuf[pz] = (sv.y << SHIFT) | (dv.y & (BNODES - 1));
            pz = atomicAdd(&hist[dv.z >> SHIFT], 1);
            ebuf[pz] = (sv.z << SHIFT) | (dv.z & (BNODES - 1));
            pz = atomicAdd(&hist[dv.w >> SHIFT], 1);
            ebuf[pz] = (sv.w << SHIFT) | (dv.w & (BNODES - 1));
        }
    } else {
        for (int i = t; i < rem; i += 1024) {
            const int d = dst[e0 + i];
            const int b = d >> SHIFT;
            const int p = atomicAdd(&hist[b], 1);
            ebuf[p] = (src[e0 + i] << SHIFT) | (d & (BNODES - 1));
        }
    }
}

// ======================= scan 782 bin counts (mid tier) =======================
__global__ __launch_bounds__(1024) void coarse_scan(const int* __restrict__ cnt,
                                                    int* __restrict__ boff,
                                                    int* __restrict__ pos) {
    __shared__ int buf[2][1024];
    const int t = threadIdx.x;
    const int v = (t < NB) ? cnt[t] : 0;
    int pi = 0;
    buf[0][t] = v;
    __syncthreads();
    #pragma unroll
    for (int o = 1; o < 1024; o <<= 1) {
        const int nv = buf[pi][t] + (t >= o ? buf[pi][t - o] : 0);
        buf[1 - pi][t] = nv;
        pi = 1 - pi;
        __syncthreads();
    }
    if (t < NB) {
        const int excl = buf[pi][t] - v;
        boff[t] = excl;
        pos[t] = excl;
    }
    if (t == 0) boff[NB] = E_EDGES;
}

// ======================= scatter packed words by coarse bin (mid tier) =======
__global__ __launch_bounds__(1024) void coarse_scatter(const int* __restrict__ src,
                                                       const int* __restrict__ dst,
                                                       int* __restrict__ pos,
                                                       int* __restrict__ ebuf) {
    __shared__ int hist[NB];
    const int t = threadIdx.x;
    const int e0 = blockIdx.x * SCAT_CHUNK;
    const int rem = (E_EDGES - e0 < SCAT_CHUNK) ? (E_EDGES - e0) : SCAT_CHUNK;
    for (int i = t; i < NB; i += 1024) hist[i] = 0;
    __syncthreads();
    if (rem == SCAT_CHUNK) {
        const int4* d4 = reinterpret_cast<const int4*>(dst + e0);
        #pragma unroll
        for (int p = 0; p < SCAT_PASS; ++p) {
            const int4 v = d4[p * 1024 + t];
            atomicAdd(&hist[v.x >> SHIFT], 1);
            atomicAdd(&hist[v.y >> SHIFT], 1);
            atomicAdd(&hist[v.z >> SHIFT], 1);
            atomicAdd(&hist[v.w >> SHIFT], 1);
        }
    } else {
        for (int i = t; i < rem; i += 1024)
            atomicAdd(&hist[dst[e0 + i] >> SHIFT], 1);
    }
    __syncthreads();
    for (int b = t; b < NB; b += 1024) {
        const int c = hist[b];
        if (c) hist[b] = atomicAdd(&pos[b], c);
    }
    __syncthreads();
    if (rem == SCAT_CHUNK) {
        const int4* d4 = reinterpret_cast<const int4*>(dst + e0);
        const int4* s4 = reinterpret_cast<const int4*>(src + e0);
        #pragma unroll
        for (int p = 0; p < SCAT_PASS; ++p) {
            const int4 dv = d4[p * 1024 + t];
            const int4 sv = s4[p * 1024 + t];
            int pz;
            pz = atomicAdd(&hist[dv.x >> SHIFT], 1);
            ebuf[pz] = (sv.x << SHIFT) | (dv.x & (BNODES - 1));
            pz = atomicAdd(&hist[dv.y >> SHIFT], 1);
            ebuf[pz] = (sv.y << SHIFT) | (dv.y & (BNODES - 1));
            pz = atomicAdd(&hist[dv.z >> SHIFT], 1);
            ebuf[pz] = (sv.z << SHIFT) | (dv.z & (BNODES - 1));
            pz = atomicAdd(&hist[dv.w >> SHIFT], 1);
            ebuf[pz] = (sv.w << SHIFT) | (dv.w & (BNODES - 1));
        }
    } else {
        for (int i = t; i < rem; i += 1024) {
            const int d = dst[e0 + i];
            const int b = d >> SHIFT;
            const int p = atomicAdd(&hist[b], 1);
            ebuf[p] = (src[e0 + i] << SHIFT) | (d & (BNODES - 1));
        }
    }
}

// ======================= per-bin counting sort -> node CSR =======================
__global__ __launch_bounds__(256) void bin_sort(const int* __restrict__ boff,
                                                const int* __restrict__ ebuf,
                                                int* __restrict__ esrc,
                                                int* __restrict__ noff) {
    __shared__ int hist[BNODES];
    __shared__ int curs[BNODES];
    __shared__ int sbuf[2][BNODES];
    const int t = threadIdx.x;
    const int bin = blockIdx.x;
    if (t < BNODES) hist[t] = 0;
    __syncthreads();
    const int b0 = boff[bin];
    const int b1 = boff[bin + 1];
    for (int i = b0 + t; i < b1; i += 256)
        atomicAdd(&hist[ebuf[i] & (BNODES - 1)], 1);
    __syncthreads();
    if (t < BNODES) sbuf[0][t] = hist[t];
    __syncthreads();
    int pi = 0;
    #pragma unroll
    for (int o = 1; o < BNODES; o <<= 1) {
        if (t < BNODES)
            sbuf[1 - pi][t] = sbuf[pi][t] + (t >= o ? sbuf[pi][t - o] : 0);
        pi = 1 - pi;
        __syncthreads();
    }
    if (t < BNODES) {
        const int base = b0 + sbuf[pi][t] - hist[t];
        curs[t] = base;
        const int node = (bin << SHIFT) + t;
        if (node < N_NODES) noff[node] = base;
    }
    if (bin == 0 && t == 0) noff[N_NODES] = E_EDGES;
    __syncthreads();
    for (int i = b0 + t; i < b1; i += 256) {
        const int w = ebuf[i];
        const int p = atomicAdd(&curs[w & (BNODES - 1)], 1);
        esrc[p] = w >> SHIFT;
    }
}

// ======================= wprep body (shared by gather kernels) =======================
__device__ __forceinline__ void wprep_body(int tid, const float* __restrict__ Wm,
                                           f16x8* __restrict__ Whs) {
    const int kiter = tid >> 9;
    const int nt = (tid >> 6) & 7;
    const int lane = tid & 63;
    const int q = lane >> 4;
    const int col = nt * 16 + (lane & 15);
    f16x8 v;
    #pragma unroll
    for (int j = 0; j < 8; ++j)
        v[j] = (_Float16)Wm[(kiter * 32 + q * 8 + j) * D + col];
    Whs[tid] = v;
}

// ======================= gather (bf16) + fused wprep =======================
__global__ __launch_bounds__(256) void gather_wprep(
    const unsigned short* __restrict__ hs, const int* __restrict__ noff,
    const int* __restrict__ esrc, _Float16* __restrict__ g16,
    const float* __restrict__ Wm, f16x8* __restrict__ Whs)
{
    if ((int)blockIdx.x >= GATH_NBLK) {
        wprep_body((blockIdx.x - GATH_NBLK) * 256 + threadIdx.x, Wm, Whs);
        return;
    }
    const int t = threadIdx.x;
    const int node = blockIdx.x * 16 + (t >> 4);
    const int c = (t & 15) << 3;                    // 8 cols per lane
    int i = noff[node];
    const int end = noff[node + 1];
    float a[8];
    #pragma unroll
    for (int j = 0; j < 8; ++j) a[j] = 0.f;
    for (; i + 7 < end; i += 8) {
        const int s0 = esrc[i];     const int s1 = esrc[i + 1];
        const int s2 = esrc[i + 2]; const int s3 = esrc[i + 3];
        const int s4 = esrc[i + 4]; const int s5 = esrc[i + 5];
        const int s6 = esrc[i + 6]; const int s7 = esrc[i + 7];
        const u16x8 u0 = *reinterpret_cast<const u16x8*>(hs + s0 * D + c);
        const u16x8 u1 = *reinterpret_cast<const u16x8*>(hs + s1 * D + c);
        const u16x8 u2 = *reinterpret_cast<const u16x8*>(hs + s2 * D + c);
        const u16x8 u3 = *reinterpret_cast<const u16x8*>(hs + s3 * D + c);
        const u16x8 u4 = *reinterpret_cast<const u16x8*>(hs + s4 * D + c);
        const u16x8 u5 = *reinterpret_cast<const u16x8*>(hs + s5 * D + c);
        const u16x8 u6 = *reinterpret_cast<const u16x8*>(hs + s6 * D + c);
        const u16x8 u7 = *reinterpret_cast<const u16x8*>(hs + s7 * D + c);
        #pragma unroll
        for (int j = 0; j < 8; ++j) {
            a[j] += __uint_as_float((unsigned int)u0[j] << 16);
            a[j] += __uint_as_float((unsigned int)u1[j] << 16);
            a[j] += __uint_as_float((unsigned int)u2[j] << 16);
            a[j] += __uint_as_float((unsigned int)u3[j] << 16);
            a[j] += __uint_as_float((unsigned int)u4[j] << 16);
            a[j] += __uint_as_float((unsigned int)u5[j] << 16);
            a[j] += __uint_as_float((unsigned int)u6[j] << 16);
            a[j] += __uint_as_float((unsigned int)u7[j] << 16);
        }
    }
    if (i + 3 < end) {
        const int s0 = esrc[i];     const int s1 = esrc[i + 1];
        const int s2 = esrc[i + 2]; const int s3 = esrc[i + 3];
        const u16x8 u0 = *reinterpret_cast<const u16x8*>(hs + s0 * D + c);
        const u16x8 u1 = *reinterpret_cast<const u16x8*>(hs + s1 * D + c);
        const u16x8 u2 = *reinterpret_cast<const u16x8*>(hs + s2 * D + c);
        const u16x8 u3 = *reinterpret_cast<const u16x8*>(hs + s3 * D + c);
        #pragma unroll
        for (int j = 0; j < 8; ++j) {
            a[j] += __uint_as_float((unsigned int)u0[j] << 16);
            a[j] += __uint_as_float((unsigned int)u1[j] << 16);
            a[j] += __uint_as_float((unsigned int)u2[j] << 16);
            a[j] += __uint_as_float((unsigned int)u3[j] << 16);
        }
        i += 4;
    }
    for (; i < end; ++i) {
        const int s = esrc[i];
        const u16x8 u = *reinterpret_cast<const u16x8*>(hs + s * D + c);
        #pragma unroll
        for (int j = 0; j < 8; ++j)
            a[j] += __uint_as_float((unsigned int)u[j] << 16);
    }
    f16x8 o;
    #pragma unroll
    for (int j = 0; j < 8; ++j) o[j] = (_Float16)a[j];
    *reinterpret_cast<f16x8*>(g16 + node * GROW16 + c) = o;
}

// ======================= MFMA GEMM + epilogue (full tier, f16 g) =======================
__global__ __launch_bounds__(256) void gemm_mfma_f16g(
    const _Float16* g16, float* out, const f16x8* __restrict__ Whs,
    const float* __restrict__ bias, const float* __restrict__ norm)
{
    __shared__ f16x8 Wlds[2048];           // 32 KB
    const int t = threadIdx.x;
    const int row0 = blockIdx.x * 64;

    #pragma unroll
    for (int p = 0; p < 8; ++p)
        reinterpret_cast<float4*>(Wlds)[p * 256 + t] =
            reinterpret_cast<const float4*>(Whs)[p * 256 + t];
    __syncthreads();

    const int lane = t & 63;
    const int strip = t >> 6;
    const int q = lane >> 4;
    const int l15 = lane & 15;

    int mrow = row0 + strip * 16 + l15;
    if (mrow >= N_NODES) mrow = N_NODES - 1;

    f32x4 acc[8];
    #pragma unroll
    for (int i = 0; i < 8; ++i) acc[i] = (f32x4){0.f, 0.f, 0.f, 0.f};

    #pragma unroll
    for (int kiter = 0; kiter < 4; ++kiter) {
        const f16x8 a =
            *reinterpret_cast<const f16x8*>(g16 + mrow * GROW16 + kiter * 32 + q * 8);
        #pragma unroll
        for (int nt = 0; nt < 8; ++nt) {
            const f16x8 b = Wlds[(kiter * 8 + nt) * 64 + lane];
            acc[nt] = __builtin_amdgcn_mfma_f32_16x16x32_f16(a, b, acc[nt], 0, 0, 0);
        }
    }

    // all f16 A-reads of this block's slab must complete before fp32 overwrite
    __syncthreads();

    float nrm[4];
    int mr[4];
    #pragma unroll
    for (int rgi = 0; rgi < 4; ++rgi) {
        mr[rgi] = row0 + strip * 16 + q * 4 + rgi;
        nrm[rgi] = (mr[rgi] < N_NODES) ? norm[mr[rgi]] : 0.f;
    }
    #pragma unroll
    for (int nt = 0; nt < 8; ++nt) {
        const int col = nt * 16 + l15;
        const float bc = bias[col];
        #pragma unroll
        for (int rgi = 0; rgi < 4; ++rgi) {
            if (mr[rgi] < N_NODES) {
                float v = acc[nt][rgi] * nrm[rgi] + bc;
                v = v > 0.f ? v : 0.2f * v;
                out[mr[rgi] * D + col] = v;
            }
        }
    }
}

// ======================= gather (fp32, mid tier) + fused wprep =======================
__global__ __launch_bounds__(256) void gather_fp32(const float* __restrict__ h,
                                                   const float* __restrict__ norm,
                                                   const int* __restrict__ noff,
                                                   const int* __restrict__ esrc,
                                                   float* __restrict__ g,
                                                   const float* __restrict__ Wm,
                                                   f16x8* __restrict__ Whs) {
    if ((int)blockIdx.x >= GATH32_NBLK) {
        wprep_body((blockIdx.x - GATH32_NBLK) * 256 + threadIdx.x, Wm, Whs);
        return;
    }
    const int t = threadIdx.x;
    const int node = blockIdx.x * 8 + (t >> 5);
    const int c = (t & 31) << 2;
    const int beg = noff[node];
    const int end = noff[node + 1];
    float4 acc = make_float4(0.f, 0.f, 0.f, 0.f);
    for (int i = beg; i < end; ++i) {
        const int s = esrc[i];
        const float nv = norm[s];
        const float4 hv = *reinterpret_cast<const float4*>(h + s * D + c);
        acc.x += hv.x * nv;
        acc.y += hv.y * nv;
        acc.z += hv.z * nv;
        acc.w += hv.w * nv;
    }
    *reinterpret_cast<float4*>(g + node * D + c) = acc;
}

// ======================= tier-0 fallback: atomic scatter =======================
__global__ __launch_bounds__(256) void scatter_kernel(
    const float* __restrict__ h, const float* __restrict__ norm,
    const int* __restrict__ src, const int* __restrict__ dst,
    float* __restrict__ g)
{
    const int idx = blockIdx.x * 256 + threadIdx.x;
    const int e = idx >> 5;
    const int c = (idx & 31) << 2;
    const int s = src[e];
    const int d = dst[e];
    const float nv = norm[s];
    const float4 hv = *reinterpret_cast<const float4*>(h + s * D + c);
    float* gp = g + d * D + c;
    atomicAdd(gp + 0, hv.x * nv);
    atomicAdd(gp + 1, hv.y * nv);
    atomicAdd(gp + 2, hv.z * nv);
    atomicAdd(gp + 3, hv.w * nv);
}

// ======================= MFMA GEMM + epilogue (mid tier, fp32 g in out) =======================
__global__ __launch_bounds__(256) void gemm_mfma(
    float* __restrict__ out, const f16x8* __restrict__ Whs,
    const float* __restrict__ bias, const float* __restrict__ norm)
{
    __shared__ f16x8 Wlds[2048];           // 32 KB
    const int t = threadIdx.x;
    const int row0 = blockIdx.x * 64;

    #pragma unroll
    for (int p = 0; p < 8; ++p)
        reinterpret_cast<float4*>(Wlds)[p * 256 + t] =
            reinterpret_cast<const float4*>(Whs)[p * 256 + t];
    __syncthreads();

    const int lane = t & 63;
    const int strip = t >> 6;
    const int q = lane >> 4;
    const int l15 = lane & 15;

    int mrow = row0 + strip * 16 + l15;
    if (mrow >= N_NODES) mrow = N_NODES - 1;

    f32x4 acc[8];
    #pragma unroll
    for (int i = 0; i < 8; ++i) acc[i] = (f32x4){0.f, 0.f, 0.f, 0.f};

    #pragma unroll
    for (int kiter = 0; kiter < 4; ++kiter) {
        const float* gp = out + mrow * D + kiter * 32 + q * 8;
        const float4 ga = *reinterpret_cast<const float4*>(gp);
        const float4 gb = *reinterpret_cast<const float4*>(gp + 4);
        f16x8 a;
        a[0] = (_Float16)ga.x; a[1] = (_Float16)ga.y;
        a[2] = (_Float16)ga.z; a[3] = (_Float16)ga.w;
        a[4] = (_Float16)gb.x; a[5] = (_Float16)gb.y;
        a[6] = (_Float16)gb.z; a[7] = (_Float16)gb.w;
        #pragma unroll
        for (int nt = 0; nt < 8; ++nt) {
            const f16x8 b = Wlds[(kiter * 8 + nt) * 64 + lane];
            acc[nt] = __builtin_amdgcn_mfma_f32_16x16x32_f16(a, b, acc[nt], 0, 0, 0);
        }
    }

    float nrm[4];
    int mr[4];
    #pragma unroll
    for (int rgi = 0; rgi < 4; ++rgi) {
        mr[rgi] = row0 + strip * 16 + q * 4 + rgi;
        nrm[rgi] = (mr[rgi] < N_NODES) ? norm[mr[rgi]] : 0.f;
    }
    #pragma unroll
    for (int nt = 0; nt < 8; ++nt) {
        const int col = nt * 16 + l15;
        const float bc = bias[col];
        #pragma unroll
        for (int rgi = 0; rgi < 4; ++rgi) {
            if (mr[rgi] < N_NODES) {
                float v = acc[nt][rgi] * nrm[rgi] + bc;
                v = v > 0.f ? v : 0.2f * v;
                out[mr[rgi] * D + col] = v;
            }
        }
    }
}

// ======================= fp32 GEMM (tier-0 fallback only) =======================
__global__ __launch_bounds__(256) void gemm_epilogue(
    float* __restrict__ out, const float* __restrict__ Wm,
    const float* __restrict__ bias, const float* __restrict__ norm)
{
    __shared__ float gs[GROWS][D + 4];
    __shared__ float Wlds[KCH][D];
    const int t = threadIdx.x;
    const int row0 = blockIdx.x * GROWS;

    #pragma unroll
    for (int p = 0; p < 8; ++p) {
        const int i = p * 256 + t;
        const int r = i >> 5;
        const int c = (i & 31) << 2;
        int gr = row0 + r;
        if (gr >= N_NODES) gr = N_NODES - 1;
        const float4 v = *reinterpret_cast<const float4*>(out + gr * D + c);
        *reinterpret_cast<float4*>(&gs[r][c]) = v;
    }

    const int rg = (t >> 5) * 8;
    const int cb = (t & 31) << 2;

    float4 acc[8];
    #pragma unroll
    for (int i = 0; i < 8; ++i) acc[i] = make_float4(0.f, 0.f, 0.f, 0.f);

    for (int kc = 0; kc < D; kc += KCH) {
        __syncthreads();
        #pragma unroll
        for (int p = 0; p < 4; ++p) {
            const int i = p * 256 + t;
            const int kk = i >> 5;
            const int c = (i & 31) << 2;
            *reinterpret_cast<float4*>(&Wlds[kk][c]) =
                *reinterpret_cast<const float4*>(Wm + (kc + kk) * D + c);
        }
        __syncthreads();

        #pragma unroll
        for (int k4 = 0; k4 < KCH; k4 += 4) {
            float4 wv[4];
            #pragma unroll
            for (int kk = 0; kk < 4; ++kk)
                wv[kk] = *reinterpret_cast<const float4*>(&Wlds[k4 + kk][cb]);
            #pragma unroll
            for (int i = 0; i < 8; ++i) {
                const float4 gv = *reinterpret_cast<const float4*>(&gs[rg + i][kc + k4]);
                acc[i].x += gv.x * wv[0].x; acc[i].y += gv.x * wv[0].y;
                acc[i].z += gv.x * wv[0].z; acc[i].w += gv.x * wv[0].w;
                acc[i].x += gv.y * wv[1].x; acc[i].y += gv.y * wv[1].y;
                acc[i].z += gv.y * wv[1].z; acc[i].w += gv.y * wv[1].w;
                acc[i].x += gv.z * wv[2].x; acc[i].y += gv.z * wv[2].y;
                acc[i].z += gv.z * wv[2].z; acc[i].w += gv.z * wv[2].w;
                acc[i].x += gv.w * wv[3].x; acc[i].y += gv.w * wv[3].y;
                acc[i].z += gv.w * wv[3].z; acc[i].w += gv.w * wv[3].w;
            }
        }
    }

    const float4 b = *reinterpret_cast<const float4*>(bias + cb);
    #pragma unroll
    for (int i = 0; i < 8; ++i) {
        const int gr = row0 + rg + i;
        if (gr < N_NODES) {
            const float nv = norm[gr];
            float4 v;
            v.x = acc[i].x * nv + b.x;
            v.y = acc[i].y * nv + b.y;
            v.z = acc[i].z * nv + b.z;
            v.w = acc[i].w * nv + b.w;
            v.x = v.x > 0.f ? v.x : 0.2f * v.x;
            v.y = v.y > 0.f ? v.y : 0.2f * v.y;
            v.z = v.z > 0.f ? v.z : 0.2f * v.z;
            v.w = v.w > 0.f ? v.w : 0.2f * v.w;
            *reinterpret_cast<float4*>(out + gr * D + cb) = v;
        }
    }
}

extern "C" void kernel_launch(void* const* d_in, const int* in_sizes, int n_in,
                              void* d_out, int out_size, void* d_ws, size_t ws_size,
                              hipStream_t stream) {
    const float* h    = (const float*)d_in[0];
    const float* norm = (const float*)d_in[1];
    const float* Wm   = (const float*)d_in[2];
    const float* bias = (const float*)d_in[3];
    const int*   src  = (const int*)d_in[4];
    const int*   dst  = (const int*)d_in[5];
    float* out = (float*)d_out;
    int* ws = (int*)d_ws;

    if (ws_size >= WS_MID_INTS * 4) {
        int* cnt  = ws + WS_CNT;
        int* pos  = ws + WS_POS;
        int* boff = ws + WS_BOFF;
        int* noff = ws + WS_NOFF;
        int* ebuf = ws + WS_EBUF;
        int* esrc = ws + WS_ESRC;
        unsigned short* hs = (unsigned short*)(ws + WS_HS);
        f16x8* Whs = (f16x8*)ebuf;         // ebuf dead after bin_sort
        const bool use_bf16 = (ws_size >= WS_FULL_INTS * 4);

        if (use_bf16) {
            // ---- full tier: 6 dispatches ----
            hipMemsetAsync(cnt, 0, 2 * 784 * sizeof(int), stream);   // cnt + pos
            prep_count<<<PREP_NBLK + CNT_NBLK, 256, 0, stream>>>(h, norm, hs, dst, cnt, PREP_NBLK);
            scatter_scan<<<SCAT_NBLK, 1024, 0, stream>>>(src, dst, cnt, pos, boff, ebuf);
            bin_sort<<<NB, 256, 0, stream>>>(boff, ebuf, esrc, noff);
            _Float16* g16 = (_Float16*)out;
            gather_wprep<<<GATH_NBLK + 8, 256, 0, stream>>>(hs, noff, esrc, g16, Wm, Whs);
            gemm_mfma_f16g<<<(N_NODES + 63) / 64, 256, 0, stream>>>(g16, out, Whs, bias, norm);
        } else {
            // ---- mid tier: legacy proven chain ----
            hipMemsetAsync(cnt, 0, 784 * sizeof(int), stream);
            prep_count<<<CNT_NBLK, 256, 0, stream>>>(h, norm, (unsigned short*)ws, dst, cnt, 0);
            coarse_scan   <<<1, 1024, 0, stream>>>(cnt, boff, pos);
            coarse_scatter<<<SCAT_NBLK, 1024, 0, stream>>>(src, dst, pos, ebuf);
            bin_sort      <<<NB, 256, 0, stream>>>(boff, ebuf, esrc, noff);
            gather_fp32<<<GATH32_NBLK + 8, 256, 0, stream>>>(h, norm, noff, esrc, out, Wm, Whs);
            gemm_mfma<<<(N_NODES + 63) / 64, 256, 0, stream>>>(out, Whs, bias, norm);
        }
    } else {
        hipMemsetAsync(out, 0, (size_t)N_NODES * D * sizeof(float), stream);
        scatter_kernel<<<(E_EDGES * 32) / 256, 256, 0, stream>>>(h, norm, src, dst, out);
        gemm_epilogue<<<(N_NODES + GROWS - 1) / GROWS, 256, 0, stream>>>(out, Wm, bias, norm);
    }
}

// Round 8
// 233.999 us; speedup vs baseline: 2.5060x; 1.0110x over previous
//
#include <hip/hip_runtime.h>

#define N_NODES 100000
#define E_EDGES 1600000
#define D 128
#define SHIFT 7
#define BNODES 128
#define NB ((N_NODES + BNODES - 1) / BNODES)     // 782 bins

#define CNT_CHUNK 2048
#define CNT_NBLK ((E_EDGES + CNT_CHUNK - 1) / CNT_CHUNK)    // 782
#define PREP_NBLK (N_NODES * 32 / 256)                      // 12500
#define SCAT_CHUNK 8192
#define SCAT_PASS 2                                         // 8192 / (1024*4)
#define SCAT_NBLK ((E_EDGES + SCAT_CHUNK - 1) / SCAT_CHUNK) // 196
#define GATH_NBLK (N_NODES / 16)                            // 6250
#define GATH32_NBLK (N_NODES / 8)                           // 12500 (mid tier)

// per-node LDS list capacity in gather_direct (deg ~ Poisson(16); 96 = +20 sigma)
#define CAP_N 96
#define LSTR 97                                             // pad -> 16 distinct banks

// fp32-GEMM tiling (tier-0 fallback only)
#define GROWS 64
#define KCH 32

typedef _Float16       f16x8  __attribute__((ext_vector_type(8)));
typedef float          f32x4  __attribute__((ext_vector_type(4)));
typedef unsigned short u16x8  __attribute__((ext_vector_type(8)));

// ---- workspace layout (int units) ----
// cnt and pos are contiguous so one memset zeroes both (full tier).
#define WS_CNT   0                         // 784 slots
#define WS_POS   784                       // 784 slots
#define WS_BOFF  1568                      // 785 slots
#define WS_NOFF  2356                      // N+1 (mid tier only)
#define WS_EBUF  102400                    // E  (LIVE through gather_direct in full tier)
#define WS_ESRC  (102400 + E_EDGES)        // E  (full tier: first 8192 ints = Whs)
#define WS_HS    (102400 + 2 * E_EDGES)    // N*D/2 ints (bf16 h*norm)
#define WS_FULL_INTS ((size_t)WS_HS + (size_t)N_NODES * D / 2)
#define WS_MID_INTS  ((size_t)WS_HS)

// f16 g staging inside `out`: row r occupies the FIRST 256 B of row r's fp32
// slot. gemm blocks read only their own 64-row slab's f16 before overwriting
// that slab with fp32 (in-block __syncthreads between A-reads and stores).
#define GROW16 256                          // _Float16 elements per row slot

// ======================= fused prep + coarse count =======================
__global__ __launch_bounds__(256) void prep_count(const float* __restrict__ h,
                                                  const float* __restrict__ norm,
                                                  unsigned short* __restrict__ hs,
                                                  const int* __restrict__ dst,
                                                  int* __restrict__ cnt,
                                                  int prep_blocks) {
    __shared__ int hist[NB];
    const int t = threadIdx.x;
    if ((int)blockIdx.x < prep_blocks) {
        const int idx = blockIdx.x * 256 + t;
        const int node = idx >> 5;
        const int c = (idx & 31) << 2;
        const float nv = norm[node];
        const float4 v = *reinterpret_cast<const float4*>(h + node * D + c);
        float a[4] = {v.x * nv, v.y * nv, v.z * nv, v.w * nv};
        ushort4 o;
        unsigned short* op = reinterpret_cast<unsigned short*>(&o);
        #pragma unroll
        for (int i = 0; i < 4; ++i) {
            unsigned int u = __float_as_uint(a[i]);
            u += 0x7FFFu + ((u >> 16) & 1u);            // round-to-nearest-even
            op[i] = (unsigned short)(u >> 16);
        }
        *reinterpret_cast<ushort4*>(hs + node * D + c) = o;
        return;
    }
    const int cb = blockIdx.x - prep_blocks;
    const int e0 = cb * CNT_CHUNK;
    const int rem = (E_EDGES - e0 < CNT_CHUNK) ? (E_EDGES - e0) : CNT_CHUNK;
    for (int i = t; i < NB; i += 256) hist[i] = 0;
    __syncthreads();
    if (rem == CNT_CHUNK) {
        const int4* d4 = reinterpret_cast<const int4*>(dst + e0);
        #pragma unroll
        for (int p = 0; p < 2; ++p) {
            const int4 v = d4[p * 256 + t];
            atomicAdd(&hist[v.x >> SHIFT], 1);
            atomicAdd(&hist[v.y >> SHIFT], 1);
            atomicAdd(&hist[v.z >> SHIFT], 1);
            atomicAdd(&hist[v.w >> SHIFT], 1);
        }
    } else {
        for (int i = t; i < rem; i += 256)
            atomicAdd(&hist[dst[e0 + i] >> SHIFT], 1);
    }
    __syncthreads();
    for (int b = t; b < NB; b += 256) {
        const int c = hist[b];
        if (c) atomicAdd(&cnt[b], c);
    }
}

// ======================= scatter + inline scan (full tier) =======================
__global__ __launch_bounds__(1024) void scatter_scan(const int* __restrict__ src,
                                                     const int* __restrict__ dst,
                                                     const int* __restrict__ cnt,
                                                     int* __restrict__ pos,
                                                     int* __restrict__ boff,
                                                     int* __restrict__ ebuf) {
    __shared__ int buf[2][1024];
    __shared__ int hist[NB];
    const int t = threadIdx.x;

    // ---- inline exclusive scan of cnt[0..NB) ----
    const int v = (t < NB) ? cnt[t] : 0;
    int pi = 0;
    buf[0][t] = v;
    __syncthreads();
    #pragma unroll
    for (int o = 1; o < 1024; o <<= 1) {
        const int nv = buf[pi][t] + (t >= o ? buf[pi][t - o] : 0);
        buf[1 - pi][t] = nv;
        pi = 1 - pi;
        __syncthreads();
    }
    const int excl = buf[pi][t] - v;                 // exclusive prefix (t < NB valid)
    if (blockIdx.x == 0) {
        if (t < NB) boff[t] = excl;
        if (t == 0) boff[NB] = E_EDGES;
    }
    if (t < NB) hist[t] = 0;
    __syncthreads();

    // ---- count this chunk ----
    const int e0 = blockIdx.x * SCAT_CHUNK;
    const int rem = (E_EDGES - e0 < SCAT_CHUNK) ? (E_EDGES - e0) : SCAT_CHUNK;
    if (rem == SCAT_CHUNK) {
        const int4* d4 = reinterpret_cast<const int4*>(dst + e0);
        #pragma unroll
        for (int p = 0; p < SCAT_PASS; ++p) {
            const int4 vv = d4[p * 1024 + t];
            atomicAdd(&hist[vv.x >> SHIFT], 1);
            atomicAdd(&hist[vv.y >> SHIFT], 1);
            atomicAdd(&hist[vv.z >> SHIFT], 1);
            atomicAdd(&hist[vv.w >> SHIFT], 1);
        }
    } else {
        for (int i = t; i < rem; i += 1024)
            atomicAdd(&hist[dst[e0 + i] >> SHIFT], 1);
    }
    __syncthreads();

    // ---- claim global slots ----
    if (t < NB) {
        const int c = hist[t];
        if (c) hist[t] = excl + atomicAdd(&pos[t], c);
    }
    __syncthreads();

    // ---- scatter packed words ----
    if (rem == SCAT_CHUNK) {
        const int4* d4 = reinterpret_cast<const int4*>(dst + e0);
        const int4* s4 = reinterpret_cast<const int4*>(src + e0);
        #pragma unroll
        for (int p = 0; p < SCAT_PASS; ++p) {
            const int4 dv = d4[p * 1024 + t];
            const int4 sv = s4[p * 1024 + t];
            int pz;
            pz = atomicAdd(&hist[dv.x >> SHIFT], 1);
            ebuf[pz] = (sv.x << SHIFT) | (dv.x & (BNODES - 1));
            pz = atomicAdd(&hist[dv.y >> SHIFT], 1);
            ebuf[pz] = (sv.y << SHIFT) | (dv.y & (BNODES - 1));
            pz = atomicAdd(&hist[dv.z >> SHIFT], 1);
            ebuf[pz] = (sv.z << SHIFT) | (dv.z & (BNODES - 1));
            pz = atomicAdd(&hist[dv.w >> SHIFT], 1);
            ebuf[pz] = (sv.w << SHIFT) | (dv.w & (BNODES - 1));
        }
    } else {
        for (int i = t; i < rem; i += 1024) {
            const int d = dst[e0 + i];
            const int b = d >> SHIFT;
            const int p = atomicAdd(&hist[b], 1);
            ebuf[p] = (src[e0 + i] << SHIFT) | (d & (BNODES - 1));
        }
    }
}

// ======================= wprep body (shared) =======================
__device__ __forceinline__ void wprep_body(int tid, const float* __restrict__ Wm,
                                           f16x8* __restrict__ Whs) {
    const int kiter = tid >> 9;
    const int nt = (tid >> 6) & 7;
    const int lane = tid & 63;
    const int q = lane >> 4;
    const int col = nt * 16 + (lane & 15);
    f16x8 v;
    #pragma unroll
    for (int j = 0; j < 8; ++j)
        v[j] = (_Float16)Wm[(kiter * 32 + q * 8 + j) * D + col];
    Whs[tid] = v;
}

// ======================= gather DIRECT from bin segments (full tier) =========
// One block per 16 nodes. bin = g>>3, sub = g&7. Phase 1: stream the bin's
// contiguous ebuf segment (coalesced), filter the 1/8 of edges whose local dst
// belongs to this block, push src ids into per-node LDS lists ([16][97] pad ->
// conflict-free broadcast reads). Phase 2: the proven 8-deep gather inner loop
// with edge indices from LDS. Deletes bin_sort + esrc/noff entirely.
// HARDENED: b0/b1 clamped to [0,E]; src validated (< N) at push time and in
// the fallback -> no wild address is reachable even from corrupt metadata.
__global__ __launch_bounds__(256) void gather_direct(
    const unsigned short* __restrict__ hs, const int* __restrict__ boff,
    const int* __restrict__ ebuf, _Float16* __restrict__ g16,
    const float* __restrict__ Wm, f16x8* __restrict__ Whs)
{
    if ((int)blockIdx.x >= GATH_NBLK) {
        wprep_body((blockIdx.x - GATH_NBLK) * 256 + threadIdx.x, Wm, Whs);
        return;
    }
    __shared__ int lists[16][LSTR];
    __shared__ int lcnt[16];
    const int t = threadIdx.x;
    const int g = blockIdx.x;
    const int bin = g >> 3;
    const int sub = g & 7;
    if (t < 16) lcnt[t] = 0;
    __syncthreads();
    int b0 = boff[bin];
    int b1 = boff[bin + 1];
    b0 = (b0 < 0) ? 0 : ((b0 > E_EDGES) ? E_EDGES : b0);
    b1 = (b1 < b0) ? b0 : ((b1 > E_EDGES) ? E_EDGES : b1);
    for (int i = b0 + t; i < b1; i += 256) {
        const int w = ebuf[i];
        const int l = w & (BNODES - 1);
        const unsigned s = (unsigned)w >> SHIFT;     // src (w >= 0: src < 2^17)
        if ((l >> 4) == sub && s < (unsigned)N_NODES) {
            const int p = atomicAdd(&lcnt[l & 15], 1);
            if (p < CAP_N) lists[l & 15][p] = (int)s;
        }
    }
    __syncthreads();

    const int grp = t >> 4;
    const int c = (t & 15) << 3;                    // 8 cols per lane
    const int node = g * 16 + grp;
    const int deg = lcnt[grp];
    float a[8];
    #pragma unroll
    for (int j = 0; j < 8; ++j) a[j] = 0.f;

    if (deg <= CAP_N) {
        const int* lp = lists[grp];
        int i = 0;
        for (; i + 7 < deg; i += 8) {
            const int s0 = lp[i];     const int s1 = lp[i + 1];
            const int s2 = lp[i + 2]; const int s3 = lp[i + 3];
            const int s4 = lp[i + 4]; const int s5 = lp[i + 5];
            const int s6 = lp[i + 6]; const int s7 = lp[i + 7];
            const u16x8 u0 = *reinterpret_cast<const u16x8*>(hs + s0 * D + c);
            const u16x8 u1 = *reinterpret_cast<const u16x8*>(hs + s1 * D + c);
            const u16x8 u2 = *reinterpret_cast<const u16x8*>(hs + s2 * D + c);
            const u16x8 u3 = *reinterpret_cast<const u16x8*>(hs + s3 * D + c);
            const u16x8 u4 = *reinterpret_cast<const u16x8*>(hs + s4 * D + c);
            const u16x8 u5 = *reinterpret_cast<const u16x8*>(hs + s5 * D + c);
            const u16x8 u6 = *reinterpret_cast<const u16x8*>(hs + s6 * D + c);
            const u16x8 u7 = *reinterpret_cast<const u16x8*>(hs + s7 * D + c);
            #pragma unroll
            for (int j = 0; j < 8; ++j) {
                a[j] += __uint_as_float((unsigned int)u0[j] << 16);
                a[j] += __uint_as_float((unsigned int)u1[j] << 16);
                a[j] += __uint_as_float((unsigned int)u2[j] << 16);
                a[j] += __uint_as_float((unsigned int)u3[j] << 16);
                a[j] += __uint_as_float((unsigned int)u4[j] << 16);
                a[j] += __uint_as_float((unsigned int)u5[j] << 16);
                a[j] += __uint_as_float((unsigned int)u6[j] << 16);
                a[j] += __uint_as_float((unsigned int)u7[j] << 16);
            }
        }
        if (i + 3 < deg) {
            const int s0 = lp[i];     const int s1 = lp[i + 1];
            const int s2 = lp[i + 2]; const int s3 = lp[i + 3];
            const u16x8 u0 = *reinterpret_cast<const u16x8*>(hs + s0 * D + c);
            const u16x8 u1 = *reinterpret_cast<const u16x8*>(hs + s1 * D + c);
            const u16x8 u2 = *reinterpret_cast<const u16x8*>(hs + s2 * D + c);
            const u16x8 u3 = *reinterpret_cast<const u16x8*>(hs + s3 * D + c);
            #pragma unroll
            for (int j = 0; j < 8; ++j) {
                a[j] += __uint_as_float((unsigned int)u0[j] << 16);
                a[j] += __uint_as_float((unsigned int)u1[j] << 16);
                a[j] += __uint_as_float((unsigned int)u2[j] << 16);
                a[j] += __uint_as_float((unsigned int)u3[j] << 16);
            }
            i += 4;
        }
        for (; i < deg; ++i) {
            const int s = lp[i];
            const u16x8 u = *reinterpret_cast<const u16x8*>(hs + s * D + c);
            #pragma unroll
            for (int j = 0; j < 8; ++j)
                a[j] += __uint_as_float((unsigned int)u[j] << 16);
        }
    } else {
        // ultra-rare overflow fallback: scan bin segment for my node's edges
        const int myl = (sub << 4) | grp;
        for (int i = b0; i < b1; ++i) {
            const int w = ebuf[i];
            const unsigned s = (unsigned)w >> SHIFT;
            if ((w & (BNODES - 1)) == myl && s < (unsigned)N_NODES) {
                const u16x8 u = *reinterpret_cast<const u16x8*>(hs + s * D + c);
                #pragma unroll
                for (int j = 0; j < 8; ++j)
                    a[j] += __uint_as_float((unsigned int)u[j] << 16);
            }
        }
    }

    f16x8 o;
    #pragma unroll
    for (int j = 0; j < 8; ++j) o[j] = (_Float16)a[j];
    *reinterpret_cast<f16x8*>(g16 + node * GROW16 + c) = o;
}

// ======================= MFMA GEMM + epilogue (full tier, f16 g) =======================
__global__ __launch_bounds__(256) void gemm_mfma_f16g(
    const _Float16* g16, float* out, const f16x8* __restrict__ Whs,
    const float* __restrict__ bias, const float* __restrict__ norm)
{
    __shared__ f16x8 Wlds[2048];           // 32 KB
    const int t = threadIdx.x;
    const int row0 = blockIdx.x * 64;

    #pragma unroll
    for (int p = 0; p < 8; ++p)
        reinterpret_cast<float4*>(Wlds)[p * 256 + t] =
            reinterpret_cast<const float4*>(Whs)[p * 256 + t];
    __syncthreads();

    const int lane = t & 63;
    const int strip = t >> 6;
    const int q = lane >> 4;
    const int l15 = lane & 15;

    int mrow = row0 + strip * 16 + l15;
    if (mrow >= N_NODES) mrow = N_NODES - 1;

    f32x4 acc[8];
    #pragma unroll
    for (int i = 0; i < 8; ++i) acc[i] = (f32x4){0.f, 0.f, 0.f, 0.f};

    #pragma unroll
    for (int kiter = 0; kiter < 4; ++kiter) {
        const f16x8 a =
            *reinterpret_cast<const f16x8*>(g16 + mrow * GROW16 + kiter * 32 + q * 8);
        #pragma unroll
        for (int nt = 0; nt < 8; ++nt) {
            const f16x8 b = Wlds[(kiter * 8 + nt) * 64 + lane];
            acc[nt] = __builtin_amdgcn_mfma_f32_16x16x32_f16(a, b, acc[nt], 0, 0, 0);
        }
    }

    // all f16 A-reads of this block's slab must complete before fp32 overwrite
    __syncthreads();

    float nrm[4];
    int mr[4];
    #pragma unroll
    for (int rgi = 0; rgi < 4; ++rgi) {
        mr[rgi] = row0 + strip * 16 + q * 4 + rgi;
        nrm[rgi] = (mr[rgi] < N_NODES) ? norm[mr[rgi]] : 0.f;
    }
    #pragma unroll
    for (int nt = 0; nt < 8; ++nt) {
        const int col = nt * 16 + l15;
        const float bc = bias[col];
        #pragma unroll
        for (int rgi = 0; rgi < 4; ++rgi) {
            if (mr[rgi] < N_NODES) {
                float v = acc[nt][rgi] * nrm[rgi] + bc;
                v = v > 0.f ? v : 0.2f * v;
                out[mr[rgi] * D + col] = v;
            }
        }
    }
}

// ======================= mid-tier legacy chain (unchanged, proven) ===========
__global__ __launch_bounds__(1024) void coarse_scan(const int* __restrict__ cnt,
                                                    int* __restrict__ boff,
                                                    int* __restrict__ pos) {
    __shared__ int buf[2][1024];
    const int t = threadIdx.x;
    const int v = (t < NB) ? cnt[t] : 0;
    int pi = 0;
    buf[0][t] = v;
    __syncthreads();
    #pragma unroll
    for (int o = 1; o < 1024; o <<= 1) {
        const int nv = buf[pi][t] + (t >= o ? buf[pi][t - o] : 0);
        buf[1 - pi][t] = nv;
        pi = 1 - pi;
        __syncthreads();
    }
    if (t < NB) {
        const int excl = buf[pi][t] - v;
        boff[t] = excl;
        pos[t] = excl;
    }
    if (t == 0) boff[NB] = E_EDGES;
}

__global__ __launch_bounds__(1024) void coarse_scatter(const int* __restrict__ src,
                                                       const int* __restrict__ dst,
                                                       int* __restrict__ pos,
                                                       int* __restrict__ ebuf) {
    __shared__ int hist[NB];
    const int t = threadIdx.x;
    const int e0 = blockIdx.x * SCAT_CHUNK;
    const int rem = (E_EDGES - e0 < SCAT_CHUNK) ? (E_EDGES - e0) : SCAT_CHUNK;
    for (int i = t; i < NB; i += 1024) hist[i] = 0;
    __syncthreads();
    if (rem == SCAT_CHUNK) {
        const int4* d4 = reinterpret_cast<const int4*>(dst + e0);
        #pragma unroll
        for (int p = 0; p < SCAT_PASS; ++p) {
            const int4 v = d4[p * 1024 + t];
            atomicAdd(&hist[v.x >> SHIFT], 1);
            atomicAdd(&hist[v.y >> SHIFT], 1);
            atomicAdd(&hist[v.z >> SHIFT], 1);
            atomicAdd(&hist[v.w >> SHIFT], 1);
        }
    } else {
        for (int i = t; i < rem; i += 1024)
            atomicAdd(&hist[dst[e0 + i] >> SHIFT], 1);
    }
    __syncthreads();
    for (int b = t; b < NB; b += 1024) {
        const int c = hist[b];
        if (c) hist[b] = atomicAdd(&pos[b], c);
    }
    __syncthreads();
    if (rem == SCAT_CHUNK) {
        const int4* d4 = reinterpret_cast<const int4*>(dst + e0);
        const int4* s4 = reinterpret_cast<const int4*>(src + e0);
        #pragma unroll
        for (int p = 0; p < SCAT_PASS; ++p) {
            const int4 dv = d4[p * 1024 + t];
            const int4 sv = s4[p * 1024 + t];
            int pz;
            pz = atomicAdd(&hist[dv.x >> SHIFT], 1);
            ebuf[pz] = (sv.x << SHIFT) | (dv.x & (BNODES - 1));
            pz = atomicAdd(&hist[dv.y >> SHIFT], 1);
            ebuf[pz] = (sv.y << SHIFT) | (dv.y & (BNODES - 1));
            pz = atomicAdd(&hist[dv.z >> SHIFT], 1);
            ebuf[pz] = (sv.z << SHIFT) | (dv.z & (BNODES - 1));
            pz = atomicAdd(&hist[dv.w >> SHIFT], 1);
            ebuf[pz] = (sv.w << SHIFT) | (dv.w & (BNODES - 1));
        }
    } else {
        for (int i = t; i < rem; i += 1024) {
            const int d = dst[e0 + i];
            const int b = d >> SHIFT;
            const int p = atomicAdd(&hist[b], 1);
            ebuf[p] = (src[e0 + i] << SHIFT) | (d & (BNODES - 1));
        }
    }
}

__global__ __launch_bounds__(256) void bin_sort(const int* __restrict__ boff,
                                                const int* __restrict__ ebuf,
                                                int* __restrict__ esrc,
                                                int* __restrict__ noff) {
    __shared__ int hist[BNODES];
    __shared__ int curs[BNODES];
    __shared__ int sbuf[2][BNODES];
    const int t = threadIdx.x;
    const int bin = blockIdx.x;
    if (t < BNODES) hist[t] = 0;
    __syncthreads();
    const int b0 = boff[bin];
    const int b1 = boff[bin + 1];
    for (int i = b0 + t; i < b1; i += 256)
        atomicAdd(&hist[ebuf[i] & (BNODES - 1)], 1);
    __syncthreads();
    if (t < BNODES) sbuf[0][t] = hist[t];
    __syncthreads();
    int pi = 0;
    #pragma unroll
    for (int o = 1; o < BNODES; o <<= 1) {
        if (t < BNODES)
            sbuf[1 - pi][t] = sbuf[pi][t] + (t >= o ? sbuf[pi][t - o] : 0);
        pi = 1 - pi;
        __syncthreads();
    }
    if (t < BNODES) {
        const int base = b0 + sbuf[pi][t] - hist[t];
        curs[t] = base;
        const int node = (bin << SHIFT) + t;
        if (node < N_NODES) noff[node] = base;
    }
    if (bin == 0 && t == 0) noff[N_NODES] = E_EDGES;
    __syncthreads();
    for (int i = b0 + t; i < b1; i += 256) {
        const int w = ebuf[i];
        const int p = atomicAdd(&curs[w & (BNODES - 1)], 1);
        esrc[p] = w >> SHIFT;
    }
}

__global__ __launch_bounds__(256) void gather_fp32(const float* __restrict__ h,
                                                   const float* __restrict__ norm,
                                                   const int* __restrict__ noff,
                                                   const int* __restrict__ esrc,
                                                   float* __restrict__ g,
                                                   const float* __restrict__ Wm,
                                                   f16x8* __restrict__ Whs) {
    if ((int)blockIdx.x >= GATH32_NBLK) {
        wprep_body((blockIdx.x - GATH32_NBLK) * 256 + threadIdx.x, Wm, Whs);
        return;
    }
    const int t = threadIdx.x;
    const int node = blockIdx.x * 8 + (t >> 5);
    const int c = (t & 31) << 2;
    const int beg = noff[node];
    const int end = noff[node + 1];
    float4 acc = make_float4(0.f, 0.f, 0.f, 0.f);
    for (int i = beg; i < end; ++i) {
        const int s = esrc[i];
        const float nv = norm[s];
        const float4 hv = *reinterpret_cast<const float4*>(h + s * D + c);
        acc.x += hv.x * nv;
        acc.y += hv.y * nv;
        acc.z += hv.z * nv;
        acc.w += hv.w * nv;
    }
    *reinterpret_cast<float4*>(g + node * D + c) = acc;
}

__global__ __launch_bounds__(256) void scatter_kernel(
    const float* __restrict__ h, const float* __restrict__ norm,
    const int* __restrict__ src, const int* __restrict__ dst,
    float* __restrict__ g)
{
    const int idx = blockIdx.x * 256 + threadIdx.x;
    const int e = idx >> 5;
    const int c = (idx & 31) << 2;
    const int s = src[e];
    const int d = dst[e];
    const float nv = norm[s];
    const float4 hv = *reinterpret_cast<const float4*>(h + s * D + c);
    float* gp = g + d * D + c;
    atomicAdd(gp + 0, hv.x * nv);
    atomicAdd(gp + 1, hv.y * nv);
    atomicAdd(gp + 2, hv.z * nv);
    atomicAdd(gp + 3, hv.w * nv);
}

__global__ __launch_bounds__(256) void gemm_mfma(
    float* __restrict__ out, const f16x8* __restrict__ Whs,
    const float* __restrict__ bias, const float* __restrict__ norm)
{
    __shared__ f16x8 Wlds[2048];           // 32 KB
    const int t = threadIdx.x;
    const int row0 = blockIdx.x * 64;

    #pragma unroll
    for (int p = 0; p < 8; ++p)
        reinterpret_cast<float4*>(Wlds)[p * 256 + t] =
            reinterpret_cast<const float4*>(Whs)[p * 256 + t];
    __syncthreads();

    const int lane = t & 63;
    const int strip = t >> 6;
    const int q = lane >> 4;
    const int l15 = lane & 15;

    int mrow = row0 + strip * 16 + l15;
    if (mrow >= N_NODES) mrow = N_NODES - 1;

    f32x4 acc[8];
    #pragma unroll
    for (int i = 0; i < 8; ++i) acc[i] = (f32x4){0.f, 0.f, 0.f, 0.f};

    #pragma unroll
    for (int kiter = 0; kiter < 4; ++kiter) {
        const float* gp = out + mrow * D + kiter * 32 + q * 8;
        const float4 ga = *reinterpret_cast<const float4*>(gp);
        const float4 gb = *reinterpret_cast<const float4*>(gp + 4);
        f16x8 a;
        a[0] = (_Float16)ga.x; a[1] = (_Float16)ga.y;
        a[2] = (_Float16)ga.z; a[3] = (_Float16)ga.w;
        a[4] = (_Float16)gb.x; a[5] = (_Float16)gb.y;
        a[6] = (_Float16)gb.z; a[7] = (_Float16)gb.w;
        #pragma unroll
        for (int nt = 0; nt < 8; ++nt) {
            const f16x8 b = Wlds[(kiter * 8 + nt) * 64 + lane];
            acc[nt] = __builtin_amdgcn_mfma_f32_16x16x32_f16(a, b, acc[nt], 0, 0, 0);
        }
    }

    float nrm[4];
    int mr[4];
    #pragma unroll
    for (int rgi = 0; rgi < 4; ++rgi) {
        mr[rgi] = row0 + strip * 16 + q * 4 + rgi;
        nrm[rgi] = (mr[rgi] < N_NODES) ? norm[mr[rgi]] : 0.f;
    }
    #pragma unroll
    for (int nt = 0; nt < 8; ++nt) {
        const int col = nt * 16 + l15;
        const float bc = bias[col];
        #pragma unroll
        for (int rgi = 0; rgi < 4; ++rgi) {
            if (mr[rgi] < N_NODES) {
                float v = acc[nt][rgi] * nrm[rgi] + bc;
                v = v > 0.f ? v : 0.2f * v;
                out[mr[rgi] * D + col] = v;
            }
        }
    }
}

__global__ __launch_bounds__(256) void gemm_epilogue(
    float* __restrict__ out, const float* __restrict__ Wm,
    const float* __restrict__ bias, const float* __restrict__ norm)
{
    __shared__ float gs[GROWS][D + 4];
    __shared__ float Wlds[KCH][D];
    const int t = threadIdx.x;
    const int row0 = blockIdx.x * GROWS;

    #pragma unroll
    for (int p = 0; p < 8; ++p) {
        const int i = p * 256 + t;
        const int r = i >> 5;
        const int c = (i & 31) << 2;
        int gr = row0 + r;
        if (gr >= N_NODES) gr = N_NODES - 1;
        const float4 v = *reinterpret_cast<const float4*>(out + gr * D + c);
        *reinterpret_cast<float4*>(&gs[r][c]) = v;
    }

    const int rg = (t >> 5) * 8;
    const int cb = (t & 31) << 2;

    float4 acc[8];
    #pragma unroll
    for (int i = 0; i < 8; ++i) acc[i] = make_float4(0.f, 0.f, 0.f, 0.f);

    for (int kc = 0; kc < D; kc += KCH) {
        __syncthreads();
        #pragma unroll
        for (int p = 0; p < 4; ++p) {
            const int i = p * 256 + t;
            const int kk = i >> 5;
            const int c = (i & 31) << 2;
            *reinterpret_cast<float4*>(&Wlds[kk][c]) =
                *reinterpret_cast<const float4*>(Wm + (kc + kk) * D + c);
        }
        __syncthreads();

        #pragma unroll
        for (int k4 = 0; k4 < KCH; k4 += 4) {
            float4 wv[4];
            #pragma unroll
            for (int kk = 0; kk < 4; ++kk)
                wv[kk] = *reinterpret_cast<const float4*>(&Wlds[k4 + kk][cb]);
            #pragma unroll
            for (int i = 0; i < 8; ++i) {
                const float4 gv = *reinterpret_cast<const float4*>(&gs[rg + i][kc + k4]);
                acc[i].x += gv.x * wv[0].x; acc[i].y += gv.x * wv[0].y;
                acc[i].z += gv.x * wv[0].z; acc[i].w += gv.x * wv[0].w;
                acc[i].x += gv.y * wv[1].x; acc[i].y += gv.y * wv[1].y;
                acc[i].z += gv.y * wv[1].z; acc[i].w += gv.y * wv[1].w;
                acc[i].x += gv.z * wv[2].x; acc[i].y += gv.z * wv[2].y;
                acc[i].z += gv.z * wv[2].z; acc[i].w += gv.z * wv[2].w;
                acc[i].x += gv.w * wv[3].x; acc[i].y += gv.w * wv[3].y;
                acc[i].z += gv.w * wv[3].z; acc[i].w += gv.w * wv[3].w;
            }
        }
    }

    const float4 b = *reinterpret_cast<const float4*>(bias + cb);
    #pragma unroll
    for (int i = 0; i < 8; ++i) {
        const int gr = row0 + rg + i;
        if (gr < N_NODES) {
            const float nv = norm[gr];
            float4 v;
            v.x = acc[i].x * nv + b.x;
            v.y = acc[i].y * nv + b.y;
            v.z = acc[i].z * nv + b.z;
            v.w = acc[i].w * nv + b.w;
            v.x = v.x > 0.f ? v.x : 0.2f * v.x;
            v.y = v.y > 0.f ? v.y : 0.2f * v.y;
            v.z = v.z > 0.f ? v.z : 0.2f * v.z;
            v.w = v.w > 0.f ? v.w : 0.2f * v.w;
            *reinterpret_cast<float4*>(out + gr * D + cb) = v;
        }
    }
}

extern "C" void kernel_launch(void* const* d_in, const int* in_sizes, int n_in,
                              void* d_out, int out_size, void* d_ws, size_t ws_size,
                              hipStream_t stream) {
    const float* h    = (const float*)d_in[0];
    const float* norm = (const float*)d_in[1];
    const float* Wm   = (const float*)d_in[2];
    const float* bias = (const float*)d_in[3];
    const int*   src  = (const int*)d_in[4];
    const int*   dst  = (const int*)d_in[5];
    float* out = (float*)d_out;
    int* ws = (int*)d_ws;

    if (ws_size >= WS_MID_INTS * 4) {
        int* cnt  = ws + WS_CNT;
        int* pos  = ws + WS_POS;
        int* boff = ws + WS_BOFF;
        int* noff = ws + WS_NOFF;
        int* ebuf = ws + WS_EBUF;
        int* esrc = ws + WS_ESRC;
        unsigned short* hs = (unsigned short*)(ws + WS_HS);
        const bool use_bf16 = (ws_size >= WS_FULL_INTS * 4);

        if (use_bf16) {
            // ---- full tier: 5 dispatches ----
            f16x8* Whs = (f16x8*)esrc;      // esrc region unused in full tier
            hipMemsetAsync(cnt, 0, 2 * 784 * sizeof(int), stream);   // cnt + pos
            prep_count<<<PREP_NBLK + CNT_NBLK, 256, 0, stream>>>(h, norm, hs, dst, cnt, PREP_NBLK);
            scatter_scan<<<SCAT_NBLK, 1024, 0, stream>>>(src, dst, cnt, pos, boff, ebuf);
            _Float16* g16 = (_Float16*)out;
            gather_direct<<<GATH_NBLK + 8, 256, 0, stream>>>(hs, boff, ebuf, g16, Wm, Whs);
            gemm_mfma_f16g<<<(N_NODES + 63) / 64, 256, 0, stream>>>(g16, out, Whs, bias, norm);
        } else {
            // ---- mid tier: legacy proven chain ----
            f16x8* Whs = (f16x8*)ebuf;      // ebuf dead after bin_sort
            hipMemsetAsync(cnt, 0, 784 * sizeof(int), stream);
            prep_count<<<CNT_NBLK, 256, 0, stream>>>(h, norm, (unsigned short*)ws, dst, cnt, 0);
            coarse_scan   <<<1, 1024, 0, stream>>>(cnt, boff, pos);
            coarse_scatter<<<SCAT_NBLK, 1024, 0, stream>>>(src, dst, pos, ebuf);
            bin_sort      <<<NB, 256, 0, stream>>>(boff, ebuf, esrc, noff);
            gather_fp32<<<GATH32_NBLK + 8, 256, 0, stream>>>(h, norm, noff, esrc, out, Wm, Whs);
            gemm_mfma<<<(N_NODES + 63) / 64, 256, 0, stream>>>(out, Whs, bias, norm);
        }
    } else {
        hipMemsetAsync(out, 0, (size_t)N_NODES * D * sizeof(float), stream);
        scatter_kernel<<<(E_EDGES * 32) / 256, 256, 0, stream>>>(h, norm, src, dst, out);
        gemm_epilogue<<<(N_NODES + GROWS - 1) / GROWS, 256, 0, stream>>>(out, Wm, bias, norm);
    }
}

// Round 9
// 228.667 us; speedup vs baseline: 2.5644x; 1.0233x over previous
//
#include <hip/hip_runtime.h>

#define N_NODES 100000
#define E_EDGES 1600000
#define D 128
#define SHIFT 7
#define BNODES 128
#define NB ((N_NODES + BNODES - 1) / BNODES)     // 782 bins

#define CNT_CHUNK 2048
#define CNT_NBLK ((E_EDGES + CNT_CHUNK - 1) / CNT_CHUNK)    // 782
#define PREP_NBLK (N_NODES * 32 / 256)                      // 12500
#define SCAT_CHUNK 8192
#define SCAT_PASS 2                                         // 8192 / (1024*4)
#define SCAT_NBLK ((E_EDGES + SCAT_CHUNK - 1) / SCAT_CHUNK) // 196
#define GATHD_NBLK ((N_NODES + 63) / 64)                    // 1563 (64-node blocks)
#define GATH32_NBLK (N_NODES / 8)                           // 12500 (mid tier)

// per-node LDS list capacity (deg ~ Poisson(16); 64 = +12 sigma, fallback kept)
#define CAP_N 64
#define LSTR 65                                             // stride 65 -> banks spread

// fp32-GEMM tiling (tier-0 fallback only)
#define GROWS 64
#define KCH 32

typedef _Float16       f16x8  __attribute__((ext_vector_type(8)));
typedef float          f32x4  __attribute__((ext_vector_type(4)));
typedef unsigned short u16x8  __attribute__((ext_vector_type(8)));

// ---- workspace layout (int units) ----
// cnt and pos are contiguous so one memset zeroes both (full tier).
#define WS_CNT   0                         // 784 slots
#define WS_POS   784                       // 784 slots
#define WS_BOFF  1568                      // 785 slots
#define WS_NOFF  2356                      // N+1 (mid tier only)
#define WS_EBUF  102400                    // E  (LIVE through gather_direct in full tier)
#define WS_ESRC  (102400 + E_EDGES)        // E  (full tier: first 8192 ints = Whs)
#define WS_HS    (102400 + 2 * E_EDGES)    // N*D/2 ints (bf16 h*norm)
#define WS_FULL_INTS ((size_t)WS_HS + (size_t)N_NODES * D / 2)
#define WS_MID_INTS  ((size_t)WS_HS)

// f16 g staging inside `out`: row r occupies the FIRST 256 B of row r's fp32
// slot. gemm blocks read only their own 64-row slab's f16 before overwriting
// that slab with fp32 (in-block __syncthreads between A-reads and stores).
#define GROW16 256                          // _Float16 elements per row slot

// ======================= fused prep + coarse count =======================
__global__ __launch_bounds__(256) void prep_count(const float* __restrict__ h,
                                                  const float* __restrict__ norm,
                                                  unsigned short* __restrict__ hs,
                                                  const int* __restrict__ dst,
                                                  int* __restrict__ cnt,
                                                  int prep_blocks) {
    __shared__ int hist[NB];
    const int t = threadIdx.x;
    if ((int)blockIdx.x < prep_blocks) {
        const int idx = blockIdx.x * 256 + t;
        const int node = idx >> 5;
        const int c = (idx & 31) << 2;
        const float nv = norm[node];
        const float4 v = *reinterpret_cast<const float4*>(h + node * D + c);
        float a[4] = {v.x * nv, v.y * nv, v.z * nv, v.w * nv};
        ushort4 o;
        unsigned short* op = reinterpret_cast<unsigned short*>(&o);
        #pragma unroll
        for (int i = 0; i < 4; ++i) {
            unsigned int u = __float_as_uint(a[i]);
            u += 0x7FFFu + ((u >> 16) & 1u);            // round-to-nearest-even
            op[i] = (unsigned short)(u >> 16);
        }
        *reinterpret_cast<ushort4*>(hs + node * D + c) = o;
        return;
    }
    const int cb = blockIdx.x - prep_blocks;
    const int e0 = cb * CNT_CHUNK;
    const int rem = (E_EDGES - e0 < CNT_CHUNK) ? (E_EDGES - e0) : CNT_CHUNK;
    for (int i = t; i < NB; i += 256) hist[i] = 0;
    __syncthreads();
    if (rem == CNT_CHUNK) {
        const int4* d4 = reinterpret_cast<const int4*>(dst + e0);
        #pragma unroll
        for (int p = 0; p < 2; ++p) {
            const int4 v = d4[p * 256 + t];
            atomicAdd(&hist[v.x >> SHIFT], 1);
            atomicAdd(&hist[v.y >> SHIFT], 1);
            atomicAdd(&hist[v.z >> SHIFT], 1);
            atomicAdd(&hist[v.w >> SHIFT], 1);
        }
    } else {
        for (int i = t; i < rem; i += 256)
            atomicAdd(&hist[dst[e0 + i] >> SHIFT], 1);
    }
    __syncthreads();
    for (int b = t; b < NB; b += 256) {
        const int c = hist[b];
        if (c) atomicAdd(&cnt[b], c);
    }
}

// ======================= scatter + inline scan (full tier) =======================
__global__ __launch_bounds__(1024) void scatter_scan(const int* __restrict__ src,
                                                     const int* __restrict__ dst,
                                                     const int* __restrict__ cnt,
                                                     int* __restrict__ pos,
                                                     int* __restrict__ boff,
                                                     int* __restrict__ ebuf) {
    __shared__ int buf[2][1024];
    __shared__ int hist[NB];
    const int t = threadIdx.x;

    // ---- inline exclusive scan of cnt[0..NB) ----
    const int v = (t < NB) ? cnt[t] : 0;
    int pi = 0;
    buf[0][t] = v;
    __syncthreads();
    #pragma unroll
    for (int o = 1; o < 1024; o <<= 1) {
        const int nv = buf[pi][t] + (t >= o ? buf[pi][t - o] : 0);
        buf[1 - pi][t] = nv;
        pi = 1 - pi;
        __syncthreads();
    }
    const int excl = buf[pi][t] - v;                 // exclusive prefix (t < NB valid)
    if (blockIdx.x == 0) {
        if (t < NB) boff[t] = excl;
        if (t == 0) boff[NB] = E_EDGES;
    }
    if (t < NB) hist[t] = 0;
    __syncthreads();

    // ---- count this chunk ----
    const int e0 = blockIdx.x * SCAT_CHUNK;
    const int rem = (E_EDGES - e0 < SCAT_CHUNK) ? (E_EDGES - e0) : SCAT_CHUNK;
    if (rem == SCAT_CHUNK) {
        const int4* d4 = reinterpret_cast<const int4*>(dst + e0);
        #pragma unroll
        for (int p = 0; p < SCAT_PASS; ++p) {
            const int4 vv = d4[p * 1024 + t];
            atomicAdd(&hist[vv.x >> SHIFT], 1);
            atomicAdd(&hist[vv.y >> SHIFT], 1);
            atomicAdd(&hist[vv.z >> SHIFT], 1);
            atomicAdd(&hist[vv.w >> SHIFT], 1);
        }
    } else {
        for (int i = t; i < rem; i += 1024)
            atomicAdd(&hist[dst[e0 + i] >> SHIFT], 1);
    }
    __syncthreads();

    // ---- claim global slots ----
    if (t < NB) {
        const int c = hist[t];
        if (c) hist[t] = excl + atomicAdd(&pos[t], c);
    }
    __syncthreads();

    // ---- scatter packed words ----
    if (rem == SCAT_CHUNK) {
        const int4* d4 = reinterpret_cast<const int4*>(dst + e0);
        const int4* s4 = reinterpret_cast<const int4*>(src + e0);
        #pragma unroll
        for (int p = 0; p < SCAT_PASS; ++p) {
            const int4 dv = d4[p * 1024 + t];
            const int4 sv = s4[p * 1024 + t];
            int pz;
            pz = atomicAdd(&hist[dv.x >> SHIFT], 1);
            ebuf[pz] = (sv.x << SHIFT) | (dv.x & (BNODES - 1));
            pz = atomicAdd(&hist[dv.y >> SHIFT], 1);
            ebuf[pz] = (sv.y << SHIFT) | (dv.y & (BNODES - 1));
            pz = atomicAdd(&hist[dv.z >> SHIFT], 1);
            ebuf[pz] = (sv.z << SHIFT) | (dv.z & (BNODES - 1));
            pz = atomicAdd(&hist[dv.w >> SHIFT], 1);
            ebuf[pz] = (sv.w << SHIFT) | (dv.w & (BNODES - 1));
        }
    } else {
        for (int i = t; i < rem; i += 1024) {
            const int d = dst[e0 + i];
            const int b = d >> SHIFT;
            const int p = atomicAdd(&hist[b], 1);
            ebuf[p] = (src[e0 + i] << SHIFT) | (d & (BNODES - 1));
        }
    }
}

// ======================= wprep body (shared) =======================
__device__ __forceinline__ void wprep_body(int tid, const float* __restrict__ Wm,
                                           f16x8* __restrict__ Whs) {
    const int kiter = tid >> 9;
    const int nt = (tid >> 6) & 7;
    const int lane = tid & 63;
    const int q = lane >> 4;
    const int col = nt * 16 + (lane & 15);
    f16x8 v;
    #pragma unroll
    for (int j = 0; j < 8; ++j)
        v[j] = (_Float16)Wm[(kiter * 32 + q * 8 + j) * D + col];
    Whs[tid] = v;
}

// ======================= gather DIRECT, 64-node blocks (full tier) ===========
// One block per 64 nodes (half coarse bin): bin = g>>1, sub = g&1. Phase 1:
// stream the bin's contiguous ebuf segment once, keep the 1/2 of edges whose
// local dst is in this half (2x redundancy vs 8x before -> 4x less filter
// work + less cross-XCD refetch). Push src ids into per-node LDS lists
// ([64][65]). Phase 2: 4 rounds of the proven 16-lane/node 8-deep gather.
// HARDENED: b0/b1 clamped; src validated at push and in fallback.
__global__ __launch_bounds__(256) void gather_direct(
    const unsigned short* __restrict__ hs, const int* __restrict__ boff,
    const int* __restrict__ ebuf, _Float16* __restrict__ g16,
    const float* __restrict__ Wm, f16x8* __restrict__ Whs)
{
    if ((int)blockIdx.x >= GATHD_NBLK) {
        wprep_body((blockIdx.x - GATHD_NBLK) * 256 + threadIdx.x, Wm, Whs);
        return;
    }
    __shared__ int lists[64][LSTR];
    __shared__ int lcnt[64];
    const int t = threadIdx.x;
    const int g = blockIdx.x;
    const int bin = g >> 1;
    const int sub = g & 1;
    if (t < 64) lcnt[t] = 0;
    __syncthreads();
    int b0 = boff[bin];
    int b1 = boff[bin + 1];
    b0 = (b0 < 0) ? 0 : ((b0 > E_EDGES) ? E_EDGES : b0);
    b1 = (b1 < b0) ? b0 : ((b1 > E_EDGES) ? E_EDGES : b1);
    for (int i = b0 + t; i < b1; i += 256) {
        const int w = ebuf[i];
        const int l = w & (BNODES - 1);
        const unsigned s = (unsigned)w >> SHIFT;     // src (w >= 0: src < 2^17)
        if ((l >> 6) == sub && s < (unsigned)N_NODES) {
            const int p = atomicAdd(&lcnt[l & 63], 1);
            if (p < CAP_N) lists[l & 63][p] = (int)s;
        }
    }
    __syncthreads();

    const int grp = t >> 4;                         // 0..15
    const int c = (t & 15) << 3;                    // 8 cols per lane

    #pragma unroll 1
    for (int r = 0; r < 4; ++r) {
        const int local = r * 16 + grp;             // 0..63
        const int node = g * 64 + local;
        const int deg = lcnt[local];
        float a[8];
        #pragma unroll
        for (int j = 0; j < 8; ++j) a[j] = 0.f;

        if (deg <= CAP_N) {
            const int* lp = lists[local];
            int i = 0;
            for (; i + 7 < deg; i += 8) {
                const int s0 = lp[i];     const int s1 = lp[i + 1];
                const int s2 = lp[i + 2]; const int s3 = lp[i + 3];
                const int s4 = lp[i + 4]; const int s5 = lp[i + 5];
                const int s6 = lp[i + 6]; const int s7 = lp[i + 7];
                const u16x8 u0 = *reinterpret_cast<const u16x8*>(hs + s0 * D + c);
                const u16x8 u1 = *reinterpret_cast<const u16x8*>(hs + s1 * D + c);
                const u16x8 u2 = *reinterpret_cast<const u16x8*>(hs + s2 * D + c);
                const u16x8 u3 = *reinterpret_cast<const u16x8*>(hs + s3 * D + c);
                const u16x8 u4 = *reinterpret_cast<const u16x8*>(hs + s4 * D + c);
                const u16x8 u5 = *reinterpret_cast<const u16x8*>(hs + s5 * D + c);
                const u16x8 u6 = *reinterpret_cast<const u16x8*>(hs + s6 * D + c);
                const u16x8 u7 = *reinterpret_cast<const u16x8*>(hs + s7 * D + c);
                #pragma unroll
                for (int j = 0; j < 8; ++j) {
                    a[j] += __uint_as_float((unsigned int)u0[j] << 16);
                    a[j] += __uint_as_float((unsigned int)u1[j] << 16);
                    a[j] += __uint_as_float((unsigned int)u2[j] << 16);
                    a[j] += __uint_as_float((unsigned int)u3[j] << 16);
                    a[j] += __uint_as_float((unsigned int)u4[j] << 16);
                    a[j] += __uint_as_float((unsigned int)u5[j] << 16);
                    a[j] += __uint_as_float((unsigned int)u6[j] << 16);
                    a[j] += __uint_as_float((unsigned int)u7[j] << 16);
                }
            }
            if (i + 3 < deg) {
                const int s0 = lp[i];     const int s1 = lp[i + 1];
                const int s2 = lp[i + 2]; const int s3 = lp[i + 3];
                const u16x8 u0 = *reinterpret_cast<const u16x8*>(hs + s0 * D + c);
                const u16x8 u1 = *reinterpret_cast<const u16x8*>(hs + s1 * D + c);
                const u16x8 u2 = *reinterpret_cast<const u16x8*>(hs + s2 * D + c);
                const u16x8 u3 = *reinterpret_cast<const u16x8*>(hs + s3 * D + c);
                #pragma unroll
                for (int j = 0; j < 8; ++j) {
                    a[j] += __uint_as_float((unsigned int)u0[j] << 16);
                    a[j] += __uint_as_float((unsigned int)u1[j] << 16);
                    a[j] += __uint_as_float((unsigned int)u2[j] << 16);
                    a[j] += __uint_as_float((unsigned int)u3[j] << 16);
                }
                i += 4;
            }
            for (; i < deg; ++i) {
                const int s = lp[i];
                const u16x8 u = *reinterpret_cast<const u16x8*>(hs + s * D + c);
                #pragma unroll
                for (int j = 0; j < 8; ++j)
                    a[j] += __uint_as_float((unsigned int)u[j] << 16);
            }
        } else {
            // ultra-rare overflow fallback: scan bin segment for my node's edges
            const int myl = (sub << 6) | local;
            for (int i = b0; i < b1; ++i) {
                const int w = ebuf[i];
                const unsigned s = (unsigned)w >> SHIFT;
                if ((w & (BNODES - 1)) == myl && s < (unsigned)N_NODES) {
                    const u16x8 u = *reinterpret_cast<const u16x8*>(hs + s * D + c);
                    #pragma unroll
                    for (int j = 0; j < 8; ++j)
                        a[j] += __uint_as_float((unsigned int)u[j] << 16);
                }
            }
        }

        if (node < N_NODES) {
            f16x8 o;
            #pragma unroll
            for (int j = 0; j < 8; ++j) o[j] = (_Float16)a[j];
            *reinterpret_cast<f16x8*>(g16 + node * GROW16 + c) = o;
        }
    }
}

// ======================= MFMA GEMM + epilogue (full tier, f16 g) =======================
__global__ __launch_bounds__(256) void gemm_mfma_f16g(
    const _Float16* g16, float* out, const f16x8* __restrict__ Whs,
    const float* __restrict__ bias, const float* __restrict__ norm)
{
    __shared__ f16x8 Wlds[2048];           // 32 KB
    const int t = threadIdx.x;
    const int row0 = blockIdx.x * 64;

    #pragma unroll
    for (int p = 0; p < 8; ++p)
        reinterpret_cast<float4*>(Wlds)[p * 256 + t] =
            reinterpret_cast<const float4*>(Whs)[p * 256 + t];
    __syncthreads();

    const int lane = t & 63;
    const int strip = t >> 6;
    const int q = lane >> 4;
    const int l15 = lane & 15;

    int mrow = row0 + strip * 16 + l15;
    if (mrow >= N_NODES) mrow = N_NODES - 1;

    f32x4 acc[8];
    #pragma unroll
    for (int i = 0; i < 8; ++i) acc[i] = (f32x4){0.f, 0.f, 0.f, 0.f};

    #pragma unroll
    for (int kiter = 0; kiter < 4; ++kiter) {
        const f16x8 a =
            *reinterpret_cast<const f16x8*>(g16 + mrow * GROW16 + kiter * 32 + q * 8);
        #pragma unroll
        for (int nt = 0; nt < 8; ++nt) {
            const f16x8 b = Wlds[(kiter * 8 + nt) * 64 + lane];
            acc[nt] = __builtin_amdgcn_mfma_f32_16x16x32_f16(a, b, acc[nt], 0, 0, 0);
        }
    }

    // all f16 A-reads of this block's slab must complete before fp32 overwrite
    __syncthreads();

    float nrm[4];
    int mr[4];
    #pragma unroll
    for (int rgi = 0; rgi < 4; ++rgi) {
        mr[rgi] = row0 + strip * 16 + q * 4 + rgi;
        nrm[rgi] = (mr[rgi] < N_NODES) ? norm[mr[rgi]] : 0.f;
    }
    #pragma unroll
    for (int nt = 0; nt < 8; ++nt) {
        const int col = nt * 16 + l15;
        const float bc = bias[col];
        #pragma unroll
        for (int rgi = 0; rgi < 4; ++rgi) {
            if (mr[rgi] < N_NODES) {
                float v = acc[nt][rgi] * nrm[rgi] + bc;
                v = v > 0.f ? v : 0.2f * v;
                out[mr[rgi] * D + col] = v;
            }
        }
    }
}

// ======================= mid-tier legacy chain (unchanged, proven) ===========
__global__ __launch_bounds__(1024) void coarse_scan(const int* __restrict__ cnt,
                                                    int* __restrict__ boff,
                                                    int* __restrict__ pos) {
    __shared__ int buf[2][1024];
    const int t = threadIdx.x;
    const int v = (t < NB) ? cnt[t] : 0;
    int pi = 0;
    buf[0][t] = v;
    __syncthreads();
    #pragma unroll
    for (int o = 1; o < 1024; o <<= 1) {
        const int nv = buf[pi][t] + (t >= o ? buf[pi][t - o] : 0);
        buf[1 - pi][t] = nv;
        pi = 1 - pi;
        __syncthreads();
    }
    if (t < NB) {
        const int excl = buf[pi][t] - v;
        boff[t] = excl;
        pos[t] = excl;
    }
    if (t == 0) boff[NB] = E_EDGES;
}

__global__ __launch_bounds__(1024) void coarse_scatter(const int* __restrict__ src,
                                                       const int* __restrict__ dst,
                                                       int* __restrict__ pos,
                                                       int* __restrict__ ebuf) {
    __shared__ int hist[NB];
    const int t = threadIdx.x;
    const int e0 = blockIdx.x * SCAT_CHUNK;
    const int rem = (E_EDGES - e0 < SCAT_CHUNK) ? (E_EDGES - e0) : SCAT_CHUNK;
    for (int i = t; i < NB; i += 1024) hist[i] = 0;
    __syncthreads();
    if (rem == SCAT_CHUNK) {
        const int4* d4 = reinterpret_cast<const int4*>(dst + e0);
        #pragma unroll
        for (int p = 0; p < SCAT_PASS; ++p) {
            const int4 v = d4[p * 1024 + t];
            atomicAdd(&hist[v.x >> SHIFT], 1);
            atomicAdd(&hist[v.y >> SHIFT], 1);
            atomicAdd(&hist[v.z >> SHIFT], 1);
            atomicAdd(&hist[v.w >> SHIFT], 1);
        }
    } else {
        for (int i = t; i < rem; i += 1024)
            atomicAdd(&hist[dst[e0 + i] >> SHIFT], 1);
    }
    __syncthreads();
    for (int b = t; b < NB; b += 1024) {
        const int c = hist[b];
        if (c) hist[b] = atomicAdd(&pos[b], c);
    }
    __syncthreads();
    if (rem == SCAT_CHUNK) {
        const int4* d4 = reinterpret_cast<const int4*>(dst + e0);
        const int4* s4 = reinterpret_cast<const int4*>(src + e0);
        #pragma unroll
        for (int p = 0; p < SCAT_PASS; ++p) {
            const int4 dv = d4[p * 1024 + t];
            const int4 sv = s4[p * 1024 + t];
            int pz;
            pz = atomicAdd(&hist[dv.x >> SHIFT], 1);
            ebuf[pz] = (sv.x << SHIFT) | (dv.x & (BNODES - 1));
            pz = atomicAdd(&hist[dv.y >> SHIFT], 1);
            ebuf[pz] = (sv.y << SHIFT) | (dv.y & (BNODES - 1));
            pz = atomicAdd(&hist[dv.z >> SHIFT], 1);
            ebuf[pz] = (sv.z << SHIFT) | (dv.z & (BNODES - 1));
            pz = atomicAdd(&hist[dv.w >> SHIFT], 1);
            ebuf[pz] = (sv.w << SHIFT) | (dv.w & (BNODES - 1));
        }
    } else {
        for (int i = t; i < rem; i += 1024) {
            const int d = dst[e0 + i];
            const int b = d >> SHIFT;
            const int p = atomicAdd(&hist[b], 1);
            ebuf[p] = (src[e0 + i] << SHIFT) | (d & (BNODES - 1));
        }
    }
}

__global__ __launch_bounds__(256) void bin_sort(const int* __restrict__ boff,
                                                const int* __restrict__ ebuf,
                                                int* __restrict__ esrc,
                                                int* __restrict__ noff) {
    __shared__ int hist[BNODES];
    __shared__ int curs[BNODES];
    __shared__ int sbuf[2][BNODES];
    const int t = threadIdx.x;
    const int bin = blockIdx.x;
    if (t < BNODES) hist[t] = 0;
    __syncthreads();
    const int b0 = boff[bin];
    const int b1 = boff[bin + 1];
    for (int i = b0 + t; i < b1; i += 256)
        atomicAdd(&hist[ebuf[i] & (BNODES - 1)], 1);
    __syncthreads();
    if (t < BNODES) sbuf[0][t] = hist[t];
    __syncthreads();
    int pi = 0;
    #pragma unroll
    for (int o = 1; o < BNODES; o <<= 1) {
        if (t < BNODES)
            sbuf[1 - pi][t] = sbuf[pi][t] + (t >= o ? sbuf[pi][t - o] : 0);
        pi = 1 - pi;
        __syncthreads();
    }
    if (t < BNODES) {
        const int base = b0 + sbuf[pi][t] - hist[t];
        curs[t] = base;
        const int node = (bin << SHIFT) + t;
        if (node < N_NODES) noff[node] = base;
    }
    if (bin == 0 && t == 0) noff[N_NODES] = E_EDGES;
    __syncthreads();
    for (int i = b0 + t; i < b1; i += 256) {
        const int w = ebuf[i];
        const int p = atomicAdd(&curs[w & (BNODES - 1)], 1);
        esrc[p] = w >> SHIFT;
    }
}

__global__ __launch_bounds__(256) void gather_fp32(const float* __restrict__ h,
                                                   const float* __restrict__ norm,
                                                   const int* __restrict__ noff,
                                                   const int* __restrict__ esrc,
                                                   float* __restrict__ g,
                                                   const float* __restrict__ Wm,
                                                   f16x8* __restrict__ Whs) {
    if ((int)blockIdx.x >= GATH32_NBLK) {
        wprep_body((blockIdx.x - GATH32_NBLK) * 256 + threadIdx.x, Wm, Whs);
        return;
    }
    const int t = threadIdx.x;
    const int node = blockIdx.x * 8 + (t >> 5);
    const int c = (t & 31) << 2;
    const int beg = noff[node];
    const int end = noff[node + 1];
    float4 acc = make_float4(0.f, 0.f, 0.f, 0.f);
    for (int i = beg; i < end; ++i) {
        const int s = esrc[i];
        const float nv = norm[s];
        const float4 hv = *reinterpret_cast<const float4*>(h + s * D + c);
        acc.x += hv.x * nv;
        acc.y += hv.y * nv;
        acc.z += hv.z * nv;
        acc.w += hv.w * nv;
    }
    *reinterpret_cast<float4*>(g + node * D + c) = acc;
}

__global__ __launch_bounds__(256) void scatter_kernel(
    const float* __restrict__ h, const float* __restrict__ norm,
    const int* __restrict__ src, const int* __restrict__ dst,
    float* __restrict__ g)
{
    const int idx = blockIdx.x * 256 + threadIdx.x;
    const int e = idx >> 5;
    const int c = (idx & 31) << 2;
    const int s = src[e];
    const int d = dst[e];
    const float nv = norm[s];
    const float4 hv = *reinterpret_cast<const float4*>(h + s * D + c);
    float* gp = g + d * D + c;
    atomicAdd(gp + 0, hv.x * nv);
    atomicAdd(gp + 1, hv.y * nv);
    atomicAdd(gp + 2, hv.z * nv);
    atomicAdd(gp + 3, hv.w * nv);
}

__global__ __launch_bounds__(256) void gemm_mfma(
    float* __restrict__ out, const f16x8* __restrict__ Whs,
    const float* __restrict__ bias, const float* __restrict__ norm)
{
    __shared__ f16x8 Wlds[2048];           // 32 KB
    const int t = threadIdx.x;
    const int row0 = blockIdx.x * 64;

    #pragma unroll
    for (int p = 0; p < 8; ++p)
        reinterpret_cast<float4*>(Wlds)[p * 256 + t] =
            reinterpret_cast<const float4*>(Whs)[p * 256 + t];
    __syncthreads();

    const int lane = t & 63;
    const int strip = t >> 6;
    const int q = lane >> 4;
    const int l15 = lane & 15;

    int mrow = row0 + strip * 16 + l15;
    if (mrow >= N_NODES) mrow = N_NODES - 1;

    f32x4 acc[8];
    #pragma unroll
    for (int i = 0; i < 8; ++i) acc[i] = (f32x4){0.f, 0.f, 0.f, 0.f};

    #pragma unroll
    for (int kiter = 0; kiter < 4; ++kiter) {
        const float* gp = out + mrow * D + kiter * 32 + q * 8;
        const float4 ga = *reinterpret_cast<const float4*>(gp);
        const float4 gb = *reinterpret_cast<const float4*>(gp + 4);
        f16x8 a;
        a[0] = (_Float16)ga.x; a[1] = (_Float16)ga.y;
        a[2] = (_Float16)ga.z; a[3] = (_Float16)ga.w;
        a[4] = (_Float16)gb.x; a[5] = (_Float16)gb.y;
        a[6] = (_Float16)gb.z; a[7] = (_Float16)gb.w;
        #pragma unroll
        for (int nt = 0; nt < 8; ++nt) {
            const f16x8 b = Wlds[(kiter * 8 + nt) * 64 + lane];
            acc[nt] = __builtin_amdgcn_mfma_f32_16x16x32_f16(a, b, acc[nt], 0, 0, 0);
        }
    }

    float nrm[4];
    int mr[4];
    #pragma unroll
    for (int rgi = 0; rgi < 4; ++rgi) {
        mr[rgi] = row0 + strip * 16 + q * 4 + rgi;
        nrm[rgi] = (mr[rgi] < N_NODES) ? norm[mr[rgi]] : 0.f;
    }
    #pragma unroll
    for (int nt = 0; nt < 8; ++nt) {
        const int col = nt * 16 + l15;
        const float bc = bias[col];
        #pragma unroll
        for (int rgi = 0; rgi < 4; ++rgi) {
            if (mr[rgi] < N_NODES) {
                float v = acc[nt][rgi] * nrm[rgi] + bc;
                v = v > 0.f ? v : 0.2f * v;
                out[mr[rgi] * D + col] = v;
            }
        }
    }
}

__global__ __launch_bounds__(256) void gemm_epilogue(
    float* __restrict__ out, const float* __restrict__ Wm,
    const float* __restrict__ bias, const float* __restrict__ norm)
{
    __shared__ float gs[GROWS][D + 4];
    __shared__ float Wlds[KCH][D];
    const int t = threadIdx.x;
    const int row0 = blockIdx.x * GROWS;

    #pragma unroll
    for (int p = 0; p < 8; ++p) {
        const int i = p * 256 + t;
        const int r = i >> 5;
        const int c = (i & 31) << 2;
        int gr = row0 + r;
        if (gr >= N_NODES) gr = N_NODES - 1;
        const float4 v = *reinterpret_cast<const float4*>(out + gr * D + c);
        *reinterpret_cast<float4*>(&gs[r][c]) = v;
    }

    const int rg = (t >> 5) * 8;
    const int cb = (t & 31) << 2;

    float4 acc[8];
    #pragma unroll
    for (int i = 0; i < 8; ++i) acc[i] = make_float4(0.f, 0.f, 0.f, 0.f);

    for (int kc = 0; kc < D; kc += KCH) {
        __syncthreads();
        #pragma unroll
        for (int p = 0; p < 4; ++p) {
            const int i = p * 256 + t;
            const int kk = i >> 5;
            const int c = (i & 31) << 2;
            *reinterpret_cast<float4*>(&Wlds[kk][c]) =
                *reinterpret_cast<const float4*>(Wm + (kc + kk) * D + c);
        }
        __syncthreads();

        #pragma unroll
        for (int k4 = 0; k4 < KCH; k4 += 4) {
            float4 wv[4];
            #pragma unroll
            for (int kk = 0; kk < 4; ++kk)
                wv[kk] = *reinterpret_cast<const float4*>(&Wlds[k4 + kk][cb]);
            #pragma unroll
            for (int i = 0; i < 8; ++i) {
                const float4 gv = *reinterpret_cast<const float4*>(&gs[rg + i][kc + k4]);
                acc[i].x += gv.x * wv[0].x; acc[i].y += gv.x * wv[0].y;
                acc[i].z += gv.x * wv[0].z; acc[i].w += gv.x * wv[0].w;
                acc[i].x += gv.y * wv[1].x; acc[i].y += gv.y * wv[1].y;
                acc[i].z += gv.y * wv[1].z; acc[i].w += gv.y * wv[1].w;
                acc[i].x += gv.z * wv[2].x; acc[i].y += gv.z * wv[2].y;
                acc[i].z += gv.z * wv[2].z; acc[i].w += gv.z * wv[2].w;
                acc[i].x += gv.w * wv[3].x; acc[i].y += gv.w * wv[3].y;
                acc[i].z += gv.w * wv[3].z; acc[i].w += gv.w * wv[3].w;
            }
        }
    }

    const float4 b = *reinterpret_cast<const float4*>(bias + cb);
    #pragma unroll
    for (int i = 0; i < 8; ++i) {
        const int gr = row0 + rg + i;
        if (gr < N_NODES) {
            const float nv = norm[gr];
            float4 v;
            v.x = acc[i].x * nv + b.x;
            v.y = acc[i].y * nv + b.y;
            v.z = acc[i].z * nv + b.z;
            v.w = acc[i].w * nv + b.w;
            v.x = v.x > 0.f ? v.x : 0.2f * v.x;
            v.y = v.y > 0.f ? v.y : 0.2f * v.y;
            v.z = v.z > 0.f ? v.z : 0.2f * v.z;
            v.w = v.w > 0.f ? v.w : 0.2f * v.w;
            *reinterpret_cast<float4*>(out + gr * D + cb) = v;
        }
    }
}

extern "C" void kernel_launch(void* const* d_in, const int* in_sizes, int n_in,
                              void* d_out, int out_size, void* d_ws, size_t ws_size,
                              hipStream_t stream) {
    const float* h    = (const float*)d_in[0];
    const float* norm = (const float*)d_in[1];
    const float* Wm   = (const float*)d_in[2];
    const float* bias = (const float*)d_in[3];
    const int*   src  = (const int*)d_in[4];
    const int*   dst  = (const int*)d_in[5];
    float* out = (float*)d_out;
    int* ws = (int*)d_ws;

    if (ws_size >= WS_MID_INTS * 4) {
        int* cnt  = ws + WS_CNT;
        int* pos  = ws + WS_POS;
        int* boff = ws + WS_BOFF;
        int* noff = ws + WS_NOFF;
        int* ebuf = ws + WS_EBUF;
        int* esrc = ws + WS_ESRC;
        unsigned short* hs = (unsigned short*)(ws + WS_HS);
        const bool use_bf16 = (ws_size >= WS_FULL_INTS * 4);

        if (use_bf16) {
            // ---- full tier: 5 dispatches ----
            f16x8* Whs = (f16x8*)esrc;      // esrc region unused in full tier
            hipMemsetAsync(cnt, 0, 2 * 784 * sizeof(int), stream);   // cnt + pos
            prep_count<<<PREP_NBLK + CNT_NBLK, 256, 0, stream>>>(h, norm, hs, dst, cnt, PREP_NBLK);
            scatter_scan<<<SCAT_NBLK, 1024, 0, stream>>>(src, dst, cnt, pos, boff, ebuf);
            _Float16* g16 = (_Float16*)out;
            gather_direct<<<GATHD_NBLK + 8, 256, 0, stream>>>(hs, boff, ebuf, g16, Wm, Whs);
            gemm_mfma_f16g<<<(N_NODES + 63) / 64, 256, 0, stream>>>(g16, out, Whs, bias, norm);
        } else {
            // ---- mid tier: legacy proven chain ----
            f16x8* Whs = (f16x8*)ebuf;      // ebuf dead after bin_sort
            hipMemsetAsync(cnt, 0, 784 * sizeof(int), stream);
            prep_count<<<CNT_NBLK, 256, 0, stream>>>(h, norm, (unsigned short*)ws, dst, cnt, 0);
            coarse_scan   <<<1, 1024, 0, stream>>>(cnt, boff, pos);
            coarse_scatter<<<SCAT_NBLK, 1024, 0, stream>>>(src, dst, pos, ebuf);
            bin_sort      <<<NB, 256, 0, stream>>>(boff, ebuf, esrc, noff);
            gather_fp32<<<GATH32_NBLK + 8, 256, 0, stream>>>(h, norm, noff, esrc, out, Wm, Whs);
            gemm_mfma<<<(N_NODES + 63) / 64, 256, 0, stream>>>(out, Whs, bias, norm);
        }
    } else {
        hipMemsetAsync(out, 0, (size_t)N_NODES * D * sizeof(float), stream);
        scatter_kernel<<<(E_EDGES * 32) / 256, 256, 0, stream>>>(h, norm, src, dst, out);
        gemm_epilogue<<<(N_NODES + GROWS - 1) / GROWS, 256, 0, stream>>>(out, Wm, bias, norm);
    }
}

// Round 10
// 218.718 us; speedup vs baseline: 2.6811x; 1.0455x over previous
//
#include <hip/hip_runtime.h>

#define N_NODES 100000
#define E_EDGES 1600000
#define D 128
#define SHIFT 7
#define BNODES 128
#define NB ((N_NODES + BNODES - 1) / BNODES)     // 782 bins

#define CNT_CHUNK 2048
#define CNT_NBLK ((E_EDGES + CNT_CHUNK - 1) / CNT_CHUNK)    // 782
#define PREP_NBLK (N_NODES * 32 / 256)                      // 12500 (mid tier / legacy)
#define PREP1K (N_NODES * 32 / 1024)                        // 3125 (full tier, 1024-thr)
#define SCAT_CHUNK 8192
#define SCAT_PASS 2                                         // 8192 / (1024*4)
#define SCAT_NBLK ((E_EDGES + SCAT_CHUNK - 1) / SCAT_CHUNK) // 196
#define GATHD_NBLK ((N_NODES + 63) / 64)                    // 1563 (64-node blocks)
#define GATH32_NBLK (N_NODES / 8)                           // 12500 (mid tier)

// fixed-capacity bin regions (full tier): bin counts ~ Poisson(2046), sigma 45;
// CAPB = 2560 = +11 sigma -> overflow statistically impossible; writes guarded.
#define CAPB 2560

// per-node LDS list capacity (deg ~ Poisson(16); 64 = +12 sigma, fallback kept)
#define CAP_N 64
#define LSTR 65

// fp32-GEMM tiling (tier-0 fallback only)
#define GROWS 64
#define KCH 32

typedef _Float16       f16x8  __attribute__((ext_vector_type(8)));
typedef float          f32x4  __attribute__((ext_vector_type(4)));
typedef unsigned short u16x8  __attribute__((ext_vector_type(8)));

// ---- workspace layout (int units) ----
#define WS_CNT   0                         // 784 slots (full tier: bcnt)
#define WS_POS   784                       // 784 slots (mid tier)
#define WS_BOFF  1568                      // 785 slots (mid tier)
#define WS_NOFF  2356                      // N+1 (mid tier only)
#define WS_EBUF  102400                    // full tier: bin regions NB*CAPB = 2,001,920 ints
#define WS_WHS   (WS_EBUF + NB * CAPB)     // full tier: Whs (8192 ints), ends < WS_HS
#define WS_ESRC  (102400 + E_EDGES)        // mid tier
#define WS_HS    (102400 + 2 * E_EDGES)    // N*D/2 ints (bf16 h*norm)
#define WS_FULL_INTS ((size_t)WS_HS + (size_t)N_NODES * D / 2)
#define WS_MID_INTS  ((size_t)WS_HS)

// f16 g staging inside `out`: row r occupies the FIRST 256 B of row r's fp32
// slot. gemm blocks read only their own 64-row slab's f16 before overwriting
// that slab with fp32 (in-block __syncthreads between A-reads and stores).
#define GROW16 256                          // _Float16 elements per row slot

// ======================= FULL TIER: fused prep + fixed-bin scatter ===========
// blocks < prep_blocks: hs = bf16(h * norm_src), 1024 threads/block.
// remaining blocks: one 8192-edge chunk each -> LDS bin hist -> claim base in
// bin via atomicAdd(&bcnt[bin], c) (fixed region base = bin*CAPB, NO scan
// needed) -> scatter packed (src<<7 | dst&127) words. Writes guarded < CAPB.
__global__ __launch_bounds__(1024) void prep_scatter(
    const float* __restrict__ h, const float* __restrict__ norm,
    unsigned short* __restrict__ hs, const int* __restrict__ src,
    const int* __restrict__ dst, int* __restrict__ bcnt,
    int* __restrict__ ebuf, int prep_blocks)
{
    __shared__ int hist[NB];
    const int t = threadIdx.x;
    if ((int)blockIdx.x < prep_blocks) {
        const int idx = blockIdx.x * 1024 + t;
        const int node = idx >> 5;
        const int c = (idx & 31) << 2;
        const float nv = norm[node];
        const float4 v = *reinterpret_cast<const float4*>(h + node * D + c);
        float a[4] = {v.x * nv, v.y * nv, v.z * nv, v.w * nv};
        ushort4 o;
        unsigned short* op = reinterpret_cast<unsigned short*>(&o);
        #pragma unroll
        for (int i = 0; i < 4; ++i) {
            unsigned int u = __float_as_uint(a[i]);
            u += 0x7FFFu + ((u >> 16) & 1u);            // round-to-nearest-even
            op[i] = (unsigned short)(u >> 16);
        }
        *reinterpret_cast<ushort4*>(hs + node * D + c) = o;
        return;
    }
    const int cb = blockIdx.x - prep_blocks;
    const int e0 = cb * SCAT_CHUNK;
    const int rem = (E_EDGES - e0 < SCAT_CHUNK) ? (E_EDGES - e0) : SCAT_CHUNK;
    for (int i = t; i < NB; i += 1024) hist[i] = 0;
    __syncthreads();

    // ---- count this chunk ----
    if (rem == SCAT_CHUNK) {
        const int4* d4 = reinterpret_cast<const int4*>(dst + e0);
        #pragma unroll
        for (int p = 0; p < SCAT_PASS; ++p) {
            const int4 vv = d4[p * 1024 + t];
            atomicAdd(&hist[vv.x >> SHIFT], 1);
            atomicAdd(&hist[vv.y >> SHIFT], 1);
            atomicAdd(&hist[vv.z >> SHIFT], 1);
            atomicAdd(&hist[vv.w >> SHIFT], 1);
        }
    } else {
        for (int i = t; i < rem; i += 1024)
            atomicAdd(&hist[dst[e0 + i] >> SHIFT], 1);
    }
    __syncthreads();

    // ---- claim in-bin bases (no scan: fixed region base is bin*CAPB) ----
    if (t < NB) {
        const int c = hist[t];
        hist[t] = c ? atomicAdd(&bcnt[t], c) : 0;
    }
    __syncthreads();

    // ---- scatter packed words into fixed bin regions ----
    if (rem == SCAT_CHUNK) {
        const int4* d4 = reinterpret_cast<const int4*>(dst + e0);
        const int4* s4 = reinterpret_cast<const int4*>(src + e0);
        #pragma unroll
        for (int p = 0; p < SCAT_PASS; ++p) {
            const int4 dv = d4[p * 1024 + t];
            const int4 sv = s4[p * 1024 + t];
            int b, pz;
            b = dv.x >> SHIFT; pz = atomicAdd(&hist[b], 1);
            if (pz < CAPB) ebuf[b * CAPB + pz] = (sv.x << SHIFT) | (dv.x & (BNODES - 1));
            b = dv.y >> SHIFT; pz = atomicAdd(&hist[b], 1);
            if (pz < CAPB) ebuf[b * CAPB + pz] = (sv.y << SHIFT) | (dv.y & (BNODES - 1));
            b = dv.z >> SHIFT; pz = atomicAdd(&hist[b], 1);
            if (pz < CAPB) ebuf[b * CAPB + pz] = (sv.z << SHIFT) | (dv.z & (BNODES - 1));
            b = dv.w >> SHIFT; pz = atomicAdd(&hist[b], 1);
            if (pz < CAPB) ebuf[b * CAPB + pz] = (sv.w << SHIFT) | (dv.w & (BNODES - 1));
        }
    } else {
        for (int i = t; i < rem; i += 1024) {
            const int d = dst[e0 + i];
            const int b = d >> SHIFT;
            const int pz = atomicAdd(&hist[b], 1);
            if (pz < CAPB) ebuf[b * CAPB + pz] = (src[e0 + i] << SHIFT) | (d & (BNODES - 1));
        }
    }
}

// ======================= wprep body (shared) =======================
__device__ __forceinline__ void wprep_body(int tid, const float* __restrict__ Wm,
                                           f16x8* __restrict__ Whs) {
    const int kiter = tid >> 9;
    const int nt = (tid >> 6) & 7;
    const int lane = tid & 63;
    const int q = lane >> 4;
    const int col = nt * 16 + (lane & 15);
    f16x8 v;
    #pragma unroll
    for (int j = 0; j < 8; ++j)
        v[j] = (_Float16)Wm[(kiter * 32 + q * 8 + j) * D + col];
    Whs[tid] = v;
}

// ======================= gather DIRECT, 64-node blocks (full tier) ===========
// One block per 64 nodes (half coarse bin): bin = g>>1, sub = g&1. Segment =
// [bin*CAPB, bin*CAPB + clamp(bcnt[bin])). Phase 1: stream segment, keep the
// 1/2 of edges whose local dst is in this half, push src ids into per-node
// LDS lists. Phase 2: 4 rounds of the proven 16-lane/node 8-deep gather.
// HARDENED: count clamped; src validated at push and in fallback.
__global__ __launch_bounds__(256) void gather_direct(
    const unsigned short* __restrict__ hs, const int* __restrict__ bcnt,
    const int* __restrict__ ebuf, _Float16* __restrict__ g16,
    const float* __restrict__ Wm, f16x8* __restrict__ Whs)
{
    if ((int)blockIdx.x >= GATHD_NBLK) {
        wprep_body((blockIdx.x - GATHD_NBLK) * 256 + threadIdx.x, Wm, Whs);
        return;
    }
    __shared__ int lists[64][LSTR];
    __shared__ int lcnt[64];
    const int t = threadIdx.x;
    const int g = blockIdx.x;
    const int bin = g >> 1;
    const int sub = g & 1;
    if (t < 64) lcnt[t] = 0;
    __syncthreads();
    int cnt = bcnt[bin];
    cnt = (cnt < 0) ? 0 : ((cnt > CAPB) ? CAPB : cnt);
    const int b0 = bin * CAPB;
    const int b1 = b0 + cnt;
    for (int i = b0 + t; i < b1; i += 256) {
        const int w = ebuf[i];
        const int l = w & (BNODES - 1);
        const unsigned s = (unsigned)w >> SHIFT;     // src (w >= 0: src < 2^17)
        if ((l >> 6) == sub && s < (unsigned)N_NODES) {
            const int p = atomicAdd(&lcnt[l & 63], 1);
            if (p < CAP_N) lists[l & 63][p] = (int)s;
        }
    }
    __syncthreads();

    const int grp = t >> 4;                         // 0..15
    const int c = (t & 15) << 3;                    // 8 cols per lane

    #pragma unroll 1
    for (int r = 0; r < 4; ++r) {
        const int local = r * 16 + grp;             // 0..63
        const int node = g * 64 + local;
        const int deg = lcnt[local];
        float a[8];
        #pragma unroll
        for (int j = 0; j < 8; ++j) a[j] = 0.f;

        if (deg <= CAP_N) {
            const int* lp = lists[local];
            int i = 0;
            for (; i + 7 < deg; i += 8) {
                const int s0 = lp[i];     const int s1 = lp[i + 1];
                const int s2 = lp[i + 2]; const int s3 = lp[i + 3];
                const int s4 = lp[i + 4]; const int s5 = lp[i + 5];
                const int s6 = lp[i + 6]; const int s7 = lp[i + 7];
                const u16x8 u0 = *reinterpret_cast<const u16x8*>(hs + s0 * D + c);
                const u16x8 u1 = *reinterpret_cast<const u16x8*>(hs + s1 * D + c);
                const u16x8 u2 = *reinterpret_cast<const u16x8*>(hs + s2 * D + c);
                const u16x8 u3 = *reinterpret_cast<const u16x8*>(hs + s3 * D + c);
                const u16x8 u4 = *reinterpret_cast<const u16x8*>(hs + s4 * D + c);
                const u16x8 u5 = *reinterpret_cast<const u16x8*>(hs + s5 * D + c);
                const u16x8 u6 = *reinterpret_cast<const u16x8*>(hs + s6 * D + c);
                const u16x8 u7 = *reinterpret_cast<const u16x8*>(hs + s7 * D + c);
                #pragma unroll
                for (int j = 0; j < 8; ++j) {
                    a[j] += __uint_as_float((unsigned int)u0[j] << 16);
                    a[j] += __uint_as_float((unsigned int)u1[j] << 16);
                    a[j] += __uint_as_float((unsigned int)u2[j] << 16);
                    a[j] += __uint_as_float((unsigned int)u3[j] << 16);
                    a[j] += __uint_as_float((unsigned int)u4[j] << 16);
                    a[j] += __uint_as_float((unsigned int)u5[j] << 16);
                    a[j] += __uint_as_float((unsigned int)u6[j] << 16);
                    a[j] += __uint_as_float((unsigned int)u7[j] << 16);
                }
            }
            if (i + 3 < deg) {
                const int s0 = lp[i];     const int s1 = lp[i + 1];
                const int s2 = lp[i + 2]; const int s3 = lp[i + 3];
                const u16x8 u0 = *reinterpret_cast<const u16x8*>(hs + s0 * D + c);
                const u16x8 u1 = *reinterpret_cast<const u16x8*>(hs + s1 * D + c);
                const u16x8 u2 = *reinterpret_cast<const u16x8*>(hs + s2 * D + c);
                const u16x8 u3 = *reinterpret_cast<const u16x8*>(hs + s3 * D + c);
                #pragma unroll
                for (int j = 0; j < 8; ++j) {
                    a[j] += __uint_as_float((unsigned int)u0[j] << 16);
                    a[j] += __uint_as_float((unsigned int)u1[j] << 16);
                    a[j] += __uint_as_float((unsigned int)u2[j] << 16);
                    a[j] += __uint_as_float((unsigned int)u3[j] << 16);
                }
                i += 4;
            }
            for (; i < deg; ++i) {
                const int s = lp[i];
                const u16x8 u = *reinterpret_cast<const u16x8*>(hs + s * D + c);
                #pragma unroll
                for (int j = 0; j < 8; ++j)
                    a[j] += __uint_as_float((unsigned int)u[j] << 16);
            }
        } else {
            // ultra-rare overflow fallback: scan bin segment for my node's edges
            const int myl = (sub << 6) | local;
            for (int i = b0; i < b1; ++i) {
                const int w = ebuf[i];
                const unsigned s = (unsigned)w >> SHIFT;
                if ((w & (BNODES - 1)) == myl && s < (unsigned)N_NODES) {
                    const u16x8 u = *reinterpret_cast<const u16x8*>(hs + s * D + c);
                    #pragma unroll
                    for (int j = 0; j < 8; ++j)
                        a[j] += __uint_as_float((unsigned int)u[j] << 16);
                }
            }
        }

        if (node < N_NODES) {
            f16x8 o;
            #pragma unroll
            for (int j = 0; j < 8; ++j) o[j] = (_Float16)a[j];
            *reinterpret_cast<f16x8*>(g16 + node * GROW16 + c) = o;
        }
    }
}

// ======================= MFMA GEMM + epilogue (full tier, f16 g) =======================
__global__ __launch_bounds__(256) void gemm_mfma_f16g(
    const _Float16* g16, float* out, const f16x8* __restrict__ Whs,
    const float* __restrict__ bias, const float* __restrict__ norm)
{
    __shared__ f16x8 Wlds[2048];           // 32 KB
    const int t = threadIdx.x;
    const int row0 = blockIdx.x * 64;

    #pragma unroll
    for (int p = 0; p < 8; ++p)
        reinterpret_cast<float4*>(Wlds)[p * 256 + t] =
            reinterpret_cast<const float4*>(Whs)[p * 256 + t];
    __syncthreads();

    const int lane = t & 63;
    const int strip = t >> 6;
    const int q = lane >> 4;
    const int l15 = lane & 15;

    int mrow = row0 + strip * 16 + l15;
    if (mrow >= N_NODES) mrow = N_NODES - 1;

    f32x4 acc[8];
    #pragma unroll
    for (int i = 0; i < 8; ++i) acc[i] = (f32x4){0.f, 0.f, 0.f, 0.f};

    #pragma unroll
    for (int kiter = 0; kiter < 4; ++kiter) {
        const f16x8 a =
            *reinterpret_cast<const f16x8*>(g16 + mrow * GROW16 + kiter * 32 + q * 8);
        #pragma unroll
        for (int nt = 0; nt < 8; ++nt) {
            const f16x8 b = Wlds[(kiter * 8 + nt) * 64 + lane];
            acc[nt] = __builtin_amdgcn_mfma_f32_16x16x32_f16(a, b, acc[nt], 0, 0, 0);
        }
    }

    // all f16 A-reads of this block's slab must complete before fp32 overwrite
    __syncthreads();

    float nrm[4];
    int mr[4];
    #pragma unroll
    for (int rgi = 0; rgi < 4; ++rgi) {
        mr[rgi] = row0 + strip * 16 + q * 4 + rgi;
        nrm[rgi] = (mr[rgi] < N_NODES) ? norm[mr[rgi]] : 0.f;
    }
    #pragma unroll
    for (int nt = 0; nt < 8; ++nt) {
        const int col = nt * 16 + l15;
        const float bc = bias[col];
        #pragma unroll
        for (int rgi = 0; rgi < 4; ++rgi) {
            if (mr[rgi] < N_NODES) {
                float v = acc[nt][rgi] * nrm[rgi] + bc;
                v = v > 0.f ? v : 0.2f * v;
                out[mr[rgi] * D + col] = v;
            }
        }
    }
}

// ======================= mid-tier legacy chain (unchanged, proven) ===========
__global__ __launch_bounds__(256) void prep_count(const float* __restrict__ h,
                                                  const float* __restrict__ norm,
                                                  unsigned short* __restrict__ hs,
                                                  const int* __restrict__ dst,
                                                  int* __restrict__ cnt,
                                                  int prep_blocks) {
    __shared__ int hist[NB];
    const int t = threadIdx.x;
    if ((int)blockIdx.x < prep_blocks) {
        const int idx = blockIdx.x * 256 + t;
        const int node = idx >> 5;
        const int c = (idx & 31) << 2;
        const float nv = norm[node];
        const float4 v = *reinterpret_cast<const float4*>(h + node * D + c);
        float a[4] = {v.x * nv, v.y * nv, v.z * nv, v.w * nv};
        ushort4 o;
        unsigned short* op = reinterpret_cast<unsigned short*>(&o);
        #pragma unroll
        for (int i = 0; i < 4; ++i) {
            unsigned int u = __float_as_uint(a[i]);
            u += 0x7FFFu + ((u >> 16) & 1u);
            op[i] = (unsigned short)(u >> 16);
        }
        *reinterpret_cast<ushort4*>(hs + node * D + c) = o;
        return;
    }
    const int cb = blockIdx.x - prep_blocks;
    const int e0 = cb * CNT_CHUNK;
    const int rem = (E_EDGES - e0 < CNT_CHUNK) ? (E_EDGES - e0) : CNT_CHUNK;
    for (int i = t; i < NB; i += 256) hist[i] = 0;
    __syncthreads();
    if (rem == CNT_CHUNK) {
        const int4* d4 = reinterpret_cast<const int4*>(dst + e0);
        #pragma unroll
        for (int p = 0; p < 2; ++p) {
            const int4 v = d4[p * 256 + t];
            atomicAdd(&hist[v.x >> SHIFT], 1);
            atomicAdd(&hist[v.y >> SHIFT], 1);
            atomicAdd(&hist[v.z >> SHIFT], 1);
            atomicAdd(&hist[v.w >> SHIFT], 1);
        }
    } else {
        for (int i = t; i < rem; i += 256)
            atomicAdd(&hist[dst[e0 + i] >> SHIFT], 1);
    }
    __syncthreads();
    for (int b = t; b < NB; b += 256) {
        const int c = hist[b];
        if (c) atomicAdd(&cnt[b], c);
    }
}

__global__ __launch_bounds__(1024) void coarse_scan(const int* __restrict__ cnt,
                                                    int* __restrict__ boff,
                                                    int* __restrict__ pos) {
    __shared__ int buf[2][1024];
    const int t = threadIdx.x;
    const int v = (t < NB) ? cnt[t] : 0;
    int pi = 0;
    buf[0][t] = v;
    __syncthreads();
    #pragma unroll
    for (int o = 1; o < 1024; o <<= 1) {
        const int nv = buf[pi][t] + (t >= o ? buf[pi][t - o] : 0);
        buf[1 - pi][t] = nv;
        pi = 1 - pi;
        __syncthreads();
    }
    if (t < NB) {
        const int excl = buf[pi][t] - v;
        boff[t] = excl;
        pos[t] = excl;
    }
    if (t == 0) boff[NB] = E_EDGES;
}

__global__ __launch_bounds__(1024) void coarse_scatter(const int* __restrict__ src,
                                                       const int* __restrict__ dst,
                                                       int* __restrict__ pos,
                                                       int* __restrict__ ebuf) {
    __shared__ int hist[NB];
    const int t = threadIdx.x;
    const int e0 = blockIdx.x * SCAT_CHUNK;
    const int rem = (E_EDGES - e0 < SCAT_CHUNK) ? (E_EDGES - e0) : SCAT_CHUNK;
    for (int i = t; i < NB; i += 1024) hist[i] = 0;
    __syncthreads();
    if (rem == SCAT_CHUNK) {
        const int4* d4 = reinterpret_cast<const int4*>(dst + e0);
        #pragma unroll
        for (int p = 0; p < SCAT_PASS; ++p) {
            const int4 v = d4[p * 1024 + t];
            atomicAdd(&hist[v.x >> SHIFT], 1);
            atomicAdd(&hist[v.y >> SHIFT], 1);
            atomicAdd(&hist[v.z >> SHIFT], 1);
            atomicAdd(&hist[v.w >> SHIFT], 1);
        }
    } else {
        for (int i = t; i < rem; i += 1024)
            atomicAdd(&hist[dst[e0 + i] >> SHIFT], 1);
    }
    __syncthreads();
    for (int b = t; b < NB; b += 1024) {
        const int c = hist[b];
        if (c) hist[b] = atomicAdd(&pos[b], c);
    }
    __syncthreads();
    if (rem == SCAT_CHUNK) {
        const int4* d4 = reinterpret_cast<const int4*>(dst + e0);
        const int4* s4 = reinterpret_cast<const int4*>(src + e0);
        #pragma unroll
        for (int p = 0; p < SCAT_PASS; ++p) {
            const int4 dv = d4[p * 1024 + t];
            const int4 sv = s4[p * 1024 + t];
            int pz;
            pz = atomicAdd(&hist[dv.x >> SHIFT], 1);
            ebuf[pz] = (sv.x << SHIFT) | (dv.x & (BNODES - 1));
            pz = atomicAdd(&hist[dv.y >> SHIFT], 1);
            ebuf[pz] = (sv.y << SHIFT) | (dv.y & (BNODES - 1));
            pz = atomicAdd(&hist[dv.z >> SHIFT], 1);
            ebuf[pz] = (sv.z << SHIFT) | (dv.z & (BNODES - 1));
            pz = atomicAdd(&hist[dv.w >> SHIFT], 1);
            ebuf[pz] = (sv.w << SHIFT) | (dv.w & (BNODES - 1));
        }
    } else {
        for (int i = t; i < rem; i += 1024) {
            const int d = dst[e0 + i];
            const int b = d >> SHIFT;
            const int p = atomicAdd(&hist[b], 1);
            ebuf[p] = (src[e0 + i] << SHIFT) | (d & (BNODES - 1));
        }
    }
}

__global__ __launch_bounds__(256) void bin_sort(const int* __restrict__ boff,
                                                const int* __restrict__ ebuf,
                                                int* __restrict__ esrc,
                                                int* __restrict__ noff) {
    __shared__ int hist[BNODES];
    __shared__ int curs[BNODES];
    __shared__ int sbuf[2][BNODES];
    const int t = threadIdx.x;
    const int bin = blockIdx.x;
    if (t < BNODES) hist[t] = 0;
    __syncthreads();
    const int b0 = boff[bin];
    const int b1 = boff[bin + 1];
    for (int i = b0 + t; i < b1; i += 256)
        atomicAdd(&hist[ebuf[i] & (BNODES - 1)], 1);
    __syncthreads();
    if (t < BNODES) sbuf[0][t] = hist[t];
    __syncthreads();
    int pi = 0;
    #pragma unroll
    for (int o = 1; o < BNODES; o <<= 1) {
        if (t < BNODES)
            sbuf[1 - pi][t] = sbuf[pi][t] + (t >= o ? sbuf[pi][t - o] : 0);
        pi = 1 - pi;
        __syncthreads();
    }
    if (t < BNODES) {
        const int base = b0 + sbuf[pi][t] - hist[t];
        curs[t] = base;
        const int node = (bin << SHIFT) + t;
        if (node < N_NODES) noff[node] = base;
    }
    if (bin == 0 && t == 0) noff[N_NODES] = E_EDGES;
    __syncthreads();
    for (int i = b0 + t; i < b1; i += 256) {
        const int w = ebuf[i];
        const int p = atomicAdd(&curs[w & (BNODES - 1)], 1);
        esrc[p] = w >> SHIFT;
    }
}

__global__ __launch_bounds__(256) void gather_fp32(const float* __restrict__ h,
                                                   const float* __restrict__ norm,
                                                   const int* __restrict__ noff,
                                                   const int* __restrict__ esrc,
                                                   float* __restrict__ g,
                                                   const float* __restrict__ Wm,
                                                   f16x8* __restrict__ Whs) {
    if ((int)blockIdx.x >= GATH32_NBLK) {
        wprep_body((blockIdx.x - GATH32_NBLK) * 256 + threadIdx.x, Wm, Whs);
        return;
    }
    const int t = threadIdx.x;
    const int node = blockIdx.x * 8 + (t >> 5);
    const int c = (t & 31) << 2;
    const int beg = noff[node];
    const int end = noff[node + 1];
    float4 acc = make_float4(0.f, 0.f, 0.f, 0.f);
    for (int i = beg; i < end; ++i) {
        const int s = esrc[i];
        const float nv = norm[s];
        const float4 hv = *reinterpret_cast<const float4*>(h + s * D + c);
        acc.x += hv.x * nv;
        acc.y += hv.y * nv;
        acc.z += hv.z * nv;
        acc.w += hv.w * nv;
    }
    *reinterpret_cast<float4*>(g + node * D + c) = acc;
}

__global__ __launch_bounds__(256) void scatter_kernel(
    const float* __restrict__ h, const float* __restrict__ norm,
    const int* __restrict__ src, const int* __restrict__ dst,
    float* __restrict__ g)
{
    const int idx = blockIdx.x * 256 + threadIdx.x;
    const int e = idx >> 5;
    const int c = (idx & 31) << 2;
    const int s = src[e];
    const int d = dst[e];
    const float nv = norm[s];
    const float4 hv = *reinterpret_cast<const float4*>(h + s * D + c);
    float* gp = g + d * D + c;
    atomicAdd(gp + 0, hv.x * nv);
    atomicAdd(gp + 1, hv.y * nv);
    atomicAdd(gp + 2, hv.z * nv);
    atomicAdd(gp + 3, hv.w * nv);
}

__global__ __launch_bounds__(256) void gemm_mfma(
    float* __restrict__ out, const f16x8* __restrict__ Whs,
    const float* __restrict__ bias, const float* __restrict__ norm)
{
    __shared__ f16x8 Wlds[2048];           // 32 KB
    const int t = threadIdx.x;
    const int row0 = blockIdx.x * 64;

    #pragma unroll
    for (int p = 0; p < 8; ++p)
        reinterpret_cast<float4*>(Wlds)[p * 256 + t] =
            reinterpret_cast<const float4*>(Whs)[p * 256 + t];
    __syncthreads();

    const int lane = t & 63;
    const int strip = t >> 6;
    const int q = lane >> 4;
    const int l15 = lane & 15;

    int mrow = row0 + strip * 16 + l15;
    if (mrow >= N_NODES) mrow = N_NODES - 1;

    f32x4 acc[8];
    #pragma unroll
    for (int i = 0; i < 8; ++i) acc[i] = (f32x4){0.f, 0.f, 0.f, 0.f};

    #pragma unroll
    for (int kiter = 0; kiter < 4; ++kiter) {
        const float* gp = out + mrow * D + kiter * 32 + q * 8;
        const float4 ga = *reinterpret_cast<const float4*>(gp);
        const float4 gb = *reinterpret_cast<const float4*>(gp + 4);
        f16x8 a;
        a[0] = (_Float16)ga.x; a[1] = (_Float16)ga.y;
        a[2] = (_Float16)ga.z; a[3] = (_Float16)ga.w;
        a[4] = (_Float16)gb.x; a[5] = (_Float16)gb.y;
        a[6] = (_Float16)gb.z; a[7] = (_Float16)gb.w;
        #pragma unroll
        for (int nt = 0; nt < 8; ++nt) {
            const f16x8 b = Wlds[(kiter * 8 + nt) * 64 + lane];
            acc[nt] = __builtin_amdgcn_mfma_f32_16x16x32_f16(a, b, acc[nt], 0, 0, 0);
        }
    }

    float nrm[4];
    int mr[4];
    #pragma unroll
    for (int rgi = 0; rgi < 4; ++rgi) {
        mr[rgi] = row0 + strip * 16 + q * 4 + rgi;
        nrm[rgi] = (mr[rgi] < N_NODES) ? norm[mr[rgi]] : 0.f;
    }
    #pragma unroll
    for (int nt = 0; nt < 8; ++nt) {
        const int col = nt * 16 + l15;
        const float bc = bias[col];
        #pragma unroll
        for (int rgi = 0; rgi < 4; ++rgi) {
            if (mr[rgi] < N_NODES) {
                float v = acc[nt][rgi] * nrm[rgi] + bc;
                v = v > 0.f ? v : 0.2f * v;
                out[mr[rgi] * D + col] = v;
            }
        }
    }
}

__global__ __launch_bounds__(256) void gemm_epilogue(
    float* __restrict__ out, const float* __restrict__ Wm,
    const float* __restrict__ bias, const float* __restrict__ norm)
{
    __shared__ float gs[GROWS][D + 4];
    __shared__ float Wlds[KCH][D];
    const int t = threadIdx.x;
    const int row0 = blockIdx.x * GROWS;

    #pragma unroll
    for (int p = 0; p < 8; ++p) {
        const int i = p * 256 + t;
        const int r = i >> 5;
        const int c = (i & 31) << 2;
        int gr = row0 + r;
        if (gr >= N_NODES) gr = N_NODES - 1;
        const float4 v = *reinterpret_cast<const float4*>(out + gr * D + c);
        *reinterpret_cast<float4*>(&gs[r][c]) = v;
    }

    const int rg = (t >> 5) * 8;
    const int cb = (t & 31) << 2;

    float4 acc[8];
    #pragma unroll
    for (int i = 0; i < 8; ++i) acc[i] = make_float4(0.f, 0.f, 0.f, 0.f);

    for (int kc = 0; kc < D; kc += KCH) {
        __syncthreads();
        #pragma unroll
        for (int p = 0; p < 4; ++p) {
            const int i = p * 256 + t;
            const int kk = i >> 5;
            const int c = (i & 31) << 2;
            *reinterpret_cast<float4*>(&Wlds[kk][c]) =
                *reinterpret_cast<const float4*>(Wm + (kc + kk) * D + c);
        }
        __syncthreads();

        #pragma unroll
        for (int k4 = 0; k4 < KCH; k4 += 4) {
            float4 wv[4];
            #pragma unroll
            for (int kk = 0; kk < 4; ++kk)
                wv[kk] = *reinterpret_cast<const float4*>(&Wlds[k4 + kk][cb]);
            #pragma unroll
            for (int i = 0; i < 8; ++i) {
                const float4 gv = *reinterpret_cast<const float4*>(&gs[rg + i][kc + k4]);
                acc[i].x += gv.x * wv[0].x; acc[i].y += gv.x * wv[0].y;
                acc[i].z += gv.x * wv[0].z; acc[i].w += gv.x * wv[0].w;
                acc[i].x += gv.y * wv[1].x; acc[i].y += gv.y * wv[1].y;
                acc[i].z += gv.y * wv[1].z; acc[i].w += gv.y * wv[1].w;
                acc[i].x += gv.z * wv[2].x; acc[i].y += gv.z * wv[2].y;
                acc[i].z += gv.z * wv[2].z; acc[i].w += gv.z * wv[2].w;
                acc[i].x += gv.w * wv[3].x; acc[i].y += gv.w * wv[3].y;
                acc[i].z += gv.w * wv[3].z; acc[i].w += gv.w * wv[3].w;
            }
        }
    }

    const float4 b = *reinterpret_cast<const float4*>(bias + cb);
    #pragma unroll
    for (int i = 0; i < 8; ++i) {
        const int gr = row0 + rg + i;
        if (gr < N_NODES) {
            const float nv = norm[gr];
            float4 v;
            v.x = acc[i].x * nv + b.x;
            v.y = acc[i].y * nv + b.y;
            v.z = acc[i].z * nv + b.z;
            v.w = acc[i].w * nv + b.w;
            v.x = v.x > 0.f ? v.x : 0.2f * v.x;
            v.y = v.y > 0.f ? v.y : 0.2f * v.y;
            v.z = v.z > 0.f ? v.z : 0.2f * v.z;
            v.w = v.w > 0.f ? v.w : 0.2f * v.w;
            *reinterpret_cast<float4*>(out + gr * D + cb) = v;
        }
    }
}

extern "C" void kernel_launch(void* const* d_in, const int* in_sizes, int n_in,
                              void* d_out, int out_size, void* d_ws, size_t ws_size,
                              hipStream_t stream) {
    const float* h    = (const float*)d_in[0];
    const float* norm = (const float*)d_in[1];
    const float* Wm   = (const float*)d_in[2];
    const float* bias = (const float*)d_in[3];
    const int*   src  = (const int*)d_in[4];
    const int*   dst  = (const int*)d_in[5];
    float* out = (float*)d_out;
    int* ws = (int*)d_ws;

    if (ws_size >= WS_MID_INTS * 4) {
        const bool use_bf16 = (ws_size >= WS_FULL_INTS * 4);

        if (use_bf16) {
            // ---- full tier: 4 dispatches (fixed-capacity bins, no scan) ----
            int* bcnt = ws + WS_CNT;
            int* ebuf = ws + WS_EBUF;                // NB*CAPB bin regions
            f16x8* Whs = (f16x8*)(ws + WS_WHS);
            unsigned short* hs = (unsigned short*)(ws + WS_HS);
            _Float16* g16 = (_Float16*)out;

            hipMemsetAsync(bcnt, 0, 784 * sizeof(int), stream);
            prep_scatter<<<PREP1K + SCAT_NBLK, 1024, 0, stream>>>(
                h, norm, hs, src, dst, bcnt, ebuf, PREP1K);
            gather_direct<<<GATHD_NBLK + 8, 256, 0, stream>>>(hs, bcnt, ebuf, g16, Wm, Whs);
            gemm_mfma_f16g<<<(N_NODES + 63) / 64, 256, 0, stream>>>(g16, out, Whs, bias, norm);
        } else {
            // ---- mid tier: legacy proven chain ----
            int* cnt  = ws + WS_CNT;
            int* pos  = ws + WS_POS;
            int* boff = ws + WS_BOFF;
            int* noff = ws + WS_NOFF;
            int* ebuf = ws + WS_EBUF;
            int* esrc = ws + WS_ESRC;
            f16x8* Whs = (f16x8*)ebuf;      // ebuf dead after bin_sort
            hipMemsetAsync(cnt, 0, 784 * sizeof(int), stream);
            prep_count<<<CNT_NBLK, 256, 0, stream>>>(h, norm, (unsigned short*)ws, dst, cnt, 0);
            coarse_scan   <<<1, 1024, 0, stream>>>(cnt, boff, pos);
            coarse_scatter<<<SCAT_NBLK, 1024, 0, stream>>>(src, dst, pos, ebuf);
            bin_sort      <<<NB, 256, 0, stream>>>(boff, ebuf, esrc, noff);
            gather_fp32<<<GATH32_NBLK + 8, 256, 0, stream>>>(h, norm, noff, esrc, out, Wm, Whs);
            gemm_mfma<<<(N_NODES + 63) / 64, 256, 0, stream>>>(out, Whs, bias, norm);
        }
    } else {
        hipMemsetAsync(out, 0, (size_t)N_NODES * D * sizeof(float), stream);
        scatter_kernel<<<(E_EDGES * 32) / 256, 256, 0, stream>>>(h, norm, src, dst, out);
        gemm_epilogue<<<(N_NODES + GROWS - 1) / GROWS, 256, 0, stream>>>(out, Wm, bias, norm);
    }
}

// Round 11
// 212.550 us; speedup vs baseline: 2.7589x; 1.0290x over previous
//
#include <hip/hip_runtime.h>

#define N_NODES 100000
#define E_EDGES 1600000
#define D 128
#define SHIFT 7
#define BNODES 128
#define NB ((N_NODES + BNODES - 1) / BNODES)     // 782 bins

#define CNT_CHUNK 2048
#define CNT_NBLK ((E_EDGES + CNT_CHUNK - 1) / CNT_CHUNK)    // 782
#define PREP_NBLK (N_NODES * 32 / 256)                      // 12500 (mid tier / legacy)
#define PREP1K (N_NODES * 32 / 1024)                        // 3125 (full tier, 1024-thr)
#define SCAT_CHUNK 8192
#define SCAT_PASS 2                                         // 8192 / (1024*4)
#define SCAT_NBLK ((E_EDGES + SCAT_CHUNK - 1) / SCAT_CHUNK) // 196
#define GATHD_NBLK ((N_NODES + 63) / 64)                    // 1563 (64-node blocks)
#define GATH32_NBLK (N_NODES / 8)                           // 12500 (mid tier)

// fixed-capacity bin regions (full tier): bin counts ~ Poisson(2046), sigma 45;
// CAPB = 2560 = +11 sigma -> overflow statistically impossible; writes guarded.
#define CAPB 2560

// per-node LDS list capacity (deg ~ Poisson(16); 64 = +12 sigma, fallback kept)
#define CAP_N 64
#define LSTR 68          // 68 ints = 272 B/row  ==  136 f16/row (gs overlay, 16B-aligned)

// fp32-GEMM tiling (tier-0 fallback only)
#define GROWS 64
#define KCH 32

typedef _Float16       f16x8  __attribute__((ext_vector_type(8)));
typedef float          f32x4  __attribute__((ext_vector_type(4)));
typedef unsigned short u16x8  __attribute__((ext_vector_type(8)));

// ---- workspace layout (int units) ----
#define WS_CNT   0                         // 784 slots (full tier: bcnt)
#define WS_POS   784                       // 784 slots (mid tier)
#define WS_BOFF  1568                      // 785 slots (mid tier)
#define WS_NOFF  2356                      // N+1 (mid tier only)
#define WS_EBUF  102400                    // full tier: bin regions NB*CAPB = 2,001,920 ints
#define WS_ESRC  (102400 + E_EDGES)        // mid tier
#define WS_HS    (102400 + 2 * E_EDGES)    // N*D/2 ints (bf16 h*norm)
#define WS_FULL_INTS ((size_t)WS_HS + (size_t)N_NODES * D / 2)
#define WS_MID_INTS  ((size_t)WS_HS)

// ======================= FULL TIER: fused prep + fixed-bin scatter ===========
__global__ __launch_bounds__(1024) void prep_scatter(
    const float* __restrict__ h, const float* __restrict__ norm,
    unsigned short* __restrict__ hs, const int* __restrict__ src,
    const int* __restrict__ dst, int* __restrict__ bcnt,
    int* __restrict__ ebuf, int prep_blocks)
{
    __shared__ int hist[NB];
    const int t = threadIdx.x;
    if ((int)blockIdx.x < prep_blocks) {
        const int idx = blockIdx.x * 1024 + t;
        const int node = idx >> 5;
        const int c = (idx & 31) << 2;
        const float nv = norm[node];
        const float4 v = *reinterpret_cast<const float4*>(h + node * D + c);
        float a[4] = {v.x * nv, v.y * nv, v.z * nv, v.w * nv};
        ushort4 o;
        unsigned short* op = reinterpret_cast<unsigned short*>(&o);
        #pragma unroll
        for (int i = 0; i < 4; ++i) {
            unsigned int u = __float_as_uint(a[i]);
            u += 0x7FFFu + ((u >> 16) & 1u);            // round-to-nearest-even
            op[i] = (unsigned short)(u >> 16);
        }
        *reinterpret_cast<ushort4*>(hs + node * D + c) = o;
        return;
    }
    const int cb = blockIdx.x - prep_blocks;
    const int e0 = cb * SCAT_CHUNK;
    const int rem = (E_EDGES - e0 < SCAT_CHUNK) ? (E_EDGES - e0) : SCAT_CHUNK;
    for (int i = t; i < NB; i += 1024) hist[i] = 0;
    __syncthreads();

    // ---- count this chunk ----
    if (rem == SCAT_CHUNK) {
        const int4* d4 = reinterpret_cast<const int4*>(dst + e0);
        #pragma unroll
        for (int p = 0; p < SCAT_PASS; ++p) {
            const int4 vv = d4[p * 1024 + t];
            atomicAdd(&hist[vv.x >> SHIFT], 1);
            atomicAdd(&hist[vv.y >> SHIFT], 1);
            atomicAdd(&hist[vv.z >> SHIFT], 1);
            atomicAdd(&hist[vv.w >> SHIFT], 1);
        }
    } else {
        for (int i = t; i < rem; i += 1024)
            atomicAdd(&hist[dst[e0 + i] >> SHIFT], 1);
    }
    __syncthreads();

    // ---- claim in-bin bases (no scan: fixed region base is bin*CAPB) ----
    if (t < NB) {
        const int c = hist[t];
        hist[t] = c ? atomicAdd(&bcnt[t], c) : 0;
    }
    __syncthreads();

    // ---- scatter packed words into fixed bin regions ----
    if (rem == SCAT_CHUNK) {
        const int4* d4 = reinterpret_cast<const int4*>(dst + e0);
        const int4* s4 = reinterpret_cast<const int4*>(src + e0);
        #pragma unroll
        for (int p = 0; p < SCAT_PASS; ++p) {
            const int4 dv = d4[p * 1024 + t];
            const int4 sv = s4[p * 1024 + t];
            int b, pz;
            b = dv.x >> SHIFT; pz = atomicAdd(&hist[b], 1);
            if (pz < CAPB) ebuf[b * CAPB + pz] = (sv.x << SHIFT) | (dv.x & (BNODES - 1));
            b = dv.y >> SHIFT; pz = atomicAdd(&hist[b], 1);
            if (pz < CAPB) ebuf[b * CAPB + pz] = (sv.y << SHIFT) | (dv.y & (BNODES - 1));
            b = dv.z >> SHIFT; pz = atomicAdd(&hist[b], 1);
            if (pz < CAPB) ebuf[b * CAPB + pz] = (sv.z << SHIFT) | (dv.z & (BNODES - 1));
            b = dv.w >> SHIFT; pz = atomicAdd(&hist[b], 1);
            if (pz < CAPB) ebuf[b * CAPB + pz] = (sv.w << SHIFT) | (dv.w & (BNODES - 1));
        }
    } else {
        for (int i = t; i < rem; i += 1024) {
            const int d = dst[e0 + i];
            const int b = d >> SHIFT;
            const int pz = atomicAdd(&hist[b], 1);
            if (pz < CAPB) ebuf[b * CAPB + pz] = (src[e0 + i] << SHIFT) | (d & (BNODES - 1));
        }
    }
}

// ======================= FULL TIER: fused gather + MFMA GEMM + epilogue ======
// One block per 64 nodes (half coarse bin). Phase 1: filter bin segment into
// per-node LDS lists[64][68]. Phase 2: 4 rounds of the proven 8-deep gather;
// each 16-lane group, after fully reading its OWN list row (wave-lockstep +
// reconvergence guarantee), overwrites that same 272B row with its f16 output
// -> lists and gs[64][136] share LDS bytes exactly (union). Phase 3: proven
// round-3 MFMA over two W half-tiles (Wlds 16KB) + norm/bias/LeakyReLU
// epilogue. Total LDS ~34KB -> 4 blocks/CU. HARDENED: counts clamped, src
// validated at push and in fallback.
__global__ __launch_bounds__(256) void gather_gemm(
    const unsigned short* __restrict__ hs, const int* __restrict__ bcnt,
    const int* __restrict__ ebuf, const float* __restrict__ Wm,
    const float* __restrict__ bias, const float* __restrict__ norm,
    float* __restrict__ out)
{
    __shared__ int lists[64][LSTR];        // 17408 B == gs[64][136] f16 (overlay)
    __shared__ int lcnt[64];
    __shared__ f16x8 Wlds[1024];           // 16 KB, half of W fragments
    _Float16 (*gs)[136] = reinterpret_cast<_Float16 (*)[136]>(&lists[0][0]);

    const int t = threadIdx.x;
    const int g = blockIdx.x;
    const int bin = g >> 1;
    const int sub = g & 1;
    if (t < 64) lcnt[t] = 0;
    __syncthreads();
    int cnt = bcnt[bin];
    cnt = (cnt < 0) ? 0 : ((cnt > CAPB) ? CAPB : cnt);
    const int b0 = bin * CAPB;
    const int b1 = b0 + cnt;
    for (int i = b0 + t; i < b1; i += 256) {
        const int w = ebuf[i];
        const int l = w & (BNODES - 1);
        const unsigned s = (unsigned)w >> SHIFT;     // src (w >= 0: src < 2^17)
        if ((l >> 6) == sub && s < (unsigned)N_NODES) {
            const int p = atomicAdd(&lcnt[l & 63], 1);
            if (p < CAP_N) lists[l & 63][p] = (int)s;
        }
    }
    __syncthreads();

    const int grp = t >> 4;                         // 0..15
    const int c = (t & 15) << 3;                    // 8 cols per lane

    #pragma unroll 1
    for (int r = 0; r < 4; ++r) {
        const int local = r * 16 + grp;             // 0..63, unique per (r,grp)
        const int deg = lcnt[local];
        float a[8];
        #pragma unroll
        for (int j = 0; j < 8; ++j) a[j] = 0.f;

        if (deg <= CAP_N) {
            const int* lp = lists[local];
            int i = 0;
            for (; i + 7 < deg; i += 8) {
                const int s0 = lp[i];     const int s1 = lp[i + 1];
                const int s2 = lp[i + 2]; const int s3 = lp[i + 3];
                const int s4 = lp[i + 4]; const int s5 = lp[i + 5];
                const int s6 = lp[i + 6]; const int s7 = lp[i + 7];
                const u16x8 u0 = *reinterpret_cast<const u16x8*>(hs + s0 * D + c);
                const u16x8 u1 = *reinterpret_cast<const u16x8*>(hs + s1 * D + c);
                const u16x8 u2 = *reinterpret_cast<const u16x8*>(hs + s2 * D + c);
                const u16x8 u3 = *reinterpret_cast<const u16x8*>(hs + s3 * D + c);
                const u16x8 u4 = *reinterpret_cast<const u16x8*>(hs + s4 * D + c);
                const u16x8 u5 = *reinterpret_cast<const u16x8*>(hs + s5 * D + c);
                const u16x8 u6 = *reinterpret_cast<const u16x8*>(hs + s6 * D + c);
                const u16x8 u7 = *reinterpret_cast<const u16x8*>(hs + s7 * D + c);
                #pragma unroll
                for (int j = 0; j < 8; ++j) {
                    a[j] += __uint_as_float((unsigned int)u0[j] << 16);
                    a[j] += __uint_as_float((unsigned int)u1[j] << 16);
                    a[j] += __uint_as_float((unsigned int)u2[j] << 16);
                    a[j] += __uint_as_float((unsigned int)u3[j] << 16);
                    a[j] += __uint_as_float((unsigned int)u4[j] << 16);
                    a[j] += __uint_as_float((unsigned int)u5[j] << 16);
                    a[j] += __uint_as_float((unsigned int)u6[j] << 16);
                    a[j] += __uint_as_float((unsigned int)u7[j] << 16);
                }
            }
            if (i + 3 < deg) {
                const int s0 = lp[i];     const int s1 = lp[i + 1];
                const int s2 = lp[i + 2]; const int s3 = lp[i + 3];
                const u16x8 u0 = *reinterpret_cast<const u16x8*>(hs + s0 * D + c);
                const u16x8 u1 = *reinterpret_cast<const u16x8*>(hs + s1 * D + c);
                const u16x8 u2 = *reinterpret_cast<const u16x8*>(hs + s2 * D + c);
                const u16x8 u3 = *reinterpret_cast<const u16x8*>(hs + s3 * D + c);
                #pragma unroll
                for (int j = 0; j < 8; ++j) {
                    a[j] += __uint_as_float((unsigned int)u0[j] << 16);
                    a[j] += __uint_as_float((unsigned int)u1[j] << 16);
                    a[j] += __uint_as_float((unsigned int)u2[j] << 16);
                    a[j] += __uint_as_float((unsigned int)u3[j] << 16);
                }
                i += 4;
            }
            for (; i < deg; ++i) {
                const int s = lp[i];
                const u16x8 u = *reinterpret_cast<const u16x8*>(hs + s * D + c);
                #pragma unroll
                for (int j = 0; j < 8; ++j)
                    a[j] += __uint_as_float((unsigned int)u[j] << 16);
            }
        } else {
            // ultra-rare overflow fallback: scan bin segment for my node's edges
            const int myl = (sub << 6) | local;
            for (int i = b0; i < b1; ++i) {
                const int w = ebuf[i];
                const unsigned s = (unsigned)w >> SHIFT;
                if ((w & (BNODES - 1)) == myl && s < (unsigned)N_NODES) {
                    const u16x8 u = *reinterpret_cast<const u16x8*>(hs + s * D + c);
                    #pragma unroll
                    for (int j = 0; j < 8; ++j)
                        a[j] += __uint_as_float((unsigned int)u[j] << 16);
                }
            }
        }

        // overwrite THIS GROUP'S OWN list row with its f16 output (row owned
        // 1:1 by (r,grp); wave-lockstep + reconvergence => reads done first)
        f16x8 o;
        #pragma unroll
        for (int j = 0; j < 8; ++j) o[j] = (_Float16)a[j];
        *reinterpret_cast<f16x8*>(&gs[local][c]) = o;
    }

    // ---------------- phase 3: MFMA over two W half-tiles ----------------
    const int lane = t & 63;
    const int strip = t >> 6;
    const int q = lane >> 4;
    const int l15 = lane & 15;
    const int row0 = g * 64;

    f32x4 acc[8];
    #pragma unroll
    for (int i = 0; i < 8; ++i) acc[i] = (f32x4){0.f, 0.f, 0.f, 0.f};

    #pragma unroll 1
    for (int half = 0; half < 2; ++half) {
        __syncthreads();                   // half 0: gs ready; half 1: Wlds drained
        for (int e = t; e < 1024; e += 256) {
            const int ge = (half << 10) + e;
            const int kiter = ge >> 9;
            const int nt = (ge >> 6) & 7;
            const int lane2 = ge & 63;
            const int q2 = lane2 >> 4;
            const int col = nt * 16 + (lane2 & 15);
            f16x8 v;
            #pragma unroll
            for (int j = 0; j < 8; ++j)
                v[j] = (_Float16)Wm[(kiter * 32 + q2 * 8 + j) * D + col];
            Wlds[e] = v;
        }
        __syncthreads();
        #pragma unroll
        for (int kk = 0; kk < 2; ++kk) {
            const int kiter = half * 2 + kk;
            const f16x8 a =
                *reinterpret_cast<const f16x8*>(&gs[strip * 16 + l15][kiter * 32 + q * 8]);
            #pragma unroll
            for (int nt = 0; nt < 8; ++nt) {
                const f16x8 b = Wlds[(kk * 8 + nt) * 64 + lane];
                acc[nt] = __builtin_amdgcn_mfma_f32_16x16x32_f16(a, b, acc[nt], 0, 0, 0);
            }
        }
    }

    float nrm[4];
    int mr[4];
    #pragma unroll
    for (int rgi = 0; rgi < 4; ++rgi) {
        mr[rgi] = row0 + strip * 16 + q * 4 + rgi;
        nrm[rgi] = (mr[rgi] < N_NODES) ? norm[mr[rgi]] : 0.f;
    }
    #pragma unroll
    for (int nt = 0; nt < 8; ++nt) {
        const int col = nt * 16 + l15;
        const float bc = bias[col];
        #pragma unroll
        for (int rgi = 0; rgi < 4; ++rgi) {
            if (mr[rgi] < N_NODES) {
                float v = acc[nt][rgi] * nrm[rgi] + bc;
                v = v > 0.f ? v : 0.2f * v;
                out[mr[rgi] * D + col] = v;
            }
        }
    }
}

// ======================= mid-tier legacy chain (unchanged, proven) ===========
__global__ __launch_bounds__(256) void prep_count(const float* __restrict__ h,
                                                  const float* __restrict__ norm,
                                                  unsigned short* __restrict__ hs,
                                                  const int* __restrict__ dst,
                                                  int* __restrict__ cnt,
                                                  int prep_blocks) {
    __shared__ int hist[NB];
    const int t = threadIdx.x;
    if ((int)blockIdx.x < prep_blocks) {
        const int idx = blockIdx.x * 256 + t;
        const int node = idx >> 5;
        const int c = (idx & 31) << 2;
        const float nv = norm[node];
        const float4 v = *reinterpret_cast<const float4*>(h + node * D + c);
        float a[4] = {v.x * nv, v.y * nv, v.z * nv, v.w * nv};
        ushort4 o;
        unsigned short* op = reinterpret_cast<unsigned short*>(&o);
        #pragma unroll
        for (int i = 0; i < 4; ++i) {
            unsigned int u = __float_as_uint(a[i]);
            u += 0x7FFFu + ((u >> 16) & 1u);
            op[i] = (unsigned short)(u >> 16);
        }
        *reinterpret_cast<ushort4*>(hs + node * D + c) = o;
        return;
    }
    const int cb = blockIdx.x - prep_blocks;
    const int e0 = cb * CNT_CHUNK;
    const int rem = (E_EDGES - e0 < CNT_CHUNK) ? (E_EDGES - e0) : CNT_CHUNK;
    for (int i = t; i < NB; i += 256) hist[i] = 0;
    __syncthreads();
    if (rem == CNT_CHUNK) {
        const int4* d4 = reinterpret_cast<const int4*>(dst + e0);
        #pragma unroll
        for (int p = 0; p < 2; ++p) {
            const int4 v = d4[p * 256 + t];
            atomicAdd(&hist[v.x >> SHIFT], 1);
            atomicAdd(&hist[v.y >> SHIFT], 1);
            atomicAdd(&hist[v.z >> SHIFT], 1);
            atomicAdd(&hist[v.w >> SHIFT], 1);
        }
    } else {
        for (int i = t; i < rem; i += 256)
            atomicAdd(&hist[dst[e0 + i] >> SHIFT], 1);
    }
    __syncthreads();
    for (int b = t; b < NB; b += 256) {
        const int c = hist[b];
        if (c) atomicAdd(&cnt[b], c);
    }
}

__global__ __launch_bounds__(1024) void coarse_scan(const int* __restrict__ cnt,
                                                    int* __restrict__ boff,
                                                    int* __restrict__ pos) {
    __shared__ int buf[2][1024];
    const int t = threadIdx.x;
    const int v = (t < NB) ? cnt[t] : 0;
    int pi = 0;
    buf[0][t] = v;
    __syncthreads();
    #pragma unroll
    for (int o = 1; o < 1024; o <<= 1) {
        const int nv = buf[pi][t] + (t >= o ? buf[pi][t - o] : 0);
        buf[1 - pi][t] = nv;
        pi = 1 - pi;
        __syncthreads();
    }
    if (t < NB) {
        const int excl = buf[pi][t] - v;
        boff[t] = excl;
        pos[t] = excl;
    }
    if (t == 0) boff[NB] = E_EDGES;
}

__global__ __launch_bounds__(1024) void coarse_scatter(const int* __restrict__ src,
                                                       const int* __restrict__ dst,
                                                       int* __restrict__ pos,
                                                       int* __restrict__ ebuf) {
    __shared__ int hist[NB];
    const int t = threadIdx.x;
    const int e0 = blockIdx.x * SCAT_CHUNK;
    const int rem = (E_EDGES - e0 < SCAT_CHUNK) ? (E_EDGES - e0) : SCAT_CHUNK;
    for (int i = t; i < NB; i += 1024) hist[i] = 0;
    __syncthreads();
    if (rem == SCAT_CHUNK) {
        const int4* d4 = reinterpret_cast<const int4*>(dst + e0);
        #pragma unroll
        for (int p = 0; p < SCAT_PASS; ++p) {
            const int4 v = d4[p * 1024 + t];
            atomicAdd(&hist[v.x >> SHIFT], 1);
            atomicAdd(&hist[v.y >> SHIFT], 1);
            atomicAdd(&hist[v.z >> SHIFT], 1);
            atomicAdd(&hist[v.w >> SHIFT], 1);
        }
    } else {
        for (int i = t; i < rem; i += 1024)
            atomicAdd(&hist[dst[e0 + i] >> SHIFT], 1);
    }
    __syncthreads();
    for (int b = t; b < NB; b += 1024) {
        const int c = hist[b];
        if (c) hist[b] = atomicAdd(&pos[b], c);
    }
    __syncthreads();
    if (rem == SCAT_CHUNK) {
        const int4* d4 = reinterpret_cast<const int4*>(dst + e0);
        const int4* s4 = reinterpret_cast<const int4*>(src + e0);
        #pragma unroll
        for (int p = 0; p < SCAT_PASS; ++p) {
            const int4 dv = d4[p * 1024 + t];
            const int4 sv = s4[p * 1024 + t];
            int pz;
            pz = atomicAdd(&hist[dv.x >> SHIFT], 1);
            ebuf[pz] = (sv.x << SHIFT) | (dv.x & (BNODES - 1));
            pz = atomicAdd(&hist[dv.y >> SHIFT], 1);
            ebuf[pz] = (sv.y << SHIFT) | (dv.y & (BNODES - 1));
            pz = atomicAdd(&hist[dv.z >> SHIFT], 1);
            ebuf[pz] = (sv.z << SHIFT) | (dv.z & (BNODES - 1));
            pz = atomicAdd(&hist[dv.w >> SHIFT], 1);
            ebuf[pz] = (sv.w << SHIFT) | (dv.w & (BNODES - 1));
        }
    } else {
        for (int i = t; i < rem; i += 1024) {
            const int d = dst[e0 + i];
            const int b = d >> SHIFT;
            const int p = atomicAdd(&hist[b], 1);
            ebuf[p] = (src[e0 + i] << SHIFT) | (d & (BNODES - 1));
        }
    }
}

__global__ __launch_bounds__(256) void bin_sort(const int* __restrict__ boff,
                                                const int* __restrict__ ebuf,
                                                int* __restrict__ esrc,
                                                int* __restrict__ noff) {
    __shared__ int hist[BNODES];
    __shared__ int curs[BNODES];
    __shared__ int sbuf[2][BNODES];
    const int t = threadIdx.x;
    const int bin = blockIdx.x;
    if (t < BNODES) hist[t] = 0;
    __syncthreads();
    const int b0 = boff[bin];
    const int b1 = boff[bin + 1];
    for (int i = b0 + t; i < b1; i += 256)
        atomicAdd(&hist[ebuf[i] & (BNODES - 1)], 1);
    __syncthreads();
    if (t < BNODES) sbuf[0][t] = hist[t];
    __syncthreads();
    int pi = 0;
    #pragma unroll
    for (int o = 1; o < BNODES; o <<= 1) {
        if (t < BNODES)
            sbuf[1 - pi][t] = sbuf[pi][t] + (t >= o ? sbuf[pi][t - o] : 0);
        pi = 1 - pi;
        __syncthreads();
    }
    if (t < BNODES) {
        const int base = b0 + sbuf[pi][t] - hist[t];
        curs[t] = base;
        const int node = (bin << SHIFT) + t;
        if (node < N_NODES) noff[node] = base;
    }
    if (bin == 0 && t == 0) noff[N_NODES] = E_EDGES;
    __syncthreads();
    for (int i = b0 + t; i < b1; i += 256) {
        const int w = ebuf[i];
        const int p = atomicAdd(&curs[w & (BNODES - 1)], 1);
        esrc[p] = w >> SHIFT;
    }
}

__device__ __forceinline__ void wprep_body(int tid, const float* __restrict__ Wm,
                                           f16x8* __restrict__ Whs) {
    const int kiter = tid >> 9;
    const int nt = (tid >> 6) & 7;
    const int lane = tid & 63;
    const int q = lane >> 4;
    const int col = nt * 16 + (lane & 15);
    f16x8 v;
    #pragma unroll
    for (int j = 0; j < 8; ++j)
        v[j] = (_Float16)Wm[(kiter * 32 + q * 8 + j) * D + col];
    Whs[tid] = v;
}

__global__ __launch_bounds__(256) void gather_fp32(const float* __restrict__ h,
                                                   const float* __restrict__ norm,
                                                   const int* __restrict__ noff,
                                                   const int* __restrict__ esrc,
                                                   float* __restrict__ g,
                                                   const float* __restrict__ Wm,
                                                   f16x8* __restrict__ Whs) {
    if ((int)blockIdx.x >= GATH32_NBLK) {
        wprep_body((blockIdx.x - GATH32_NBLK) * 256 + threadIdx.x, Wm, Whs);
        return;
    }
    const int t = threadIdx.x;
    const int node = blockIdx.x * 8 + (t >> 5);
    const int c = (t & 31) << 2;
    const int beg = noff[node];
    const int end = noff[node + 1];
    float4 acc = make_float4(0.f, 0.f, 0.f, 0.f);
    for (int i = beg; i < end; ++i) {
        const int s = esrc[i];
        const float nv = norm[s];
        const float4 hv = *reinterpret_cast<const float4*>(h + s * D + c);
        acc.x += hv.x * nv;
        acc.y += hv.y * nv;
        acc.z += hv.z * nv;
        acc.w += hv.w * nv;
    }
    *reinterpret_cast<float4*>(g + node * D + c) = acc;
}

__global__ __launch_bounds__(256) void scatter_kernel(
    const float* __restrict__ h, const float* __restrict__ norm,
    const int* __restrict__ src, const int* __restrict__ dst,
    float* __restrict__ g)
{
    const int idx = blockIdx.x * 256 + threadIdx.x;
    const int e = idx >> 5;
    const int c = (idx & 31) << 2;
    const int s = src[e];
    const int d = dst[e];
    const float nv = norm[s];
    const float4 hv = *reinterpret_cast<const float4*>(h + s * D + c);
    float* gp = g + d * D + c;
    atomicAdd(gp + 0, hv.x * nv);
    atomicAdd(gp + 1, hv.y * nv);
    atomicAdd(gp + 2, hv.z * nv);
    atomicAdd(gp + 3, hv.w * nv);
}

__global__ __launch_bounds__(256) void gemm_mfma(
    float* __restrict__ out, const f16x8* __restrict__ Whs,
    const float* __restrict__ bias, const float* __restrict__ norm)
{
    __shared__ f16x8 Wlds[2048];           // 32 KB
    const int t = threadIdx.x;
    const int row0 = blockIdx.x * 64;

    #pragma unroll
    for (int p = 0; p < 8; ++p)
        reinterpret_cast<float4*>(Wlds)[p * 256 + t] =
            reinterpret_cast<const float4*>(Whs)[p * 256 + t];
    __syncthreads();

    const int lane = t & 63;
    const int strip = t >> 6;
    const int q = lane >> 4;
    const int l15 = lane & 15;

    int mrow = row0 + strip * 16 + l15;
    if (mrow >= N_NODES) mrow = N_NODES - 1;

    f32x4 acc[8];
    #pragma unroll
    for (int i = 0; i < 8; ++i) acc[i] = (f32x4){0.f, 0.f, 0.f, 0.f};

    #pragma unroll
    for (int kiter = 0; kiter < 4; ++kiter) {
        const float* gp = out + mrow * D + kiter * 32 + q * 8;
        const float4 ga = *reinterpret_cast<const float4*>(gp);
        const float4 gb = *reinterpret_cast<const float4*>(gp + 4);
        f16x8 a;
        a[0] = (_Float16)ga.x; a[1] = (_Float16)ga.y;
        a[2] = (_Float16)ga.z; a[3] = (_Float16)ga.w;
        a[4] = (_Float16)gb.x; a[5] = (_Float16)gb.y;
        a[6] = (_Float16)gb.z; a[7] = (_Float16)gb.w;
        #pragma unroll
        for (int nt = 0; nt < 8; ++nt) {
            const f16x8 b = Wlds[(kiter * 8 + nt) * 64 + lane];
            acc[nt] = __builtin_amdgcn_mfma_f32_16x16x32_f16(a, b, acc[nt], 0, 0, 0);
        }
    }

    float nrm[4];
    int mr[4];
    #pragma unroll
    for (int rgi = 0; rgi < 4; ++rgi) {
        mr[rgi] = row0 + strip * 16 + q * 4 + rgi;
        nrm[rgi] = (mr[rgi] < N_NODES) ? norm[mr[rgi]] : 0.f;
    }
    #pragma unroll
    for (int nt = 0; nt < 8; ++nt) {
        const int col = nt * 16 + l15;
        const float bc = bias[col];
        #pragma unroll
        for (int rgi = 0; rgi < 4; ++rgi) {
            if (mr[rgi] < N_NODES) {
                float v = acc[nt][rgi] * nrm[rgi] + bc;
                v = v > 0.f ? v : 0.2f * v;
                out[mr[rgi] * D + col] = v;
            }
        }
    }
}

__global__ __launch_bounds__(256) void gemm_epilogue(
    float* __restrict__ out, const float* __restrict__ Wm,
    const float* __restrict__ bias, const float* __restrict__ norm)
{
    __shared__ float gs[GROWS][D + 4];
    __shared__ float Wlds[KCH][D];
    const int t = threadIdx.x;
    const int row0 = blockIdx.x * GROWS;

    #pragma unroll
    for (int p = 0; p < 8; ++p) {
        const int i = p * 256 + t;
        const int r = i >> 5;
        const int c = (i & 31) << 2;
        int gr = row0 + r;
        if (gr >= N_NODES) gr = N_NODES - 1;
        const float4 v = *reinterpret_cast<const float4*>(out + gr * D + c);
        *reinterpret_cast<float4*>(&gs[r][c]) = v;
    }

    const int rg = (t >> 5) * 8;
    const int cb = (t & 31) << 2;

    float4 acc[8];
    #pragma unroll
    for (int i = 0; i < 8; ++i) acc[i] = make_float4(0.f, 0.f, 0.f, 0.f);

    for (int kc = 0; kc < D; kc += KCH) {
        __syncthreads();
        #pragma unroll
        for (int p = 0; p < 4; ++p) {
            const int i = p * 256 + t;
            const int kk = i >> 5;
            const int c = (i & 31) << 2;
            *reinterpret_cast<float4*>(&Wlds[kk][c]) =
                *reinterpret_cast<const float4*>(Wm + (kc + kk) * D + c);
        }
        __syncthreads();

        #pragma unroll
        for (int k4 = 0; k4 < KCH; k4 += 4) {
            float4 wv[4];
            #pragma unroll
            for (int kk = 0; kk < 4; ++kk)
                wv[kk] = *reinterpret_cast<const float4*>(&Wlds[k4 + kk][cb]);
            #pragma unroll
            for (int i = 0; i < 8; ++i) {
                const float4 gv = *reinterpret_cast<const float4*>(&gs[rg + i][kc + k4]);
                acc[i].x += gv.x * wv[0].x; acc[i].y += gv.x * wv[0].y;
                acc[i].z += gv.x * wv[0].z; acc[i].w += gv.x * wv[0].w;
                acc[i].x += gv.y * wv[1].x; acc[i].y += gv.y * wv[1].y;
                acc[i].z += gv.y * wv[1].z; acc[i].w += gv.y * wv[1].w;
                acc[i].x += gv.z * wv[2].x; acc[i].y += gv.z * wv[2].y;
                acc[i].z += gv.z * wv[2].z; acc[i].w += gv.z * wv[2].w;
                acc[i].x += gv.w * wv[3].x; acc[i].y += gv.w * wv[3].y;
                acc[i].z += gv.w * wv[3].z; acc[i].w += gv.w * wv[3].w;
            }
        }
    }

    const float4 b = *reinterpret_cast<const float4*>(bias + cb);
    #pragma unroll
    for (int i = 0; i < 8; ++i) {
        const int gr = row0 + rg + i;
        if (gr < N_NODES) {
            const float nv = norm[gr];
            float4 v;
            v.x = acc[i].x * nv + b.x;
            v.y = acc[i].y * nv + b.y;
            v.z = acc[i].z * nv + b.z;
            v.w = acc[i].w * nv + b.w;
            v.x = v.x > 0.f ? v.x : 0.2f * v.x;
            v.y = v.y > 0.f ? v.y : 0.2f * v.y;
            v.z = v.z > 0.f ? v.z : 0.2f * v.z;
            v.w = v.w > 0.f ? v.w : 0.2f * v.w;
            *reinterpret_cast<float4*>(out + gr * D + cb) = v;
        }
    }
}

extern "C" void kernel_launch(void* const* d_in, const int* in_sizes, int n_in,
                              void* d_out, int out_size, void* d_ws, size_t ws_size,
                              hipStream_t stream) {
    const float* h    = (const float*)d_in[0];
    const float* norm = (const float*)d_in[1];
    const float* Wm   = (const float*)d_in[2];
    const float* bias = (const float*)d_in[3];
    const int*   src  = (const int*)d_in[4];
    const int*   dst  = (const int*)d_in[5];
    float* out = (float*)d_out;
    int* ws = (int*)d_ws;

    if (ws_size >= WS_MID_INTS * 4) {
        const bool use_bf16 = (ws_size >= WS_FULL_INTS * 4);

        if (use_bf16) {
            // ---- full tier: 3 dispatches (fixed bins + fused gather/GEMM) ----
            int* bcnt = ws + WS_CNT;
            int* ebuf = ws + WS_EBUF;                // NB*CAPB bin regions
            unsigned short* hs = (unsigned short*)(ws + WS_HS);

            hipMemsetAsync(bcnt, 0, 784 * sizeof(int), stream);
            prep_scatter<<<PREP1K + SCAT_NBLK, 1024, 0, stream>>>(
                h, norm, hs, src, dst, bcnt, ebuf, PREP1K);
            gather_gemm<<<GATHD_NBLK, 256, 0, stream>>>(hs, bcnt, ebuf, Wm, bias, norm, out);
        } else {
            // ---- mid tier: legacy proven chain ----
            int* cnt  = ws + WS_CNT;
            int* pos  = ws + WS_POS;
            int* boff = ws + WS_BOFF;
            int* noff = ws + WS_NOFF;
            int* ebuf = ws + WS_EBUF;
            int* esrc = ws + WS_ESRC;
            f16x8* Whs = (f16x8*)ebuf;      // ebuf dead after bin_sort
            hipMemsetAsync(cnt, 0, 784 * sizeof(int), stream);
            prep_count<<<CNT_NBLK, 256, 0, stream>>>(h, norm, (unsigned short*)ws, dst, cnt, 0);
            coarse_scan   <<<1, 1024, 0, stream>>>(cnt, boff, pos);
            coarse_scatter<<<SCAT_NBLK, 1024, 0, stream>>>(src, dst, pos, ebuf);
            bin_sort      <<<NB, 256, 0, stream>>>(boff, ebuf, esrc, noff);
            gather_fp32<<<GATH32_NBLK + 8, 256, 0, stream>>>(h, norm, noff, esrc, out, Wm, Whs);
            gemm_mfma<<<(N_NODES + 63) / 64, 256, 0, stream>>>(out, Whs, bias, norm);
        }
    } else {
        hipMemsetAsync(out, 0, (size_t)N_NODES * D * sizeof(float), stream);
        scatter_kernel<<<(E_EDGES * 32) / 256, 256, 0, stream>>>(h, norm, src, dst, out);
        gemm_epilogue<<<(N_NODES + GROWS - 1) / GROWS, 256, 0, stream>>>(out, Wm, bias, norm);
    }
}